// Round 1
// baseline (1483.319 us; speedup 1.0000x reference)
//
#include <hip/hip_runtime.h>
#include <math.h>

constexpr int N_ = 50000;
constexpr int E_ = 800000;
constexpr int IN_ = 64;
constexpr int HID_ = 128;
constexpr int G_ = 64;
constexpr float NEG_ = 0.2f;

// ---------------- activation tags ----------------
#define ACT_NONE 0
#define ACT_RELU 1
#define ACT_ELU 2
#define ACT_LEAKY 3

// ---------------- CSR build ----------------
__global__ __launch_bounds__(256) void hist_kernel(const int* __restrict__ dst,
                                                   int* __restrict__ deg, int e) {
  int i = blockIdx.x * 256 + threadIdx.x;
  if (i < e) atomicAdd(&deg[dst[i]], 1);
}

__global__ __launch_bounds__(256) void scan1_kernel(const int* __restrict__ deg,
                                                    int* __restrict__ excl,
                                                    int* __restrict__ bscan, int n) {
  __shared__ int sh[256];
  int t = threadIdx.x;
  int i = blockIdx.x * 256 + t;
  int v = (i < n) ? deg[i] : 0;
  sh[t] = v;
  __syncthreads();
  for (int off = 1; off < 256; off <<= 1) {
    int y = (t >= off) ? sh[t - off] : 0;
    __syncthreads();
    sh[t] += y;
    __syncthreads();
  }
  int incl = sh[t];
  if (i < n) excl[i] = incl - v;
  if (t == 255) bscan[blockIdx.x] = incl;
}

__global__ __launch_bounds__(256) void scan2_kernel(int* __restrict__ data, int nb) {
  __shared__ int sh[256];
  int t = threadIdx.x;
  int v = (t < nb) ? data[t] : 0;
  sh[t] = v;
  __syncthreads();
  for (int off = 1; off < 256; off <<= 1) {
    int y = (t >= off) ? sh[t - off] : 0;
    __syncthreads();
    sh[t] += y;
    __syncthreads();
  }
  if (t < nb) data[t] = sh[t] - v;  // exclusive
}

__global__ __launch_bounds__(256) void scan3_kernel(int* __restrict__ rowptr,
                                                    int* __restrict__ cursor,
                                                    const int* __restrict__ bscan,
                                                    int n, int e) {
  int i = blockIdx.x * 256 + threadIdx.x;
  if (i < n) {
    int v = rowptr[i] + bscan[blockIdx.x];
    rowptr[i] = v;
    cursor[i] = v;
  }
  if (i == n) rowptr[n] = e;
}

__global__ __launch_bounds__(256) void fill_kernel(const int* __restrict__ src,
                                                   const int* __restrict__ dst,
                                                   int* __restrict__ cursor,
                                                   int* __restrict__ csr, int e) {
  int i = blockIdx.x * 256 + threadIdx.x;
  if (i < e) {
    int d = dst[i];
    int p = atomicAdd(&cursor[d], 1);
    csr[p] = src[i];
  }
}

// ---------------- small elementwise add (weight prep) ----------------
__global__ __launch_bounds__(256) void addv_kernel(const float* __restrict__ a,
                                                   const float* __restrict__ b,
                                                   float* __restrict__ o, int n) {
  int i = blockIdx.x * 256 + threadIdx.x;
  if (i < n) o[i] = a[i] + b[i];
}

// ---------------- GEMM: C[M,128] = act(A[M,K] @ W[K,128] + bias), or C += A@W ----------------
template <int K, int ACT, bool ACC>
__global__ __launch_bounds__(256) void gemm_k(const float* __restrict__ A,
                                              const float* __restrict__ W,
                                              const float* __restrict__ bias,
                                              float* __restrict__ C, int M) {
  __shared__ float4 sW[K * 32];
  const int t = threadIdx.x;
  for (int i = t; i < K * 32; i += 256) {
    sW[i] = reinterpret_cast<const float4*>(W)[i];
  }
  __syncthreads();
  const int cg = t & 31;   // cols [4*cg, 4*cg+4)
  const int rg = t >> 5;   // row group 0..7
  const int row0 = blockIdx.x * 64 + rg * 8;
  float4 acc[8];
#pragma unroll
  for (int j = 0; j < 8; ++j) acc[j] = make_float4(0.f, 0.f, 0.f, 0.f);

#pragma unroll 2
  for (int k = 0; k < K; k += 4) {
    float4 w0 = sW[(k + 0) * 32 + cg];
    float4 w1 = sW[(k + 1) * 32 + cg];
    float4 w2 = sW[(k + 2) * 32 + cg];
    float4 w3 = sW[(k + 3) * 32 + cg];
#pragma unroll
    for (int j = 0; j < 8; ++j) {
      int r = row0 + j;
      if (r >= M) r = M - 1;
      float4 a = *reinterpret_cast<const float4*>(A + (size_t)r * K + k);
      acc[j].x += a.x * w0.x + a.y * w1.x + a.z * w2.x + a.w * w3.x;
      acc[j].y += a.x * w0.y + a.y * w1.y + a.z * w2.y + a.w * w3.y;
      acc[j].z += a.x * w0.z + a.y * w1.z + a.z * w2.z + a.w * w3.z;
      acc[j].w += a.x * w0.w + a.y * w1.w + a.z * w2.w + a.w * w3.w;
    }
  }

  float4 bv = make_float4(0.f, 0.f, 0.f, 0.f);
  if (!ACC) bv = reinterpret_cast<const float4*>(bias)[cg];
#pragma unroll
  for (int j = 0; j < 8; ++j) {
    int r = row0 + j;
    if (r < M) {
      float4 v = acc[j];
      float4* cp = reinterpret_cast<float4*>(C + (size_t)r * 128) + cg;
      if (ACC) {
        float4 c0 = *cp;
        v.x += c0.x; v.y += c0.y; v.z += c0.z; v.w += c0.w;
      } else {
        v.x += bv.x; v.y += bv.y; v.z += bv.z; v.w += bv.w;
      }
      if (ACT == ACT_RELU) {
        v.x = fmaxf(v.x, 0.f); v.y = fmaxf(v.y, 0.f);
        v.z = fmaxf(v.z, 0.f); v.w = fmaxf(v.w, 0.f);
      }
      *cp = v;
    }
  }
}

// ---------------- GATv2 aggregation: one wave per dst node, online softmax ----------------
__global__ __launch_bounds__(256) void gat_kernel(const float* __restrict__ xl,
                                                  const float* __restrict__ xr,
                                                  const float* __restrict__ att,
                                                  const float* __restrict__ gbias,
                                                  const int* __restrict__ rowptr,
                                                  const int* __restrict__ csr,
                                                  float* __restrict__ out, int n) {
  int wid = (blockIdx.x * 256 + threadIdx.x) >> 6;
  int lane = threadIdx.x & 63;
  if (wid >= n) return;
  const int d = wid;
  const float2 xrv = *reinterpret_cast<const float2*>(xr + (size_t)d * 128 + 2 * lane);
  const float2 atv = *reinterpret_cast<const float2*>(att + 2 * lane);

  float m, den;
  float2 acc;
  {  // self loop (reference appends one per node)
    const float2 xlv = *reinterpret_cast<const float2*>(xl + (size_t)d * 128 + 2 * lane);
    float t0 = xlv.x + xrv.x, t1 = xlv.y + xrv.y;
    t0 = t0 >= 0.f ? t0 : NEG_ * t0;
    t1 = t1 >= 0.f ? t1 : NEG_ * t1;
    float p = atv.x * t0 + atv.y * t1;
    p += __shfl_xor(p, 1, 64);
    p += __shfl_xor(p, 2, 64);
    p += __shfl_xor(p, 4, 64);
    m = p;
    den = 1.f;
    acc = xlv;
  }
  int beg = rowptr[d], end = rowptr[d + 1];
  for (int base = beg; base < end; base += 64) {
    int nb = end - base;
    if (nb > 64) nb = 64;
    int sl = (base + lane < end) ? csr[base + lane] : 0;
    for (int j = 0; j < nb; ++j) {
      int s = __shfl(sl, j, 64);
      const float2 xlv = *reinterpret_cast<const float2*>(xl + (size_t)s * 128 + 2 * lane);
      float t0 = xlv.x + xrv.x, t1 = xlv.y + xrv.y;
      t0 = t0 >= 0.f ? t0 : NEG_ * t0;
      t1 = t1 >= 0.f ? t1 : NEG_ * t1;
      float p = atv.x * t0 + atv.y * t1;
      p += __shfl_xor(p, 1, 64);
      p += __shfl_xor(p, 2, 64);
      p += __shfl_xor(p, 4, 64);
      float nm = fmaxf(m, p);
      float sc = expf(m - nm);
      float w = expf(p - nm);
      den = den * sc + w;
      acc.x = acc.x * sc + w * xlv.x;
      acc.y = acc.y * sc + w * xlv.y;
      m = nm;
    }
  }
  float inv = 1.f / (den + 1e-16f);
  const float2 bv = *reinterpret_cast<const float2*>(gbias + 2 * lane);
  float2 o = make_float2(acc.x * inv + bv.x, acc.y * inv + bv.y);
  *reinterpret_cast<float2*>(out + (size_t)d * 128 + 2 * lane) = o;
}

// ---------------- SAGE mean aggregation ----------------
__global__ __launch_bounds__(256) void sage_agg_kernel(const float* __restrict__ xp,
                                                       const int* __restrict__ rowptr,
                                                       const int* __restrict__ csr,
                                                       float* __restrict__ mean, int n) {
  int wid = (blockIdx.x * 256 + threadIdx.x) >> 6;
  int lane = threadIdx.x & 63;
  if (wid >= n) return;
  int beg = rowptr[wid], end = rowptr[wid + 1];
  float2 acc = make_float2(0.f, 0.f);
  for (int base = beg; base < end; base += 64) {
    int nb = end - base;
    if (nb > 64) nb = 64;
    int sl = (base + lane < end) ? csr[base + lane] : 0;
    for (int j = 0; j < nb; ++j) {
      int s = __shfl(sl, j, 64);
      const float2 v = *reinterpret_cast<const float2*>(xp + (size_t)s * 128 + 2 * lane);
      acc.x += v.x;
      acc.y += v.y;
    }
  }
  float inv = 1.f / fmaxf((float)(end - beg), 1.f);
  float2 o = make_float2(acc.x * inv, acc.y * inv);
  *reinterpret_cast<float2*>(mean + (size_t)wid * 128 + 2 * lane) = o;
}

// ---------------- LayerNorm + activation (in-place), wave per row ----------------
template <int ACT>
__global__ __launch_bounds__(256) void ln_act_kernel(float* __restrict__ x,
                                                     const float* __restrict__ g,
                                                     const float* __restrict__ b, int n) {
  int wid = (blockIdx.x * 256 + threadIdx.x) >> 6;
  int lane = threadIdx.x & 63;
  if (wid >= n) return;
  float2 v = *reinterpret_cast<const float2*>(x + (size_t)wid * 128 + 2 * lane);
  float s1 = v.x + v.y;
  float s2 = v.x * v.x + v.y * v.y;
#pragma unroll
  for (int off = 1; off < 64; off <<= 1) {
    s1 += __shfl_xor(s1, off, 64);
    s2 += __shfl_xor(s2, off, 64);
  }
  float mu = s1 * (1.f / 128.f);
  float var = s2 * (1.f / 128.f) - mu * mu;
  float rstd = rsqrtf(var + 1e-5f);
  float2 gv = *reinterpret_cast<const float2*>(g + 2 * lane);
  float2 bv = *reinterpret_cast<const float2*>(b + 2 * lane);
  float o0 = (v.x - mu) * rstd * gv.x + bv.x;
  float o1 = (v.y - mu) * rstd * gv.y + bv.y;
  if (ACT == ACT_ELU) {
    o0 = o0 > 0.f ? o0 : expm1f(o0);
    o1 = o1 > 0.f ? o1 : expm1f(o1);
  } else if (ACT == ACT_LEAKY) {
    o0 = o0 >= 0.f ? o0 : NEG_ * o0;
    o1 = o1 >= 0.f ? o1 : NEG_ * o1;
  }
  *reinterpret_cast<float2*>(x + (size_t)wid * 128 + 2 * lane) = make_float2(o0, o1);
}

// ---------------- SAGE post: L2 normalize row, then LN + leaky (in-place) ----------------
__global__ __launch_bounds__(256) void sage_post_kernel(float* __restrict__ x,
                                                        const float* __restrict__ g,
                                                        const float* __restrict__ b, int n) {
  int wid = (blockIdx.x * 256 + threadIdx.x) >> 6;
  int lane = threadIdx.x & 63;
  if (wid >= n) return;
  float2 v = *reinterpret_cast<const float2*>(x + (size_t)wid * 128 + 2 * lane);
  float s1 = v.x + v.y;
  float s2 = v.x * v.x + v.y * v.y;
#pragma unroll
  for (int off = 1; off < 64; off <<= 1) {
    s1 += __shfl_xor(s1, off, 64);
    s2 += __shfl_xor(s2, off, 64);
  }
  float nrm = sqrtf(s2);
  float inv = 1.f / fmaxf(nrm, 1e-12f);
  float mu = s1 * inv * (1.f / 128.f);
  float ex2 = s2 * inv * inv * (1.f / 128.f);
  float var = ex2 - mu * mu;
  float rstd = rsqrtf(var + 1e-5f);
  float2 gv = *reinterpret_cast<const float2*>(g + 2 * lane);
  float2 bv = *reinterpret_cast<const float2*>(b + 2 * lane);
  float o0 = (v.x * inv - mu) * rstd * gv.x + bv.x;
  float o1 = (v.y * inv - mu) * rstd * gv.y + bv.y;
  o0 = o0 >= 0.f ? o0 : NEG_ * o0;
  o1 = o1 >= 0.f ? o1 : NEG_ * o1;
  *reinterpret_cast<float2*>(x + (size_t)wid * 128 + 2 * lane) = make_float2(o0, o1);
}

// ---------------- JK max + sigmoid gate + mean-pool accumulate ----------------
__global__ __launch_bounds__(256) void jk_pool_kernel(const float* __restrict__ x0,
                                                      const float* __restrict__ x1,
                                                      const float* __restrict__ x2,
                                                      const float* __restrict__ x3,
                                                      const float* __restrict__ wap,
                                                      const float* __restrict__ bap,
                                                      const int* __restrict__ batch,
                                                      float* __restrict__ pooled,
                                                      float* __restrict__ cnt, int n) {
  int wid = (blockIdx.x * 256 + threadIdx.x) >> 6;
  int lane = threadIdx.x & 63;
  if (wid >= n) return;
  size_t off = (size_t)wid * 128 + 2 * lane;
  float2 a0 = *reinterpret_cast<const float2*>(x0 + off);
  float2 a1 = *reinterpret_cast<const float2*>(x1 + off);
  float2 a2 = *reinterpret_cast<const float2*>(x2 + off);
  float2 a3 = *reinterpret_cast<const float2*>(x3 + off);
  float2 v;
  v.x = fmaxf(fmaxf(a0.x, a1.x), fmaxf(a2.x, a3.x));
  v.y = fmaxf(fmaxf(a0.y, a1.y), fmaxf(a2.y, a3.y));
  float2 wv = *reinterpret_cast<const float2*>(wap + 2 * lane);
  float p = v.x * wv.x + v.y * wv.y;
#pragma unroll
  for (int o = 1; o < 64; o <<= 1) p += __shfl_xor(p, o, 64);
  float a = 1.f / (1.f + expf(-(p + bap[0])));
  int bg = batch[wid];
  atomicAdd(&pooled[bg * 128 + 2 * lane], v.x * a);
  atomicAdd(&pooled[bg * 128 + 2 * lane + 1], v.y * a);
  if (lane == 0) atomicAdd(&cnt[bg], 1.f);
}

// ---------------- final MLP: one block per graph ----------------
__global__ __launch_bounds__(128) void mlp_kernel(const float* __restrict__ pooled,
                                                  const float* __restrict__ cnt,
                                                  const float* __restrict__ Wc1,
                                                  const float* __restrict__ bc1,
                                                  const float* __restrict__ a1,
                                                  const float* __restrict__ Wc2,
                                                  const float* __restrict__ bc2,
                                                  const float* __restrict__ a2,
                                                  const float* __restrict__ Wc3,
                                                  const float* __restrict__ bc3,
                                                  float* __restrict__ out) {
  __shared__ float sh[128];
  __shared__ float sh2[128];
  __shared__ float sh3[64];
  int g = blockIdx.x, t = threadIdx.x;
  float inv = 1.f / fmaxf(cnt[g], 1.f);
  sh[t] = pooled[g * 128 + t] * inv;
  __syncthreads();
  float z = bc1[t];
  for (int k = 0; k < 128; ++k) z += sh[k] * Wc1[k * 128 + t];
  float al = a1[0];
  z = z >= 0.f ? z : al * z;
  sh2[t] = z;
  __syncthreads();
  if (t < 64) {
    float z2 = bc2[t];
    for (int k = 0; k < 128; ++k) z2 += sh2[k] * Wc2[k * 64 + t];
    float a2v = a2[0];
    z2 = z2 >= 0.f ? z2 : a2v * z2;
    sh3[t] = z2;
  }
  __syncthreads();
  if (t < 2) {
    float o = bc3[t];
    for (int k = 0; k < 64; ++k) o += sh3[k] * Wc3[k * 2 + t];
    out[g * 2 + t] = o;
  }
}

// ================= host =================
extern "C" void kernel_launch(void* const* d_in, const int* in_sizes, int n_in,
                              void* d_out, int out_size, void* d_ws, size_t ws_size,
                              hipStream_t stream) {
  // inputs (setup_inputs dict order)
  const float* x = (const float*)d_in[0];
  const int* ei = (const int*)d_in[1];      // [2,E]: src = ei, dst = ei+E
  const int* batch = (const int*)d_in[2];
  const float* W_in = (const float*)d_in[3];
  const float* b_in = (const float*)d_in[4];
  const float* W_res = (const float*)d_in[5];
  const float* b_res = (const float*)d_in[6];
  const float* g0_Wl = (const float*)d_in[7];
  const float* g0_bl = (const float*)d_in[8];
  const float* g0_Wr = (const float*)d_in[9];
  const float* g0_br = (const float*)d_in[10];
  const float* g0_att = (const float*)d_in[11];
  const float* g0_bias = (const float*)d_in[12];
  const float* g2_Wl = (const float*)d_in[13];
  const float* g2_bl = (const float*)d_in[14];
  const float* g2_Wr = (const float*)d_in[15];
  const float* g2_br = (const float*)d_in[16];
  const float* g2_att = (const float*)d_in[17];
  const float* g2_bias = (const float*)d_in[18];
  const float* s1_Wp = (const float*)d_in[19];
  const float* s1_bp = (const float*)d_in[20];
  const float* s1_Wl = (const float*)d_in[21];
  const float* s1_bl = (const float*)d_in[22];
  const float* s1_Wr = (const float*)d_in[23];
  const float* s3_Wp = (const float*)d_in[24];
  const float* s3_bp = (const float*)d_in[25];
  const float* s3_Wl = (const float*)d_in[26];
  const float* s3_bl = (const float*)d_in[27];
  const float* s3_Wr = (const float*)d_in[28];
  const float* ln_g = (const float*)d_in[29];
  const float* ln_b = (const float*)d_in[30];
  const float* Wap = (const float*)d_in[31];
  const float* bap = (const float*)d_in[32];
  const float* Wc1 = (const float*)d_in[33];
  const float* bc1 = (const float*)d_in[34];
  const float* a1 = (const float*)d_in[35];
  const float* Wc2 = (const float*)d_in[36];
  const float* bc2 = (const float*)d_in[37];
  const float* a2 = (const float*)d_in[38];
  const float* Wc3 = (const float*)d_in[39];
  const float* bc3 = (const float*)d_in[40];
  float* out = (float*)d_out;

  // workspace carve-up
  char* w = (char*)d_ws;
  auto alloc = [&](size_t bytes) -> void* {
    void* p = (void*)w;
    w += (bytes + 255) & ~(size_t)255;
    return p;
  };
  int* deg_cursor = (int*)alloc((size_t)N_ * 4);
  int* rowptr = (int*)alloc((size_t)(N_ + 1) * 4);
  int* bscan = (int*)alloc(256 * 4);
  int* csr = (int*)alloc((size_t)E_ * 4);
  float* Wsum = (float*)alloc((size_t)IN_ * HID_ * 4);
  float* bsumf = (float*)alloc((size_t)HID_ * 4);
  float* pooled = (float*)alloc((size_t)G_ * HID_ * 4);
  float* cntf = (float*)alloc((size_t)G_ * 4);
  size_t big = (size_t)N_ * HID_ * 4;
  float* T0 = (float*)alloc(big);
  float* T1 = (float*)alloc(big);
  float* T2 = (float*)alloc(big);
  float* B0 = (float*)alloc(big);
  float* B1 = (float*)alloc(big);
  float* B2 = (float*)alloc(big);
  float* B3 = (float*)alloc(big);

  const int EB = (E_ + 255) / 256;          // edge-grid
  const int NB256 = (N_ + 255) / 256;       // 196 scan blocks
  const int WB = (N_ + 3) / 4;              // wave-per-node grid
  const int GB = (N_ + 63) / 64;            // gemm grid (64 rows/block)

  // ---- CSR build (reused by all 4 graph layers) ----
  hipMemsetAsync(deg_cursor, 0, (size_t)N_ * 4, stream);
  hist_kernel<<<EB, 256, 0, stream>>>(ei + E_, deg_cursor, E_);
  scan1_kernel<<<NB256, 256, 0, stream>>>(deg_cursor, rowptr, bscan, N_);
  scan2_kernel<<<1, 256, 0, stream>>>(bscan, NB256);
  scan3_kernel<<<NB256, 256, 0, stream>>>(rowptr, deg_cursor, bscan, N_, E_);
  fill_kernel<<<EB, 256, 0, stream>>>(ei, ei + E_, deg_cursor, csr, E_);

  // ---- input proj: h = x @ (W_in+W_res) + (b_in+b_res) ----
  addv_kernel<<<(IN_ * HID_ + 255) / 256, 256, 0, stream>>>(W_in, W_res, Wsum, IN_ * HID_);
  addv_kernel<<<1, 256, 0, stream>>>(b_in, b_res, bsumf, HID_);
  gemm_k<64, ACT_NONE, false><<<GB, 256, 0, stream>>>(x, Wsum, bsumf, T2, N_);  // h in T2

  // ---- GAT layer 0 ----
  gemm_k<128, ACT_NONE, false><<<GB, 256, 0, stream>>>(T2, g0_Wl, g0_bl, T0, N_);  // xl
  gemm_k<128, ACT_NONE, false><<<GB, 256, 0, stream>>>(T2, g0_Wr, g0_br, T1, N_);  // xr
  gat_kernel<<<WB, 256, 0, stream>>>(T0, T1, g0_att, g0_bias, rowptr, csr, B0, N_);
  ln_act_kernel<ACT_ELU><<<WB, 256, 0, stream>>>(B0, ln_g + 0 * 128, ln_b + 0 * 128, N_);  // xs0

  // ---- SAGE layer 1 ----
  gemm_k<128, ACT_RELU, false><<<GB, 256, 0, stream>>>(B0, s1_Wp, s1_bp, T0, N_);  // xp
  sage_agg_kernel<<<WB, 256, 0, stream>>>(T0, rowptr, csr, T1, N_);               // mean
  gemm_k<128, ACT_NONE, false><<<GB, 256, 0, stream>>>(T1, s1_Wl, s1_bl, B1, N_);
  gemm_k<128, ACT_NONE, true><<<GB, 256, 0, stream>>>(B0, s1_Wr, nullptr, B1, N_);  // += xs0@Wr
  sage_post_kernel<<<WB, 256, 0, stream>>>(B1, ln_g + 1 * 128, ln_b + 1 * 128, N_);  // xs1

  // ---- GAT layer 2 ----
  gemm_k<128, ACT_NONE, false><<<GB, 256, 0, stream>>>(B1, g2_Wl, g2_bl, T0, N_);
  gemm_k<128, ACT_NONE, false><<<GB, 256, 0, stream>>>(B1, g2_Wr, g2_br, T1, N_);
  gat_kernel<<<WB, 256, 0, stream>>>(T0, T1, g2_att, g2_bias, rowptr, csr, B2, N_);
  ln_act_kernel<ACT_ELU><<<WB, 256, 0, stream>>>(B2, ln_g + 2 * 128, ln_b + 2 * 128, N_);  // xs2

  // ---- SAGE layer 3 ----
  gemm_k<128, ACT_RELU, false><<<GB, 256, 0, stream>>>(B2, s3_Wp, s3_bp, T0, N_);
  sage_agg_kernel<<<WB, 256, 0, stream>>>(T0, rowptr, csr, T1, N_);
  gemm_k<128, ACT_NONE, false><<<GB, 256, 0, stream>>>(T1, s3_Wl, s3_bl, B3, N_);
  gemm_k<128, ACT_NONE, true><<<GB, 256, 0, stream>>>(B2, s3_Wr, nullptr, B3, N_);
  sage_post_kernel<<<WB, 256, 0, stream>>>(B3, ln_g + 3 * 128, ln_b + 3 * 128, N_);  // xs3

  // ---- JK max + gate + pool + MLP ----
  hipMemsetAsync(pooled, 0, (size_t)G_ * HID_ * 4, stream);
  hipMemsetAsync(cntf, 0, (size_t)G_ * 4, stream);
  jk_pool_kernel<<<WB, 256, 0, stream>>>(B0, B1, B2, B3, Wap, bap, batch, pooled, cntf, N_);
  mlp_kernel<<<G_, 128, 0, stream>>>(pooled, cntf, Wc1, bc1, a1, Wc2, bc2, a2, Wc3, bc3, out);
}

// Round 2
// 1132.025 us; speedup vs baseline: 1.3103x; 1.3103x over previous
//
#include <hip/hip_runtime.h>
#include <math.h>

constexpr int N_ = 50000;
constexpr int E_ = 800000;
constexpr int IN_ = 64;
constexpr int HID_ = 128;
constexpr int G_ = 64;
constexpr float NEG_ = 0.2f;

// ---------------- activation tags ----------------
#define ACT_NONE 0
#define ACT_RELU 1
#define ACT_ELU 2
#define ACT_LEAKY 3

// ---------------- CSR build ----------------
__global__ __launch_bounds__(256) void hist_kernel(const int* __restrict__ dst,
                                                   int* __restrict__ deg, int e) {
  int i = blockIdx.x * 256 + threadIdx.x;
  if (i < e) atomicAdd(&deg[dst[i]], 1);
}

__global__ __launch_bounds__(256) void scan1_kernel(const int* __restrict__ deg,
                                                    int* __restrict__ excl,
                                                    int* __restrict__ bscan, int n) {
  __shared__ int sh[256];
  int t = threadIdx.x;
  int i = blockIdx.x * 256 + t;
  int v = (i < n) ? deg[i] : 0;
  sh[t] = v;
  __syncthreads();
  for (int off = 1; off < 256; off <<= 1) {
    int y = (t >= off) ? sh[t - off] : 0;
    __syncthreads();
    sh[t] += y;
    __syncthreads();
  }
  int incl = sh[t];
  if (i < n) excl[i] = incl - v;
  if (t == 255) bscan[blockIdx.x] = incl;
}

__global__ __launch_bounds__(256) void scan2_kernel(int* __restrict__ data, int nb) {
  __shared__ int sh[256];
  int t = threadIdx.x;
  int v = (t < nb) ? data[t] : 0;
  sh[t] = v;
  __syncthreads();
  for (int off = 1; off < 256; off <<= 1) {
    int y = (t >= off) ? sh[t - off] : 0;
    __syncthreads();
    sh[t] += y;
    __syncthreads();
  }
  if (t < nb) data[t] = sh[t] - v;  // exclusive
}

__global__ __launch_bounds__(256) void scan3_kernel(int* __restrict__ rowptr,
                                                    int* __restrict__ cursor,
                                                    const int* __restrict__ bscan,
                                                    int n, int e) {
  int i = blockIdx.x * 256 + threadIdx.x;
  if (i < n) {
    int v = rowptr[i] + bscan[blockIdx.x];
    rowptr[i] = v;
    cursor[i] = v;
  }
  if (i == n) rowptr[n] = e;
}

__global__ __launch_bounds__(256) void fill_kernel(const int* __restrict__ src,
                                                   const int* __restrict__ dst,
                                                   int* __restrict__ cursor,
                                                   int* __restrict__ csr, int e) {
  int i = blockIdx.x * 256 + threadIdx.x;
  if (i < e) {
    int d = dst[i];
    int p = atomicAdd(&cursor[d], 1);
    csr[p] = src[i];
  }
}

// ---------------- small elementwise add (weight prep) ----------------
__global__ __launch_bounds__(256) void addv_kernel(const float* __restrict__ a,
                                                   const float* __restrict__ b,
                                                   float* __restrict__ o, int n) {
  int i = blockIdx.x * 256 + threadIdx.x;
  if (i < n) o[i] = a[i] + b[i];
}

// ---------------- GEMM: C[M,128] = act(A[M,K] @ W[K,128] + bias), or C += A@W ----------------
template <int K, int ACT, bool ACC>
__global__ __launch_bounds__(256) void gemm_k(const float* __restrict__ A,
                                              const float* __restrict__ W,
                                              const float* __restrict__ bias,
                                              float* __restrict__ C, int M) {
  __shared__ float4 sW[K * 32];
  const int t = threadIdx.x;
  for (int i = t; i < K * 32; i += 256) {
    sW[i] = reinterpret_cast<const float4*>(W)[i];
  }
  __syncthreads();
  const int cg = t & 31;   // cols [4*cg, 4*cg+4)
  const int rg = t >> 5;   // row group 0..7
  const int row0 = blockIdx.x * 64 + rg * 8;
  float4 acc[8];
#pragma unroll
  for (int j = 0; j < 8; ++j) acc[j] = make_float4(0.f, 0.f, 0.f, 0.f);

#pragma unroll 2
  for (int k = 0; k < K; k += 4) {
    float4 w0 = sW[(k + 0) * 32 + cg];
    float4 w1 = sW[(k + 1) * 32 + cg];
    float4 w2 = sW[(k + 2) * 32 + cg];
    float4 w3 = sW[(k + 3) * 32 + cg];
#pragma unroll
    for (int j = 0; j < 8; ++j) {
      int r = row0 + j;
      if (r >= M) r = M - 1;
      float4 a = *reinterpret_cast<const float4*>(A + (size_t)r * K + k);
      acc[j].x += a.x * w0.x + a.y * w1.x + a.z * w2.x + a.w * w3.x;
      acc[j].y += a.x * w0.y + a.y * w1.y + a.z * w2.y + a.w * w3.y;
      acc[j].z += a.x * w0.z + a.y * w1.z + a.z * w2.z + a.w * w3.z;
      acc[j].w += a.x * w0.w + a.y * w1.w + a.z * w2.w + a.w * w3.w;
    }
  }

  float4 bv = make_float4(0.f, 0.f, 0.f, 0.f);
  if (!ACC) bv = reinterpret_cast<const float4*>(bias)[cg];
#pragma unroll
  for (int j = 0; j < 8; ++j) {
    int r = row0 + j;
    if (r < M) {
      float4 v = acc[j];
      float4* cp = reinterpret_cast<float4*>(C + (size_t)r * 128) + cg;
      if (ACC) {
        float4 c0 = *cp;
        v.x += c0.x; v.y += c0.y; v.z += c0.z; v.w += c0.w;
      } else {
        v.x += bv.x; v.y += bv.y; v.z += bv.z; v.w += bv.w;
      }
      if (ACT == ACT_RELU) {
        v.x = fmaxf(v.x, 0.f); v.y = fmaxf(v.y, 0.f);
        v.z = fmaxf(v.z, 0.f); v.w = fmaxf(v.w, 0.f);
      }
      *cp = v;
    }
  }
}

// ---------------- GATv2 aggregation: one wave per dst node, online softmax ----------------
__global__ __launch_bounds__(256) void gat_kernel(const float* __restrict__ xl,
                                                  const float* __restrict__ xr,
                                                  const float* __restrict__ att,
                                                  const float* __restrict__ gbias,
                                                  const int* __restrict__ rowptr,
                                                  const int* __restrict__ csr,
                                                  float* __restrict__ out, int n) {
  int wid = (blockIdx.x * 256 + threadIdx.x) >> 6;
  int lane = threadIdx.x & 63;
  if (wid >= n) return;
  const int d = wid;
  const float2 xrv = *reinterpret_cast<const float2*>(xr + (size_t)d * 128 + 2 * lane);
  const float2 atv = *reinterpret_cast<const float2*>(att + 2 * lane);

  float m, den;
  float2 acc;
  {  // self loop (reference appends one per node)
    const float2 xlv = *reinterpret_cast<const float2*>(xl + (size_t)d * 128 + 2 * lane);
    float t0 = xlv.x + xrv.x, t1 = xlv.y + xrv.y;
    t0 = t0 >= 0.f ? t0 : NEG_ * t0;
    t1 = t1 >= 0.f ? t1 : NEG_ * t1;
    float p = atv.x * t0 + atv.y * t1;
    p += __shfl_xor(p, 1, 64);
    p += __shfl_xor(p, 2, 64);
    p += __shfl_xor(p, 4, 64);
    m = p;
    den = 1.f;
    acc = xlv;
  }
  int beg = rowptr[d], end = rowptr[d + 1];
  for (int base = beg; base < end; base += 64) {
    int nb = end - base;
    if (nb > 64) nb = 64;
    int sl = (base + lane < end) ? csr[base + lane] : 0;
    for (int j = 0; j < nb; ++j) {
      int s = __shfl(sl, j, 64);
      const float2 xlv = *reinterpret_cast<const float2*>(xl + (size_t)s * 128 + 2 * lane);
      float t0 = xlv.x + xrv.x, t1 = xlv.y + xrv.y;
      t0 = t0 >= 0.f ? t0 : NEG_ * t0;
      t1 = t1 >= 0.f ? t1 : NEG_ * t1;
      float p = atv.x * t0 + atv.y * t1;
      p += __shfl_xor(p, 1, 64);
      p += __shfl_xor(p, 2, 64);
      p += __shfl_xor(p, 4, 64);
      float nm = fmaxf(m, p);
      float sc = expf(m - nm);
      float w = expf(p - nm);
      den = den * sc + w;
      acc.x = acc.x * sc + w * xlv.x;
      acc.y = acc.y * sc + w * xlv.y;
      m = nm;
    }
  }
  float inv = 1.f / (den + 1e-16f);
  const float2 bv = *reinterpret_cast<const float2*>(gbias + 2 * lane);
  float2 o = make_float2(acc.x * inv + bv.x, acc.y * inv + bv.y);
  *reinterpret_cast<float2*>(out + (size_t)d * 128 + 2 * lane) = o;
}

// ---------------- SAGE mean aggregation ----------------
__global__ __launch_bounds__(256) void sage_agg_kernel(const float* __restrict__ xp,
                                                       const int* __restrict__ rowptr,
                                                       const int* __restrict__ csr,
                                                       float* __restrict__ mean, int n) {
  int wid = (blockIdx.x * 256 + threadIdx.x) >> 6;
  int lane = threadIdx.x & 63;
  if (wid >= n) return;
  int beg = rowptr[wid], end = rowptr[wid + 1];
  float2 acc = make_float2(0.f, 0.f);
  for (int base = beg; base < end; base += 64) {
    int nb = end - base;
    if (nb > 64) nb = 64;
    int sl = (base + lane < end) ? csr[base + lane] : 0;
    for (int j = 0; j < nb; ++j) {
      int s = __shfl(sl, j, 64);
      const float2 v = *reinterpret_cast<const float2*>(xp + (size_t)s * 128 + 2 * lane);
      acc.x += v.x;
      acc.y += v.y;
    }
  }
  float inv = 1.f / fmaxf((float)(end - beg), 1.f);
  float2 o = make_float2(acc.x * inv, acc.y * inv);
  *reinterpret_cast<float2*>(mean + (size_t)wid * 128 + 2 * lane) = o;
}

// ---------------- LayerNorm + activation (in-place), wave per row ----------------
template <int ACT>
__global__ __launch_bounds__(256) void ln_act_kernel(float* __restrict__ x,
                                                     const float* __restrict__ g,
                                                     const float* __restrict__ b, int n) {
  int wid = (blockIdx.x * 256 + threadIdx.x) >> 6;
  int lane = threadIdx.x & 63;
  if (wid >= n) return;
  float2 v = *reinterpret_cast<const float2*>(x + (size_t)wid * 128 + 2 * lane);
  float s1 = v.x + v.y;
  float s2 = v.x * v.x + v.y * v.y;
#pragma unroll
  for (int off = 1; off < 64; off <<= 1) {
    s1 += __shfl_xor(s1, off, 64);
    s2 += __shfl_xor(s2, off, 64);
  }
  float mu = s1 * (1.f / 128.f);
  float var = s2 * (1.f / 128.f) - mu * mu;
  float rstd = rsqrtf(var + 1e-5f);
  float2 gv = *reinterpret_cast<const float2*>(g + 2 * lane);
  float2 bv = *reinterpret_cast<const float2*>(b + 2 * lane);
  float o0 = (v.x - mu) * rstd * gv.x + bv.x;
  float o1 = (v.y - mu) * rstd * gv.y + bv.y;
  if (ACT == ACT_ELU) {
    o0 = o0 > 0.f ? o0 : expm1f(o0);
    o1 = o1 > 0.f ? o1 : expm1f(o1);
  } else if (ACT == ACT_LEAKY) {
    o0 = o0 >= 0.f ? o0 : NEG_ * o0;
    o1 = o1 >= 0.f ? o1 : NEG_ * o1;
  }
  *reinterpret_cast<float2*>(x + (size_t)wid * 128 + 2 * lane) = make_float2(o0, o1);
}

// ---------------- SAGE post: L2 normalize row, then LN + leaky (in-place) ----------------
__global__ __launch_bounds__(256) void sage_post_kernel(float* __restrict__ x,
                                                        const float* __restrict__ g,
                                                        const float* __restrict__ b, int n) {
  int wid = (blockIdx.x * 256 + threadIdx.x) >> 6;
  int lane = threadIdx.x & 63;
  if (wid >= n) return;
  float2 v = *reinterpret_cast<const float2*>(x + (size_t)wid * 128 + 2 * lane);
  float s1 = v.x + v.y;
  float s2 = v.x * v.x + v.y * v.y;
#pragma unroll
  for (int off = 1; off < 64; off <<= 1) {
    s1 += __shfl_xor(s1, off, 64);
    s2 += __shfl_xor(s2, off, 64);
  }
  float nrm = sqrtf(s2);
  float inv = 1.f / fmaxf(nrm, 1e-12f);
  float mu = s1 * inv * (1.f / 128.f);
  float ex2 = s2 * inv * inv * (1.f / 128.f);
  float var = ex2 - mu * mu;
  float rstd = rsqrtf(var + 1e-5f);
  float2 gv = *reinterpret_cast<const float2*>(g + 2 * lane);
  float2 bv = *reinterpret_cast<const float2*>(b + 2 * lane);
  float o0 = (v.x * inv - mu) * rstd * gv.x + bv.x;
  float o1 = (v.y * inv - mu) * rstd * gv.y + bv.y;
  o0 = o0 >= 0.f ? o0 : NEG_ * o0;
  o1 = o1 >= 0.f ? o1 : NEG_ * o1;
  *reinterpret_cast<float2*>(x + (size_t)wid * 128 + 2 * lane) = make_float2(o0, o1);
}

// ---------------- JK max + sigmoid gate + mean-pool accumulate ----------------
// batch is sorted: each wave owns a contiguous chunk of nodes, keeps a running
// per-graph accumulator in registers, and flushes one atomicAdd per channel only
// at graph boundaries (~24x fewer atomics per address than node-per-wave).
__global__ __launch_bounds__(256) void jk_pool_kernel(const float* __restrict__ x0,
                                                      const float* __restrict__ x1,
                                                      const float* __restrict__ x2,
                                                      const float* __restrict__ x3,
                                                      const float* __restrict__ wap,
                                                      const float* __restrict__ bap,
                                                      const int* __restrict__ batch,
                                                      float* __restrict__ pooled,
                                                      float* __restrict__ cnt, int n,
                                                      int chunk) {
  int wid = (blockIdx.x * 256 + threadIdx.x) >> 6;
  int lane = threadIdx.x & 63;
  int start = wid * chunk;
  if (start >= n) return;
  int end = start + chunk;
  if (end > n) end = n;

  const float2 wv = *reinterpret_cast<const float2*>(wap + 2 * lane);
  const float b0 = bap[0];

  int cur = -1;
  float2 acc = make_float2(0.f, 0.f);
  float c = 0.f;

  for (int i = start; i < end; ++i) {
    size_t off = (size_t)i * 128 + 2 * lane;
    float2 a0 = *reinterpret_cast<const float2*>(x0 + off);
    float2 a1 = *reinterpret_cast<const float2*>(x1 + off);
    float2 a2 = *reinterpret_cast<const float2*>(x2 + off);
    float2 a3 = *reinterpret_cast<const float2*>(x3 + off);
    float2 v;
    v.x = fmaxf(fmaxf(a0.x, a1.x), fmaxf(a2.x, a3.x));
    v.y = fmaxf(fmaxf(a0.y, a1.y), fmaxf(a2.y, a3.y));
    float p = v.x * wv.x + v.y * wv.y;
#pragma unroll
    for (int o = 1; o < 64; o <<= 1) p += __shfl_xor(p, o, 64);
    float a = 1.f / (1.f + expf(-(p + b0)));
    int bg = batch[i];
    if (bg != cur) {
      if (cur >= 0) {
        atomicAdd(&pooled[cur * 128 + 2 * lane], acc.x);
        atomicAdd(&pooled[cur * 128 + 2 * lane + 1], acc.y);
        if (lane == 0) atomicAdd(&cnt[cur], c);
      }
      cur = bg;
      acc = make_float2(0.f, 0.f);
      c = 0.f;
    }
    acc.x += v.x * a;
    acc.y += v.y * a;
    c += 1.f;
  }
  if (cur >= 0) {
    atomicAdd(&pooled[cur * 128 + 2 * lane], acc.x);
    atomicAdd(&pooled[cur * 128 + 2 * lane + 1], acc.y);
    if (lane == 0) atomicAdd(&cnt[cur], c);
  }
}

// ---------------- final MLP: one block per graph ----------------
__global__ __launch_bounds__(128) void mlp_kernel(const float* __restrict__ pooled,
                                                  const float* __restrict__ cnt,
                                                  const float* __restrict__ Wc1,
                                                  const float* __restrict__ bc1,
                                                  const float* __restrict__ a1,
                                                  const float* __restrict__ Wc2,
                                                  const float* __restrict__ bc2,
                                                  const float* __restrict__ a2,
                                                  const float* __restrict__ Wc3,
                                                  const float* __restrict__ bc3,
                                                  float* __restrict__ out) {
  __shared__ float sh[128];
  __shared__ float sh2[128];
  __shared__ float sh3[64];
  int g = blockIdx.x, t = threadIdx.x;
  float inv = 1.f / fmaxf(cnt[g], 1.f);
  sh[t] = pooled[g * 128 + t] * inv;
  __syncthreads();
  float z = bc1[t];
  for (int k = 0; k < 128; ++k) z += sh[k] * Wc1[k * 128 + t];
  float al = a1[0];
  z = z >= 0.f ? z : al * z;
  sh2[t] = z;
  __syncthreads();
  if (t < 64) {
    float z2 = bc2[t];
    for (int k = 0; k < 128; ++k) z2 += sh2[k] * Wc2[k * 64 + t];
    float a2v = a2[0];
    z2 = z2 >= 0.f ? z2 : a2v * z2;
    sh3[t] = z2;
  }
  __syncthreads();
  if (t < 2) {
    float o = bc3[t];
    for (int k = 0; k < 64; ++k) o += sh3[k] * Wc3[k * 2 + t];
    out[g * 2 + t] = o;
  }
}

// ================= host =================
extern "C" void kernel_launch(void* const* d_in, const int* in_sizes, int n_in,
                              void* d_out, int out_size, void* d_ws, size_t ws_size,
                              hipStream_t stream) {
  // inputs (setup_inputs dict order)
  const float* x = (const float*)d_in[0];
  const int* ei = (const int*)d_in[1];      // [2,E]: src = ei, dst = ei+E
  const int* batch = (const int*)d_in[2];
  const float* W_in = (const float*)d_in[3];
  const float* b_in = (const float*)d_in[4];
  const float* W_res = (const float*)d_in[5];
  const float* b_res = (const float*)d_in[6];
  const float* g0_Wl = (const float*)d_in[7];
  const float* g0_bl = (const float*)d_in[8];
  const float* g0_Wr = (const float*)d_in[9];
  const float* g0_br = (const float*)d_in[10];
  const float* g0_att = (const float*)d_in[11];
  const float* g0_bias = (const float*)d_in[12];
  const float* g2_Wl = (const float*)d_in[13];
  const float* g2_bl = (const float*)d_in[14];
  const float* g2_Wr = (const float*)d_in[15];
  const float* g2_br = (const float*)d_in[16];
  const float* g2_att = (const float*)d_in[17];
  const float* g2_bias = (const float*)d_in[18];
  const float* s1_Wp = (const float*)d_in[19];
  const float* s1_bp = (const float*)d_in[20];
  const float* s1_Wl = (const float*)d_in[21];
  const float* s1_bl = (const float*)d_in[22];
  const float* s1_Wr = (const float*)d_in[23];
  const float* s3_Wp = (const float*)d_in[24];
  const float* s3_bp = (const float*)d_in[25];
  const float* s3_Wl = (const float*)d_in[26];
  const float* s3_bl = (const float*)d_in[27];
  const float* s3_Wr = (const float*)d_in[28];
  const float* ln_g = (const float*)d_in[29];
  const float* ln_b = (const float*)d_in[30];
  const float* Wap = (const float*)d_in[31];
  const float* bap = (const float*)d_in[32];
  const float* Wc1 = (const float*)d_in[33];
  const float* bc1 = (const float*)d_in[34];
  const float* a1 = (const float*)d_in[35];
  const float* Wc2 = (const float*)d_in[36];
  const float* bc2 = (const float*)d_in[37];
  const float* a2 = (const float*)d_in[38];
  const float* Wc3 = (const float*)d_in[39];
  const float* bc3 = (const float*)d_in[40];
  float* out = (float*)d_out;

  // workspace carve-up
  char* w = (char*)d_ws;
  auto alloc = [&](size_t bytes) -> void* {
    void* p = (void*)w;
    w += (bytes + 255) & ~(size_t)255;
    return p;
  };
  int* deg_cursor = (int*)alloc((size_t)N_ * 4);
  int* rowptr = (int*)alloc((size_t)(N_ + 1) * 4);
  int* bscan = (int*)alloc(256 * 4);
  int* csr = (int*)alloc((size_t)E_ * 4);
  float* Wsum = (float*)alloc((size_t)IN_ * HID_ * 4);
  float* bsumf = (float*)alloc((size_t)HID_ * 4);
  float* pooled = (float*)alloc((size_t)G_ * HID_ * 4);
  float* cntf = (float*)alloc((size_t)G_ * 4);
  size_t big = (size_t)N_ * HID_ * 4;
  float* T0 = (float*)alloc(big);
  float* T1 = (float*)alloc(big);
  float* T2 = (float*)alloc(big);
  float* B0 = (float*)alloc(big);
  float* B1 = (float*)alloc(big);
  float* B2 = (float*)alloc(big);
  float* B3 = (float*)alloc(big);

  const int EB = (E_ + 255) / 256;          // edge-grid
  const int NB256 = (N_ + 255) / 256;       // 196 scan blocks
  const int WB = (N_ + 3) / 4;              // wave-per-node grid
  const int GB = (N_ + 63) / 64;            // gemm grid (64 rows/block)

  // ---- CSR build (reused by all 4 graph layers) ----
  hipMemsetAsync(deg_cursor, 0, (size_t)N_ * 4, stream);
  hist_kernel<<<EB, 256, 0, stream>>>(ei + E_, deg_cursor, E_);
  scan1_kernel<<<NB256, 256, 0, stream>>>(deg_cursor, rowptr, bscan, N_);
  scan2_kernel<<<1, 256, 0, stream>>>(bscan, NB256);
  scan3_kernel<<<NB256, 256, 0, stream>>>(rowptr, deg_cursor, bscan, N_, E_);
  fill_kernel<<<EB, 256, 0, stream>>>(ei, ei + E_, deg_cursor, csr, E_);

  // ---- input proj: h = x @ (W_in+W_res) + (b_in+b_res) ----
  addv_kernel<<<(IN_ * HID_ + 255) / 256, 256, 0, stream>>>(W_in, W_res, Wsum, IN_ * HID_);
  addv_kernel<<<1, 256, 0, stream>>>(b_in, b_res, bsumf, HID_);
  gemm_k<64, ACT_NONE, false><<<GB, 256, 0, stream>>>(x, Wsum, bsumf, T2, N_);  // h in T2

  // ---- GAT layer 0 ----
  gemm_k<128, ACT_NONE, false><<<GB, 256, 0, stream>>>(T2, g0_Wl, g0_bl, T0, N_);  // xl
  gemm_k<128, ACT_NONE, false><<<GB, 256, 0, stream>>>(T2, g0_Wr, g0_br, T1, N_);  // xr
  gat_kernel<<<WB, 256, 0, stream>>>(T0, T1, g0_att, g0_bias, rowptr, csr, B0, N_);
  ln_act_kernel<ACT_ELU><<<WB, 256, 0, stream>>>(B0, ln_g + 0 * 128, ln_b + 0 * 128, N_);  // xs0

  // ---- SAGE layer 1 ----
  gemm_k<128, ACT_RELU, false><<<GB, 256, 0, stream>>>(B0, s1_Wp, s1_bp, T0, N_);  // xp
  sage_agg_kernel<<<WB, 256, 0, stream>>>(T0, rowptr, csr, T1, N_);               // mean
  gemm_k<128, ACT_NONE, false><<<GB, 256, 0, stream>>>(T1, s1_Wl, s1_bl, B1, N_);
  gemm_k<128, ACT_NONE, true><<<GB, 256, 0, stream>>>(B0, s1_Wr, nullptr, B1, N_);  // += xs0@Wr
  sage_post_kernel<<<WB, 256, 0, stream>>>(B1, ln_g + 1 * 128, ln_b + 1 * 128, N_);  // xs1

  // ---- GAT layer 2 ----
  gemm_k<128, ACT_NONE, false><<<GB, 256, 0, stream>>>(B1, g2_Wl, g2_bl, T0, N_);
  gemm_k<128, ACT_NONE, false><<<GB, 256, 0, stream>>>(B1, g2_Wr, g2_br, T1, N_);
  gat_kernel<<<WB, 256, 0, stream>>>(T0, T1, g2_att, g2_bias, rowptr, csr, B2, N_);
  ln_act_kernel<ACT_ELU><<<WB, 256, 0, stream>>>(B2, ln_g + 2 * 128, ln_b + 2 * 128, N_);  // xs2

  // ---- SAGE layer 3 ----
  gemm_k<128, ACT_RELU, false><<<GB, 256, 0, stream>>>(B2, s3_Wp, s3_bp, T0, N_);
  sage_agg_kernel<<<WB, 256, 0, stream>>>(T0, rowptr, csr, T1, N_);
  gemm_k<128, ACT_NONE, false><<<GB, 256, 0, stream>>>(T1, s3_Wl, s3_bl, B3, N_);
  gemm_k<128, ACT_NONE, true><<<GB, 256, 0, stream>>>(B2, s3_Wr, nullptr, B3, N_);
  sage_post_kernel<<<WB, 256, 0, stream>>>(B3, ln_g + 3 * 128, ln_b + 3 * 128, N_);  // xs3

  // ---- JK max + gate + pool + MLP ----
  hipMemsetAsync(pooled, 0, (size_t)G_ * HID_ * 4, stream);
  hipMemsetAsync(cntf, 0, (size_t)G_ * 4, stream);
  {
    const int chunk = 24;
    int nwaves = (N_ + chunk - 1) / chunk;
    int nblocks = (nwaves + 3) / 4;
    jk_pool_kernel<<<nblocks, 256, 0, stream>>>(B0, B1, B2, B3, Wap, bap, batch,
                                                pooled, cntf, N_, chunk);
  }
  mlp_kernel<<<G_, 128, 0, stream>>>(pooled, cntf, Wc1, bc1, a1, Wc2, bc2, a2, Wc3, bc3, out);
}

// Round 3
// 1049.606 us; speedup vs baseline: 1.4132x; 1.0785x over previous
//
#include <hip/hip_runtime.h>
#include <math.h>

constexpr int N_ = 50000;
constexpr int E_ = 800000;
constexpr int IN_ = 64;
constexpr int HID_ = 128;
constexpr int G_ = 64;
constexpr float NEG_ = 0.2f;

#define ACT_NONE 0
#define ACT_RELU 1
#define ACT_ELU 2
#define ACT_LEAKY 3

typedef _Float16 half8 __attribute__((ext_vector_type(8)));
typedef float floatx4 __attribute__((ext_vector_type(4)));

// ---------------- CSR build ----------------
__global__ __launch_bounds__(256) void hist_kernel(const int* __restrict__ dst,
                                                   int* __restrict__ deg, int e) {
  int i = blockIdx.x * 256 + threadIdx.x;
  if (i < e) atomicAdd(&deg[dst[i]], 1);
}

__global__ __launch_bounds__(256) void scan1_kernel(const int* __restrict__ deg,
                                                    int* __restrict__ excl,
                                                    int* __restrict__ bscan, int n) {
  __shared__ int sh[256];
  int t = threadIdx.x;
  int i = blockIdx.x * 256 + t;
  int v = (i < n) ? deg[i] : 0;
  sh[t] = v;
  __syncthreads();
  for (int off = 1; off < 256; off <<= 1) {
    int y = (t >= off) ? sh[t - off] : 0;
    __syncthreads();
    sh[t] += y;
    __syncthreads();
  }
  int incl = sh[t];
  if (i < n) excl[i] = incl - v;
  if (t == 255) bscan[blockIdx.x] = incl;
}

__global__ __launch_bounds__(256) void scan2_kernel(int* __restrict__ data, int nb) {
  __shared__ int sh[256];
  int t = threadIdx.x;
  int v = (t < nb) ? data[t] : 0;
  sh[t] = v;
  __syncthreads();
  for (int off = 1; off < 256; off <<= 1) {
    int y = (t >= off) ? sh[t - off] : 0;
    __syncthreads();
    sh[t] += y;
    __syncthreads();
  }
  if (t < nb) data[t] = sh[t] - v;  // exclusive
}

__global__ __launch_bounds__(256) void scan3_kernel(int* __restrict__ rowptr,
                                                    int* __restrict__ cursor,
                                                    const int* __restrict__ bscan,
                                                    int n, int e) {
  int i = blockIdx.x * 256 + threadIdx.x;
  if (i < n) {
    int v = rowptr[i] + bscan[blockIdx.x];
    rowptr[i] = v;
    cursor[i] = v;
  }
  if (i == n) rowptr[n] = e;
}

__global__ __launch_bounds__(256) void fill_kernel(const int* __restrict__ src,
                                                   const int* __restrict__ dst,
                                                   int* __restrict__ cursor,
                                                   int* __restrict__ csr, int e) {
  int i = blockIdx.x * 256 + threadIdx.x;
  if (i < e) {
    int d = dst[i];
    int p = atomicAdd(&cursor[d], 1);
    csr[p] = src[i];
  }
}

// ---------------- bias sum ----------------
__global__ __launch_bounds__(256) void addv_kernel(const float* __restrict__ a,
                                                   const float* __restrict__ b,
                                                   float* __restrict__ o, int n) {
  int i = blockIdx.x * 256 + threadIdx.x;
  if (i < n) o[i] = a[i] + b[i];
}

// ---------------- weight prep: transpose + fp16 hi/lo split ----------------
// dst layout (_Float16): [0,8192) WsumT_hi [128n][64k]; [8192,16384) WsumT_lo;
// then for j in 0..9: base=16384+j*32768: hi [128n][128k], lo at base+16384.
__global__ __launch_bounds__(256) void prep_w_kernel(
    const float* __restrict__ W_in, const float* __restrict__ W_res,
    const float* __restrict__ m0, const float* __restrict__ m1,
    const float* __restrict__ m2, const float* __restrict__ m3,
    const float* __restrict__ m4, const float* __restrict__ m5,
    const float* __restrict__ m6, const float* __restrict__ m7,
    const float* __restrict__ m8, const float* __restrict__ m9,
    _Float16* __restrict__ dst) {
  int idx = blockIdx.x * 256 + threadIdx.x;
  if (idx < 8192) {
    int n = idx >> 6, k = idx & 63;
    float v = W_in[k * 128 + n] + W_res[k * 128 + n];
    _Float16 h = (_Float16)v;
    dst[idx] = h;
    dst[8192 + idx] = (_Float16)(v - (float)h);
  } else if (idx < 8192 + 10 * 16384) {
    int r = idx - 8192;
    int j = r >> 14;
    int e = r & 16383;
    int n = e >> 7, k = e & 127;
    const float* S;
    switch (j) {
      case 0: S = m0; break; case 1: S = m1; break; case 2: S = m2; break;
      case 3: S = m3; break; case 4: S = m4; break; case 5: S = m5; break;
      case 6: S = m6; break; case 7: S = m7; break; case 8: S = m8; break;
      default: S = m9; break;
    }
    float v = S[k * 128 + n];
    _Float16 h = (_Float16)v;
    _Float16* base = dst + 16384 + j * 32768;
    base[e] = h;                       // e == n*128+k
    base[16384 + e] = (_Float16)(v - (float)h);
  }
}

// ---------------- MFMA GEMM: C[M,128] = act(A[M,K1]@W + (A2@W2) + bias) ----------------
// W given transposed+split: Wh/Wl are [128][K] f16 (row = output col n).
// fp16x2 split of A done in-register; 3 MFMAs per tile (AhWh + AhWl + AlWh).
__device__ inline void split8(const float* __restrict__ p, half8& h, half8& l) {
  float4 a = *reinterpret_cast<const float4*>(p);
  float4 b = *reinterpret_cast<const float4*>(p + 4);
  float v0 = a.x, v1 = a.y, v2 = a.z, v3 = a.w;
  float v4 = b.x, v5 = b.y, v6 = b.z, v7 = b.w;
  _Float16 h0 = (_Float16)v0, h1 = (_Float16)v1, h2 = (_Float16)v2, h3 = (_Float16)v3;
  _Float16 h4 = (_Float16)v4, h5 = (_Float16)v5, h6 = (_Float16)v6, h7 = (_Float16)v7;
  h[0] = h0; h[1] = h1; h[2] = h2; h[3] = h3; h[4] = h4; h[5] = h5; h[6] = h6; h[7] = h7;
  l[0] = (_Float16)(v0 - (float)h0); l[1] = (_Float16)(v1 - (float)h1);
  l[2] = (_Float16)(v2 - (float)h2); l[3] = (_Float16)(v3 - (float)h3);
  l[4] = (_Float16)(v4 - (float)h4); l[5] = (_Float16)(v5 - (float)h5);
  l[6] = (_Float16)(v6 - (float)h6); l[7] = (_Float16)(v7 - (float)h7);
}

template <int K1, int ACT, bool DUAL>
__global__ __launch_bounds__(256) void gemm16(const float* __restrict__ A,
                                              const _Float16* __restrict__ Wh,
                                              const _Float16* __restrict__ Wl,
                                              const float* __restrict__ A2,
                                              const _Float16* __restrict__ W2h,
                                              const _Float16* __restrict__ W2l,
                                              const float* __restrict__ bias,
                                              float* __restrict__ C, int M) {
  const int t = threadIdx.x;
  const int wave = t >> 6, lane = t & 63;
  const int quad = lane >> 4, l16 = lane & 15;
  const int r0 = blockIdx.x * 64 + wave * 16;
  int arow = r0 + l16;
  if (arow >= M) arow = M - 1;

  floatx4 acc[8];
#pragma unroll
  for (int i = 0; i < 8; ++i) acc[i] = (floatx4){0.f, 0.f, 0.f, 0.f};

#pragma unroll
  for (int kk = 0; kk < K1; kk += 32) {
    half8 ah, al;
    split8(A + (size_t)arow * K1 + kk + quad * 8, ah, al);
#pragma unroll
    for (int nt = 0; nt < 8; ++nt) {
      size_t woff = (size_t)(nt * 16 + l16) * K1 + kk + quad * 8;
      half8 wh = *reinterpret_cast<const half8*>(Wh + woff);
      half8 wl = *reinterpret_cast<const half8*>(Wl + woff);
      acc[nt] = __builtin_amdgcn_mfma_f32_16x16x32_f16(ah, wh, acc[nt], 0, 0, 0);
      acc[nt] = __builtin_amdgcn_mfma_f32_16x16x32_f16(ah, wl, acc[nt], 0, 0, 0);
      acc[nt] = __builtin_amdgcn_mfma_f32_16x16x32_f16(al, wh, acc[nt], 0, 0, 0);
    }
  }
  if (DUAL) {
#pragma unroll
    for (int kk = 0; kk < 128; kk += 32) {
      half8 ah, al;
      split8(A2 + (size_t)arow * 128 + kk + quad * 8, ah, al);
#pragma unroll
      for (int nt = 0; nt < 8; ++nt) {
        size_t woff = (size_t)(nt * 16 + l16) * 128 + kk + quad * 8;
        half8 wh = *reinterpret_cast<const half8*>(W2h + woff);
        half8 wl = *reinterpret_cast<const half8*>(W2l + woff);
        acc[nt] = __builtin_amdgcn_mfma_f32_16x16x32_f16(ah, wh, acc[nt], 0, 0, 0);
        acc[nt] = __builtin_amdgcn_mfma_f32_16x16x32_f16(ah, wl, acc[nt], 0, 0, 0);
        acc[nt] = __builtin_amdgcn_mfma_f32_16x16x32_f16(al, wh, acc[nt], 0, 0, 0);
      }
    }
  }

#pragma unroll
  for (int nt = 0; nt < 8; ++nt) {
    float b = bias[nt * 16 + l16];
#pragma unroll
    for (int reg = 0; reg < 4; ++reg) {
      int r = r0 + quad * 4 + reg;
      if (r < M) {
        float v = acc[nt][reg] + b;
        if (ACT == ACT_RELU) v = fmaxf(v, 0.f);
        C[(size_t)r * 128 + nt * 16 + l16] = v;
      }
    }
  }
}

// ---------------- GATv2 aggregation: one wave per dst node, online softmax ----------------
__global__ __launch_bounds__(256) void gat_kernel(const float* __restrict__ xl,
                                                  const float* __restrict__ xr,
                                                  const float* __restrict__ att,
                                                  const float* __restrict__ gbias,
                                                  const int* __restrict__ rowptr,
                                                  const int* __restrict__ csr,
                                                  float* __restrict__ out, int n) {
  int wid = (blockIdx.x * 256 + threadIdx.x) >> 6;
  int lane = threadIdx.x & 63;
  if (wid >= n) return;
  const int d = wid;
  const float2 xrv = *reinterpret_cast<const float2*>(xr + (size_t)d * 128 + 2 * lane);
  const float2 atv = *reinterpret_cast<const float2*>(att + 2 * lane);

  float m, den;
  float2 acc;
  {  // self loop
    const float2 xlv = *reinterpret_cast<const float2*>(xl + (size_t)d * 128 + 2 * lane);
    float t0 = xlv.x + xrv.x, t1 = xlv.y + xrv.y;
    t0 = t0 >= 0.f ? t0 : NEG_ * t0;
    t1 = t1 >= 0.f ? t1 : NEG_ * t1;
    float p = atv.x * t0 + atv.y * t1;
    p += __shfl_xor(p, 1, 64);
    p += __shfl_xor(p, 2, 64);
    p += __shfl_xor(p, 4, 64);
    m = p;
    den = 1.f;
    acc = xlv;
  }
  int beg = rowptr[d], end = rowptr[d + 1];
  for (int base = beg; base < end; base += 64) {
    int nb = end - base;
    if (nb > 64) nb = 64;
    int sl = (base + lane < end) ? csr[base + lane] : 0;
    for (int j = 0; j < nb; ++j) {
      int s = __shfl(sl, j, 64);
      const float2 xlv = *reinterpret_cast<const float2*>(xl + (size_t)s * 128 + 2 * lane);
      float t0 = xlv.x + xrv.x, t1 = xlv.y + xrv.y;
      t0 = t0 >= 0.f ? t0 : NEG_ * t0;
      t1 = t1 >= 0.f ? t1 : NEG_ * t1;
      float p = atv.x * t0 + atv.y * t1;
      p += __shfl_xor(p, 1, 64);
      p += __shfl_xor(p, 2, 64);
      p += __shfl_xor(p, 4, 64);
      float nm = fmaxf(m, p);
      float sc = expf(m - nm);
      float w = expf(p - nm);
      den = den * sc + w;
      acc.x = acc.x * sc + w * xlv.x;
      acc.y = acc.y * sc + w * xlv.y;
      m = nm;
    }
  }
  float inv = 1.f / (den + 1e-16f);
  const float2 bv = *reinterpret_cast<const float2*>(gbias + 2 * lane);
  float2 o = make_float2(acc.x * inv + bv.x, acc.y * inv + bv.y);
  *reinterpret_cast<float2*>(out + (size_t)d * 128 + 2 * lane) = o;
}

// ---------------- SAGE mean aggregation ----------------
__global__ __launch_bounds__(256) void sage_agg_kernel(const float* __restrict__ xp,
                                                       const int* __restrict__ rowptr,
                                                       const int* __restrict__ csr,
                                                       float* __restrict__ mean, int n) {
  int wid = (blockIdx.x * 256 + threadIdx.x) >> 6;
  int lane = threadIdx.x & 63;
  if (wid >= n) return;
  int beg = rowptr[wid], end = rowptr[wid + 1];
  float2 acc = make_float2(0.f, 0.f);
  for (int base = beg; base < end; base += 64) {
    int nb = end - base;
    if (nb > 64) nb = 64;
    int sl = (base + lane < end) ? csr[base + lane] : 0;
    for (int j = 0; j < nb; ++j) {
      int s = __shfl(sl, j, 64);
      const float2 v = *reinterpret_cast<const float2*>(xp + (size_t)s * 128 + 2 * lane);
      acc.x += v.x;
      acc.y += v.y;
    }
  }
  float inv = 1.f / fmaxf((float)(end - beg), 1.f);
  float2 o = make_float2(acc.x * inv, acc.y * inv);
  *reinterpret_cast<float2*>(mean + (size_t)wid * 128 + 2 * lane) = o;
}

// ---------------- LayerNorm + activation (in-place), wave per row ----------------
template <int ACT>
__global__ __launch_bounds__(256) void ln_act_kernel(float* __restrict__ x,
                                                     const float* __restrict__ g,
                                                     const float* __restrict__ b, int n) {
  int wid = (blockIdx.x * 256 + threadIdx.x) >> 6;
  int lane = threadIdx.x & 63;
  if (wid >= n) return;
  float2 v = *reinterpret_cast<const float2*>(x + (size_t)wid * 128 + 2 * lane);
  float s1 = v.x + v.y;
  float s2 = v.x * v.x + v.y * v.y;
#pragma unroll
  for (int off = 1; off < 64; off <<= 1) {
    s1 += __shfl_xor(s1, off, 64);
    s2 += __shfl_xor(s2, off, 64);
  }
  float mu = s1 * (1.f / 128.f);
  float var = s2 * (1.f / 128.f) - mu * mu;
  float rstd = rsqrtf(var + 1e-5f);
  float2 gv = *reinterpret_cast<const float2*>(g + 2 * lane);
  float2 bv = *reinterpret_cast<const float2*>(b + 2 * lane);
  float o0 = (v.x - mu) * rstd * gv.x + bv.x;
  float o1 = (v.y - mu) * rstd * gv.y + bv.y;
  if (ACT == ACT_ELU) {
    o0 = o0 > 0.f ? o0 : expm1f(o0);
    o1 = o1 > 0.f ? o1 : expm1f(o1);
  } else if (ACT == ACT_LEAKY) {
    o0 = o0 >= 0.f ? o0 : NEG_ * o0;
    o1 = o1 >= 0.f ? o1 : NEG_ * o1;
  }
  *reinterpret_cast<float2*>(x + (size_t)wid * 128 + 2 * lane) = make_float2(o0, o1);
}

// ---------------- SAGE post: L2 normalize row, then LN + leaky (in-place) ----------------
__global__ __launch_bounds__(256) void sage_post_kernel(float* __restrict__ x,
                                                        const float* __restrict__ g,
                                                        const float* __restrict__ b, int n) {
  int wid = (blockIdx.x * 256 + threadIdx.x) >> 6;
  int lane = threadIdx.x & 63;
  if (wid >= n) return;
  float2 v = *reinterpret_cast<const float2*>(x + (size_t)wid * 128 + 2 * lane);
  float s1 = v.x + v.y;
  float s2 = v.x * v.x + v.y * v.y;
#pragma unroll
  for (int off = 1; off < 64; off <<= 1) {
    s1 += __shfl_xor(s1, off, 64);
    s2 += __shfl_xor(s2, off, 64);
  }
  float nrm = sqrtf(s2);
  float inv = 1.f / fmaxf(nrm, 1e-12f);
  float mu = s1 * inv * (1.f / 128.f);
  float ex2 = s2 * inv * inv * (1.f / 128.f);
  float var = ex2 - mu * mu;
  float rstd = rsqrtf(var + 1e-5f);
  float2 gv = *reinterpret_cast<const float2*>(g + 2 * lane);
  float2 bv = *reinterpret_cast<const float2*>(b + 2 * lane);
  float o0 = (v.x * inv - mu) * rstd * gv.x + bv.x;
  float o1 = (v.y * inv - mu) * rstd * gv.y + bv.y;
  o0 = o0 >= 0.f ? o0 : NEG_ * o0;
  o1 = o1 >= 0.f ? o1 : NEG_ * o1;
  *reinterpret_cast<float2*>(x + (size_t)wid * 128 + 2 * lane) = make_float2(o0, o1);
}

// ---------------- JK max + sigmoid gate + mean-pool (chunked, few atomics) ----------------
__global__ __launch_bounds__(256) void jk_pool_kernel(const float* __restrict__ x0,
                                                      const float* __restrict__ x1,
                                                      const float* __restrict__ x2,
                                                      const float* __restrict__ x3,
                                                      const float* __restrict__ wap,
                                                      const float* __restrict__ bap,
                                                      const int* __restrict__ batch,
                                                      float* __restrict__ pooled,
                                                      float* __restrict__ cnt, int n,
                                                      int chunk) {
  int wid = (blockIdx.x * 256 + threadIdx.x) >> 6;
  int lane = threadIdx.x & 63;
  int start = wid * chunk;
  if (start >= n) return;
  int end = start + chunk;
  if (end > n) end = n;

  const float2 wv = *reinterpret_cast<const float2*>(wap + 2 * lane);
  const float b0 = bap[0];

  int cur = -1;
  float2 acc = make_float2(0.f, 0.f);
  float c = 0.f;

  for (int i = start; i < end; ++i) {
    size_t off = (size_t)i * 128 + 2 * lane;
    float2 a0 = *reinterpret_cast<const float2*>(x0 + off);
    float2 a1 = *reinterpret_cast<const float2*>(x1 + off);
    float2 a2 = *reinterpret_cast<const float2*>(x2 + off);
    float2 a3 = *reinterpret_cast<const float2*>(x3 + off);
    float2 v;
    v.x = fmaxf(fmaxf(a0.x, a1.x), fmaxf(a2.x, a3.x));
    v.y = fmaxf(fmaxf(a0.y, a1.y), fmaxf(a2.y, a3.y));
    float p = v.x * wv.x + v.y * wv.y;
#pragma unroll
    for (int o = 1; o < 64; o <<= 1) p += __shfl_xor(p, o, 64);
    float a = 1.f / (1.f + expf(-(p + b0)));
    int bg = batch[i];
    if (bg != cur) {
      if (cur >= 0) {
        atomicAdd(&pooled[cur * 128 + 2 * lane], acc.x);
        atomicAdd(&pooled[cur * 128 + 2 * lane + 1], acc.y);
        if (lane == 0) atomicAdd(&cnt[cur], c);
      }
      cur = bg;
      acc = make_float2(0.f, 0.f);
      c = 0.f;
    }
    acc.x += v.x * a;
    acc.y += v.y * a;
    c += 1.f;
  }
  if (cur >= 0) {
    atomicAdd(&pooled[cur * 128 + 2 * lane], acc.x);
    atomicAdd(&pooled[cur * 128 + 2 * lane + 1], acc.y);
    if (lane == 0) atomicAdd(&cnt[cur], c);
  }
}

// ---------------- final MLP: one block per graph ----------------
__global__ __launch_bounds__(128) void mlp_kernel(const float* __restrict__ pooled,
                                                  const float* __restrict__ cnt,
                                                  const float* __restrict__ Wc1,
                                                  const float* __restrict__ bc1,
                                                  const float* __restrict__ a1,
                                                  const float* __restrict__ Wc2,
                                                  const float* __restrict__ bc2,
                                                  const float* __restrict__ a2,
                                                  const float* __restrict__ Wc3,
                                                  const float* __restrict__ bc3,
                                                  float* __restrict__ out) {
  __shared__ float sh[128];
  __shared__ float sh2[128];
  __shared__ float sh3[64];
  int g = blockIdx.x, t = threadIdx.x;
  float inv = 1.f / fmaxf(cnt[g], 1.f);
  sh[t] = pooled[g * 128 + t] * inv;
  __syncthreads();
  float z = bc1[t];
  for (int k = 0; k < 128; ++k) z += sh[k] * Wc1[k * 128 + t];
  float al = a1[0];
  z = z >= 0.f ? z : al * z;
  sh2[t] = z;
  __syncthreads();
  if (t < 64) {
    float z2 = bc2[t];
    for (int k = 0; k < 128; ++k) z2 += sh2[k] * Wc2[k * 64 + t];
    float a2v = a2[0];
    z2 = z2 >= 0.f ? z2 : a2v * z2;
    sh3[t] = z2;
  }
  __syncthreads();
  if (t < 2) {
    float o = bc3[t];
    for (int k = 0; k < 64; ++k) o += sh3[k] * Wc3[k * 2 + t];
    out[g * 2 + t] = o;
  }
}

// ================= host =================
extern "C" void kernel_launch(void* const* d_in, const int* in_sizes, int n_in,
                              void* d_out, int out_size, void* d_ws, size_t ws_size,
                              hipStream_t stream) {
  const float* x = (const float*)d_in[0];
  const int* ei = (const int*)d_in[1];
  const int* batch = (const int*)d_in[2];
  const float* W_in = (const float*)d_in[3];
  const float* b_in = (const float*)d_in[4];
  const float* W_res = (const float*)d_in[5];
  const float* b_res = (const float*)d_in[6];
  const float* g0_Wl = (const float*)d_in[7];
  const float* g0_bl = (const float*)d_in[8];
  const float* g0_Wr = (const float*)d_in[9];
  const float* g0_br = (const float*)d_in[10];
  const float* g0_att = (const float*)d_in[11];
  const float* g0_bias = (const float*)d_in[12];
  const float* g2_Wl = (const float*)d_in[13];
  const float* g2_bl = (const float*)d_in[14];
  const float* g2_Wr = (const float*)d_in[15];
  const float* g2_br = (const float*)d_in[16];
  const float* g2_att = (const float*)d_in[17];
  const float* g2_bias = (const float*)d_in[18];
  const float* s1_Wp = (const float*)d_in[19];
  const float* s1_bp = (const float*)d_in[20];
  const float* s1_Wl = (const float*)d_in[21];
  const float* s1_bl = (const float*)d_in[22];
  const float* s1_Wr = (const float*)d_in[23];
  const float* s3_Wp = (const float*)d_in[24];
  const float* s3_bp = (const float*)d_in[25];
  const float* s3_Wl = (const float*)d_in[26];
  const float* s3_bl = (const float*)d_in[27];
  const float* s3_Wr = (const float*)d_in[28];
  const float* ln_g = (const float*)d_in[29];
  const float* ln_b = (const float*)d_in[30];
  const float* Wap = (const float*)d_in[31];
  const float* bap = (const float*)d_in[32];
  const float* Wc1 = (const float*)d_in[33];
  const float* bc1 = (const float*)d_in[34];
  const float* a1 = (const float*)d_in[35];
  const float* Wc2 = (const float*)d_in[36];
  const float* bc2 = (const float*)d_in[37];
  const float* a2 = (const float*)d_in[38];
  const float* Wc3 = (const float*)d_in[39];
  const float* bc3 = (const float*)d_in[40];
  float* out = (float*)d_out;

  char* w = (char*)d_ws;
  auto alloc = [&](size_t bytes) -> void* {
    void* p = (void*)w;
    w += (bytes + 255) & ~(size_t)255;
    return p;
  };
  int* deg_cursor = (int*)alloc((size_t)N_ * 4);
  int* rowptr = (int*)alloc((size_t)(N_ + 1) * 4);
  int* bscan = (int*)alloc(256 * 4);
  int* csr = (int*)alloc((size_t)E_ * 4);
  float* bsumf = (float*)alloc((size_t)HID_ * 4);
  float* pooled = (float*)alloc((size_t)G_ * HID_ * 4);
  float* cntf = (float*)alloc((size_t)G_ * 4);
  _Float16* wsp = (_Float16*)alloc((size_t)(16384 + 10 * 32768) * 2);  // split+transposed weights
  size_t big = (size_t)N_ * HID_ * 4;
  float* T0 = (float*)alloc(big);
  float* T1 = (float*)alloc(big);
  float* T2 = (float*)alloc(big);
  float* B0 = (float*)alloc(big);
  float* B1 = (float*)alloc(big);
  float* B2 = (float*)alloc(big);
  float* B3 = (float*)alloc(big);

  const _Float16* WsT_h = wsp;
  const _Float16* WsT_l = wsp + 8192;
  auto WTh = [&](int j) { return (const _Float16*)(wsp + 16384 + j * 32768); };
  auto WTl = [&](int j) { return (const _Float16*)(wsp + 16384 + j * 32768 + 16384); };
  // j: 0 g0_Wl, 1 g0_Wr, 2 s1_Wp, 3 s1_Wl, 4 s1_Wr, 5 g2_Wl, 6 g2_Wr, 7 s3_Wp, 8 s3_Wl, 9 s3_Wr

  const int EB = (E_ + 255) / 256;
  const int NB256 = (N_ + 255) / 256;
  const int WB = (N_ + 3) / 4;
  const int GB = (N_ + 63) / 64;

  // ---- CSR build ----
  hipMemsetAsync(deg_cursor, 0, (size_t)N_ * 4, stream);
  hist_kernel<<<EB, 256, 0, stream>>>(ei + E_, deg_cursor, E_);
  scan1_kernel<<<NB256, 256, 0, stream>>>(deg_cursor, rowptr, bscan, N_);
  scan2_kernel<<<1, 256, 0, stream>>>(bscan, NB256);
  scan3_kernel<<<NB256, 256, 0, stream>>>(rowptr, deg_cursor, bscan, N_, E_);
  fill_kernel<<<EB, 256, 0, stream>>>(ei, ei + E_, deg_cursor, csr, E_);

  // ---- weight prep ----
  prep_w_kernel<<<(8192 + 10 * 16384 + 255) / 256, 256, 0, stream>>>(
      W_in, W_res, g0_Wl, g0_Wr, s1_Wp, s1_Wl, s1_Wr, g2_Wl, g2_Wr, s3_Wp, s3_Wl, s3_Wr, wsp);
  addv_kernel<<<1, 256, 0, stream>>>(b_in, b_res, bsumf, HID_);

  // ---- input proj: h = x @ (W_in+W_res) + bsum  -> T2 ----
  gemm16<64, ACT_NONE, false><<<GB, 256, 0, stream>>>(x, WsT_h, WsT_l, nullptr, nullptr,
                                                      nullptr, bsumf, T2, N_);

  // ---- GAT layer 0 ----
  gemm16<128, ACT_NONE, false><<<GB, 256, 0, stream>>>(T2, WTh(0), WTl(0), nullptr, nullptr,
                                                       nullptr, g0_bl, T0, N_);
  gemm16<128, ACT_NONE, false><<<GB, 256, 0, stream>>>(T2, WTh(1), WTl(1), nullptr, nullptr,
                                                       nullptr, g0_br, T1, N_);
  gat_kernel<<<WB, 256, 0, stream>>>(T0, T1, g0_att, g0_bias, rowptr, csr, B0, N_);
  ln_act_kernel<ACT_ELU><<<WB, 256, 0, stream>>>(B0, ln_g + 0 * 128, ln_b + 0 * 128, N_);

  // ---- SAGE layer 1 ----
  gemm16<128, ACT_RELU, false><<<GB, 256, 0, stream>>>(B0, WTh(2), WTl(2), nullptr, nullptr,
                                                       nullptr, s1_bp, T0, N_);  // xp
  sage_agg_kernel<<<WB, 256, 0, stream>>>(T0, rowptr, csr, T1, N_);              // mean
  gemm16<128, ACT_NONE, true><<<GB, 256, 0, stream>>>(T1, WTh(3), WTl(3), B0, WTh(4), WTl(4),
                                                      s1_bl, B1, N_);  // mean@Wl + xs0@Wr
  sage_post_kernel<<<WB, 256, 0, stream>>>(B1, ln_g + 1 * 128, ln_b + 1 * 128, N_);

  // ---- GAT layer 2 ----
  gemm16<128, ACT_NONE, false><<<GB, 256, 0, stream>>>(B1, WTh(5), WTl(5), nullptr, nullptr,
                                                       nullptr, g2_bl, T0, N_);
  gemm16<128, ACT_NONE, false><<<GB, 256, 0, stream>>>(B1, WTh(6), WTl(6), nullptr, nullptr,
                                                       nullptr, g2_br, T1, N_);
  gat_kernel<<<WB, 256, 0, stream>>>(T0, T1, g2_att, g2_bias, rowptr, csr, B2, N_);
  ln_act_kernel<ACT_ELU><<<WB, 256, 0, stream>>>(B2, ln_g + 2 * 128, ln_b + 2 * 128, N_);

  // ---- SAGE layer 3 ----
  gemm16<128, ACT_RELU, false><<<GB, 256, 0, stream>>>(B2, WTh(7), WTl(7), nullptr, nullptr,
                                                       nullptr, s3_bp, T0, N_);
  sage_agg_kernel<<<WB, 256, 0, stream>>>(T0, rowptr, csr, T1, N_);
  gemm16<128, ACT_NONE, true><<<GB, 256, 0, stream>>>(T1, WTh(8), WTl(8), B2, WTh(9), WTl(9),
                                                      s3_bl, B3, N_);
  sage_post_kernel<<<WB, 256, 0, stream>>>(B3, ln_g + 3 * 128, ln_b + 3 * 128, N_);

  // ---- JK max + gate + pool + MLP ----
  hipMemsetAsync(pooled, 0, (size_t)G_ * HID_ * 4, stream);
  hipMemsetAsync(cntf, 0, (size_t)G_ * 4, stream);
  {
    const int chunk = 24;
    int nwaves = (N_ + chunk - 1) / chunk;
    int nblocks = (nwaves + 3) / 4;
    jk_pool_kernel<<<nblocks, 256, 0, stream>>>(B0, B1, B2, B3, Wap, bap, batch,
                                                pooled, cntf, N_, chunk);
  }
  mlp_kernel<<<G_, 128, 0, stream>>>(pooled, cntf, Wc1, bc1, a1, Wc2, bc2, a2, Wc3, bc3, out);
}

// Round 4
// 1013.608 us; speedup vs baseline: 1.4634x; 1.0355x over previous
//
#include <hip/hip_runtime.h>
#include <math.h>

constexpr int N_ = 50000;
constexpr int E_ = 800000;
constexpr int IN_ = 64;
constexpr int HID_ = 128;
constexpr int G_ = 64;
constexpr float NEG_ = 0.2f;
constexpr float LOG2E_ = 1.44269504088896340736f;

#define ACT_NONE 0
#define ACT_RELU 1
#define ACT_ELU 2
#define ACT_LEAKY 3

typedef _Float16 half8 __attribute__((ext_vector_type(8)));
typedef float floatx4 __attribute__((ext_vector_type(4)));

// ---------------- CSR build ----------------
__global__ __launch_bounds__(256) void hist_kernel(const int* __restrict__ dst,
                                                   int* __restrict__ deg, int e) {
  int i = blockIdx.x * 256 + threadIdx.x;
  if (i < e) atomicAdd(&deg[dst[i]], 1);
}

__global__ __launch_bounds__(256) void scan1_kernel(const int* __restrict__ deg,
                                                    int* __restrict__ excl,
                                                    int* __restrict__ bscan, int n) {
  __shared__ int sh[256];
  int t = threadIdx.x;
  int i = blockIdx.x * 256 + t;
  int v = (i < n) ? deg[i] : 0;
  sh[t] = v;
  __syncthreads();
  for (int off = 1; off < 256; off <<= 1) {
    int y = (t >= off) ? sh[t - off] : 0;
    __syncthreads();
    sh[t] += y;
    __syncthreads();
  }
  int incl = sh[t];
  if (i < n) excl[i] = incl - v;
  if (t == 255) bscan[blockIdx.x] = incl;
}

__global__ __launch_bounds__(256) void scan2_kernel(int* __restrict__ data, int nb) {
  __shared__ int sh[256];
  int t = threadIdx.x;
  int v = (t < nb) ? data[t] : 0;
  sh[t] = v;
  __syncthreads();
  for (int off = 1; off < 256; off <<= 1) {
    int y = (t >= off) ? sh[t - off] : 0;
    __syncthreads();
    sh[t] += y;
    __syncthreads();
  }
  if (t < nb) data[t] = sh[t] - v;  // exclusive
}

__global__ __launch_bounds__(256) void scan3_kernel(int* __restrict__ rowptr,
                                                    int* __restrict__ cursor,
                                                    const int* __restrict__ bscan,
                                                    int n, int e) {
  int i = blockIdx.x * 256 + threadIdx.x;
  if (i < n) {
    int v = rowptr[i] + bscan[blockIdx.x];
    rowptr[i] = v;
    cursor[i] = v;
  }
  if (i == n) rowptr[n] = e;
}

__global__ __launch_bounds__(256) void fill_kernel(const int* __restrict__ src,
                                                   const int* __restrict__ dst,
                                                   int* __restrict__ cursor,
                                                   int* __restrict__ csr, int e) {
  int i = blockIdx.x * 256 + threadIdx.x;
  if (i < e) {
    int d = dst[i];
    int p = atomicAdd(&cursor[d], 1);
    csr[p] = src[i];
  }
}

// ---------------- bias sum ----------------
__global__ __launch_bounds__(256) void addv_kernel(const float* __restrict__ a,
                                                   const float* __restrict__ b,
                                                   float* __restrict__ o, int n) {
  int i = blockIdx.x * 256 + threadIdx.x;
  if (i < n) o[i] = a[i] + b[i];
}

// ---------------- weight prep: transpose + fp16 hi/lo split ----------------
__global__ __launch_bounds__(256) void prep_w_kernel(
    const float* __restrict__ W_in, const float* __restrict__ W_res,
    const float* __restrict__ m0, const float* __restrict__ m1,
    const float* __restrict__ m2, const float* __restrict__ m3,
    const float* __restrict__ m4, const float* __restrict__ m5,
    const float* __restrict__ m6, const float* __restrict__ m7,
    const float* __restrict__ m8, const float* __restrict__ m9,
    _Float16* __restrict__ dst) {
  int idx = blockIdx.x * 256 + threadIdx.x;
  if (idx < 8192) {
    int n = idx >> 6, k = idx & 63;
    float v = W_in[k * 128 + n] + W_res[k * 128 + n];
    _Float16 h = (_Float16)v;
    dst[idx] = h;
    dst[8192 + idx] = (_Float16)(v - (float)h);
  } else if (idx < 8192 + 10 * 16384) {
    int r = idx - 8192;
    int j = r >> 14;
    int e = r & 16383;
    int n = e >> 7, k = e & 127;
    const float* S;
    switch (j) {
      case 0: S = m0; break; case 1: S = m1; break; case 2: S = m2; break;
      case 3: S = m3; break; case 4: S = m4; break; case 5: S = m5; break;
      case 6: S = m6; break; case 7: S = m7; break; case 8: S = m8; break;
      default: S = m9; break;
    }
    float v = S[k * 128 + n];
    _Float16 h = (_Float16)v;
    _Float16* base = dst + 16384 + j * 32768;
    base[e] = h;                       // e == n*128+k
    base[16384 + e] = (_Float16)(v - (float)h);
  }
}

// ---------------- MFMA GEMM (fp16 hi/lo split, fp32-accurate) ----------------
__device__ inline void split8(const float* __restrict__ p, half8& h, half8& l) {
  float4 a = *reinterpret_cast<const float4*>(p);
  float4 b = *reinterpret_cast<const float4*>(p + 4);
  float v0 = a.x, v1 = a.y, v2 = a.z, v3 = a.w;
  float v4 = b.x, v5 = b.y, v6 = b.z, v7 = b.w;
  _Float16 h0 = (_Float16)v0, h1 = (_Float16)v1, h2 = (_Float16)v2, h3 = (_Float16)v3;
  _Float16 h4 = (_Float16)v4, h5 = (_Float16)v5, h6 = (_Float16)v6, h7 = (_Float16)v7;
  h[0] = h0; h[1] = h1; h[2] = h2; h[3] = h3; h[4] = h4; h[5] = h5; h[6] = h6; h[7] = h7;
  l[0] = (_Float16)(v0 - (float)h0); l[1] = (_Float16)(v1 - (float)h1);
  l[2] = (_Float16)(v2 - (float)h2); l[3] = (_Float16)(v3 - (float)h3);
  l[4] = (_Float16)(v4 - (float)h4); l[5] = (_Float16)(v5 - (float)h5);
  l[6] = (_Float16)(v6 - (float)h6); l[7] = (_Float16)(v7 - (float)h7);
}

template <int K1, int ACT, bool DUAL>
__global__ __launch_bounds__(256) void gemm16(const float* __restrict__ A,
                                              const _Float16* __restrict__ Wh,
                                              const _Float16* __restrict__ Wl,
                                              const float* __restrict__ A2,
                                              const _Float16* __restrict__ W2h,
                                              const _Float16* __restrict__ W2l,
                                              const float* __restrict__ bias,
                                              float* __restrict__ C, int M) {
  const int t = threadIdx.x;
  const int wave = t >> 6, lane = t & 63;
  const int quad = lane >> 4, l16 = lane & 15;
  const int r0 = blockIdx.x * 64 + wave * 16;
  int arow = r0 + l16;
  if (arow >= M) arow = M - 1;

  floatx4 acc[8];
#pragma unroll
  for (int i = 0; i < 8; ++i) acc[i] = (floatx4){0.f, 0.f, 0.f, 0.f};

#pragma unroll
  for (int kk = 0; kk < K1; kk += 32) {
    half8 ah, al;
    split8(A + (size_t)arow * K1 + kk + quad * 8, ah, al);
#pragma unroll
    for (int nt = 0; nt < 8; ++nt) {
      size_t woff = (size_t)(nt * 16 + l16) * K1 + kk + quad * 8;
      half8 wh = *reinterpret_cast<const half8*>(Wh + woff);
      half8 wl = *reinterpret_cast<const half8*>(Wl + woff);
      acc[nt] = __builtin_amdgcn_mfma_f32_16x16x32_f16(ah, wh, acc[nt], 0, 0, 0);
      acc[nt] = __builtin_amdgcn_mfma_f32_16x16x32_f16(ah, wl, acc[nt], 0, 0, 0);
      acc[nt] = __builtin_amdgcn_mfma_f32_16x16x32_f16(al, wh, acc[nt], 0, 0, 0);
    }
  }
  if (DUAL) {
#pragma unroll
    for (int kk = 0; kk < 128; kk += 32) {
      half8 ah, al;
      split8(A2 + (size_t)arow * 128 + kk + quad * 8, ah, al);
#pragma unroll
      for (int nt = 0; nt < 8; ++nt) {
        size_t woff = (size_t)(nt * 16 + l16) * 128 + kk + quad * 8;
        half8 wh = *reinterpret_cast<const half8*>(W2h + woff);
        half8 wl = *reinterpret_cast<const half8*>(W2l + woff);
        acc[nt] = __builtin_amdgcn_mfma_f32_16x16x32_f16(ah, wh, acc[nt], 0, 0, 0);
        acc[nt] = __builtin_amdgcn_mfma_f32_16x16x32_f16(ah, wl, acc[nt], 0, 0, 0);
        acc[nt] = __builtin_amdgcn_mfma_f32_16x16x32_f16(al, wh, acc[nt], 0, 0, 0);
      }
    }
  }

#pragma unroll
  for (int nt = 0; nt < 8; ++nt) {
    float b = bias[nt * 16 + l16];
#pragma unroll
    for (int reg = 0; reg < 4; ++reg) {
      int r = r0 + quad * 4 + reg;
      if (r < M) {
        float v = acc[nt][reg] + b;
        if (ACT == ACT_RELU) v = fmaxf(v, 0.f);
        C[(size_t)r * 128 + nt * 16 + l16] = v;
      }
    }
  }
}

// ---------------- GATv2 + LayerNorm + ELU fused: one wave per dst node ----------------
// Online softmax in log2 domain; scalar (readlane) source index -> scalar address path;
// leaky(x) = fmax(x, 0.2x). Epilogue does LN over the 128-ch row + ELU in-wave.
__global__ __launch_bounds__(256) void gat_ln_kernel(const float* __restrict__ xl,
                                                     const float* __restrict__ xr,
                                                     const float* __restrict__ att,
                                                     const float* __restrict__ gbias,
                                                     const int* __restrict__ rowptr,
                                                     const int* __restrict__ csr,
                                                     const float* __restrict__ lng,
                                                     const float* __restrict__ lnb,
                                                     float* __restrict__ out, int n) {
  int wid = (blockIdx.x * 256 + threadIdx.x) >> 6;
  int lane = threadIdx.x & 63;
  if (wid >= n) return;
  const float2* __restrict__ xl2 = reinterpret_cast<const float2*>(xl);
  const float2 xrv = reinterpret_cast<const float2*>(xr)[wid * 64 + lane];
  const float2 atv = reinterpret_cast<const float2*>(att)[lane];

  float m2, den;
  float2 acc;
  {  // self loop
    float2 xlv = xl2[wid * 64 + lane];
    float a0 = xlv.x + xrv.x, a1 = xlv.y + xrv.y;
    float t0 = fmaxf(a0, NEG_ * a0), t1 = fmaxf(a1, NEG_ * a1);
    float p = t0 * atv.x + t1 * atv.y;
    p += __shfl_xor(p, 1, 64);
    p += __shfl_xor(p, 2, 64);
    p += __shfl_xor(p, 4, 64);
    m2 = p * LOG2E_;
    den = 1.f;
    acc = xlv;
  }
  int beg = rowptr[wid], end = rowptr[wid + 1];
  for (int base = beg; base < end; base += 64) {
    int nb = end - base;
    if (nb > 64) nb = 64;
    int sl = (base + lane < end) ? csr[base + lane] : 0;
    for (int j = 0; j < nb; ++j) {
      int s = __builtin_amdgcn_readlane(sl, j);      // wave-uniform -> scalar addr path
      float2 v = xl2[s * 64 + lane];
      float a0 = v.x + xrv.x, a1 = v.y + xrv.y;
      float t0 = fmaxf(a0, NEG_ * a0), t1 = fmaxf(a1, NEG_ * a1);
      float p = t0 * atv.x + t1 * atv.y;
      p += __shfl_xor(p, 1, 64);
      p += __shfl_xor(p, 2, 64);
      p += __shfl_xor(p, 4, 64);
      float p2 = p * LOG2E_;
      float nm = fmaxf(m2, p2);
      float sc = exp2f(m2 - nm);
      float w = exp2f(p2 - nm);
      den = den * sc + w;
      acc.x = acc.x * sc + w * v.x;
      acc.y = acc.y * sc + w * v.y;
      m2 = nm;
    }
  }
  float inv = 1.f / (den + 1e-16f);
  const float2 bv = reinterpret_cast<const float2*>(gbias)[lane];
  float o0 = acc.x * inv + bv.x;
  float o1 = acc.y * inv + bv.y;
  // fused LayerNorm + ELU
  float s1 = o0 + o1;
  float s2 = o0 * o0 + o1 * o1;
#pragma unroll
  for (int off = 1; off < 64; off <<= 1) {
    s1 += __shfl_xor(s1, off, 64);
    s2 += __shfl_xor(s2, off, 64);
  }
  float mu = s1 * (1.f / 128.f);
  float var = s2 * (1.f / 128.f) - mu * mu;
  float rstd = rsqrtf(var + 1e-5f);
  float2 gv = reinterpret_cast<const float2*>(lng)[lane];
  float2 lbv = reinterpret_cast<const float2*>(lnb)[lane];
  float e0 = (o0 - mu) * rstd * gv.x + lbv.x;
  float e1 = (o1 - mu) * rstd * gv.y + lbv.y;
  e0 = e0 > 0.f ? e0 : exp2f(e0 * LOG2E_) - 1.f;
  e1 = e1 > 0.f ? e1 : exp2f(e1 * LOG2E_) - 1.f;
  reinterpret_cast<float2*>(out)[wid * 64 + lane] = make_float2(e0, e1);
}

// ---------------- SAGE mean aggregation (readlane + 2-way unroll) ----------------
__global__ __launch_bounds__(256) void sage_agg_kernel(const float* __restrict__ xp,
                                                       const int* __restrict__ rowptr,
                                                       const int* __restrict__ csr,
                                                       float* __restrict__ mean, int n) {
  int wid = (blockIdx.x * 256 + threadIdx.x) >> 6;
  int lane = threadIdx.x & 63;
  if (wid >= n) return;
  const float2* __restrict__ xp2 = reinterpret_cast<const float2*>(xp);
  int beg = rowptr[wid], end = rowptr[wid + 1];
  float2 acc0 = make_float2(0.f, 0.f), acc1 = make_float2(0.f, 0.f);
  for (int base = beg; base < end; base += 64) {
    int nb = end - base;
    if (nb > 64) nb = 64;
    int sl = (base + lane < end) ? csr[base + lane] : 0;
    int j = 0;
    for (; j + 2 <= nb; j += 2) {
      int s0 = __builtin_amdgcn_readlane(sl, j);
      int s1i = __builtin_amdgcn_readlane(sl, j + 1);
      float2 v0 = xp2[s0 * 64 + lane];
      float2 v1 = xp2[s1i * 64 + lane];
      acc0.x += v0.x; acc0.y += v0.y;
      acc1.x += v1.x; acc1.y += v1.y;
    }
    if (j < nb) {
      int s0 = __builtin_amdgcn_readlane(sl, j);
      float2 v0 = xp2[s0 * 64 + lane];
      acc0.x += v0.x; acc0.y += v0.y;
    }
  }
  float inv = 1.f / fmaxf((float)(end - beg), 1.f);
  float2 o = make_float2((acc0.x + acc1.x) * inv, (acc0.y + acc1.y) * inv);
  reinterpret_cast<float2*>(mean)[wid * 64 + lane] = o;
}

// ---------------- SAGE post: L2 normalize row, then LN + leaky (in-place) ----------------
__global__ __launch_bounds__(256) void sage_post_kernel(float* __restrict__ x,
                                                        const float* __restrict__ g,
                                                        const float* __restrict__ b, int n) {
  int wid = (blockIdx.x * 256 + threadIdx.x) >> 6;
  int lane = threadIdx.x & 63;
  if (wid >= n) return;
  float2 v = reinterpret_cast<const float2*>(x)[wid * 64 + lane];
  float s1 = v.x + v.y;
  float s2 = v.x * v.x + v.y * v.y;
#pragma unroll
  for (int off = 1; off < 64; off <<= 1) {
    s1 += __shfl_xor(s1, off, 64);
    s2 += __shfl_xor(s2, off, 64);
  }
  float nrm = sqrtf(s2);
  float inv = 1.f / fmaxf(nrm, 1e-12f);
  float mu = s1 * inv * (1.f / 128.f);
  float ex2 = s2 * inv * inv * (1.f / 128.f);
  float var = ex2 - mu * mu;
  float rstd = rsqrtf(var + 1e-5f);
  float2 gv = reinterpret_cast<const float2*>(g)[lane];
  float2 bv = reinterpret_cast<const float2*>(b)[lane];
  float o0 = (v.x * inv - mu) * rstd * gv.x + bv.x;
  float o1 = (v.y * inv - mu) * rstd * gv.y + bv.y;
  o0 = fmaxf(o0, NEG_ * o0);
  o1 = fmaxf(o1, NEG_ * o1);
  reinterpret_cast<float2*>(x)[wid * 64 + lane] = make_float2(o0, o1);
}

// ---------------- JK max + sigmoid gate + mean-pool (chunked, few atomics) ----------------
__global__ __launch_bounds__(256) void jk_pool_kernel(const float* __restrict__ x0,
                                                      const float* __restrict__ x1,
                                                      const float* __restrict__ x2,
                                                      const float* __restrict__ x3,
                                                      const float* __restrict__ wap,
                                                      const float* __restrict__ bap,
                                                      const int* __restrict__ batch,
                                                      float* __restrict__ pooled,
                                                      float* __restrict__ cnt, int n,
                                                      int chunk) {
  int wid = (blockIdx.x * 256 + threadIdx.x) >> 6;
  int lane = threadIdx.x & 63;
  int start = wid * chunk;
  if (start >= n) return;
  int end = start + chunk;
  if (end > n) end = n;

  const float2 wv = reinterpret_cast<const float2*>(wap)[lane];
  const float b0 = bap[0];

  int cur = -1;
  float2 acc = make_float2(0.f, 0.f);
  float c = 0.f;

  for (int i = start; i < end; ++i) {
    int off = i * 64 + lane;
    float2 a0 = reinterpret_cast<const float2*>(x0)[off];
    float2 a1 = reinterpret_cast<const float2*>(x1)[off];
    float2 a2 = reinterpret_cast<const float2*>(x2)[off];
    float2 a3 = reinterpret_cast<const float2*>(x3)[off];
    float2 v;
    v.x = fmaxf(fmaxf(a0.x, a1.x), fmaxf(a2.x, a3.x));
    v.y = fmaxf(fmaxf(a0.y, a1.y), fmaxf(a2.y, a3.y));
    float p = v.x * wv.x + v.y * wv.y;
#pragma unroll
    for (int o = 1; o < 64; o <<= 1) p += __shfl_xor(p, o, 64);
    float a = 1.f / (1.f + exp2f(-(p + b0) * LOG2E_));
    int bg = batch[i];
    if (bg != cur) {
      if (cur >= 0) {
        atomicAdd(&pooled[cur * 128 + 2 * lane], acc.x);
        atomicAdd(&pooled[cur * 128 + 2 * lane + 1], acc.y);
        if (lane == 0) atomicAdd(&cnt[cur], c);
      }
      cur = bg;
      acc = make_float2(0.f, 0.f);
      c = 0.f;
    }
    acc.x += v.x * a;
    acc.y += v.y * a;
    c += 1.f;
  }
  if (cur >= 0) {
    atomicAdd(&pooled[cur * 128 + 2 * lane], acc.x);
    atomicAdd(&pooled[cur * 128 + 2 * lane + 1], acc.y);
    if (lane == 0) atomicAdd(&cnt[cur], c);
  }
}

// ---------------- final MLP: one block per graph ----------------
__global__ __launch_bounds__(128) void mlp_kernel(const float* __restrict__ pooled,
                                                  const float* __restrict__ cnt,
                                                  const float* __restrict__ Wc1,
                                                  const float* __restrict__ bc1,
                                                  const float* __restrict__ a1,
                                                  const float* __restrict__ Wc2,
                                                  const float* __restrict__ bc2,
                                                  const float* __restrict__ a2,
                                                  const float* __restrict__ Wc3,
                                                  const float* __restrict__ bc3,
                                                  float* __restrict__ out) {
  __shared__ float sh[128];
  __shared__ float sh2[128];
  __shared__ float sh3[64];
  int g = blockIdx.x, t = threadIdx.x;
  float inv = 1.f / fmaxf(cnt[g], 1.f);
  sh[t] = pooled[g * 128 + t] * inv;
  __syncthreads();
  float z = bc1[t];
  for (int k = 0; k < 128; ++k) z += sh[k] * Wc1[k * 128 + t];
  float al = a1[0];
  z = z >= 0.f ? z : al * z;
  sh2[t] = z;
  __syncthreads();
  if (t < 64) {
    float z2 = bc2[t];
    for (int k = 0; k < 128; ++k) z2 += sh2[k] * Wc2[k * 64 + t];
    float a2v = a2[0];
    z2 = z2 >= 0.f ? z2 : a2v * z2;
    sh3[t] = z2;
  }
  __syncthreads();
  if (t < 2) {
    float o = bc3[t];
    for (int k = 0; k < 64; ++k) o += sh3[k] * Wc3[k * 2 + t];
    out[g * 2 + t] = o;
  }
}

// ================= host =================
extern "C" void kernel_launch(void* const* d_in, const int* in_sizes, int n_in,
                              void* d_out, int out_size, void* d_ws, size_t ws_size,
                              hipStream_t stream) {
  const float* x = (const float*)d_in[0];
  const int* ei = (const int*)d_in[1];
  const int* batch = (const int*)d_in[2];
  const float* W_in = (const float*)d_in[3];
  const float* b_in = (const float*)d_in[4];
  const float* W_res = (const float*)d_in[5];
  const float* b_res = (const float*)d_in[6];
  const float* g0_Wl = (const float*)d_in[7];
  const float* g0_bl = (const float*)d_in[8];
  const float* g0_Wr = (const float*)d_in[9];
  const float* g0_br = (const float*)d_in[10];
  const float* g0_att = (const float*)d_in[11];
  const float* g0_bias = (const float*)d_in[12];
  const float* g2_Wl = (const float*)d_in[13];
  const float* g2_bl = (const float*)d_in[14];
  const float* g2_Wr = (const float*)d_in[15];
  const float* g2_br = (const float*)d_in[16];
  const float* g2_att = (const float*)d_in[17];
  const float* g2_bias = (const float*)d_in[18];
  const float* s1_Wp = (const float*)d_in[19];
  const float* s1_bp = (const float*)d_in[20];
  const float* s1_Wl = (const float*)d_in[21];
  const float* s1_bl = (const float*)d_in[22];
  const float* s1_Wr = (const float*)d_in[23];
  const float* s3_Wp = (const float*)d_in[24];
  const float* s3_bp = (const float*)d_in[25];
  const float* s3_Wl = (const float*)d_in[26];
  const float* s3_bl = (const float*)d_in[27];
  const float* s3_Wr = (const float*)d_in[28];
  const float* ln_g = (const float*)d_in[29];
  const float* ln_b = (const float*)d_in[30];
  const float* Wap = (const float*)d_in[31];
  const float* bap = (const float*)d_in[32];
  const float* Wc1 = (const float*)d_in[33];
  const float* bc1 = (const float*)d_in[34];
  const float* a1 = (const float*)d_in[35];
  const float* Wc2 = (const float*)d_in[36];
  const float* bc2 = (const float*)d_in[37];
  const float* a2 = (const float*)d_in[38];
  const float* Wc3 = (const float*)d_in[39];
  const float* bc3 = (const float*)d_in[40];
  float* out = (float*)d_out;

  char* w = (char*)d_ws;
  auto alloc = [&](size_t bytes) -> void* {
    void* p = (void*)w;
    w += (bytes + 255) & ~(size_t)255;
    return p;
  };
  int* deg_cursor = (int*)alloc((size_t)N_ * 4);
  int* rowptr = (int*)alloc((size_t)(N_ + 1) * 4);
  int* bscan = (int*)alloc(256 * 4);
  int* csr = (int*)alloc((size_t)E_ * 4);
  float* bsumf = (float*)alloc((size_t)HID_ * 4);
  float* pooled = (float*)alloc((size_t)G_ * HID_ * 4);
  float* cntf = (float*)alloc((size_t)G_ * 4);
  _Float16* wsp = (_Float16*)alloc((size_t)(16384 + 10 * 32768) * 2);
  size_t big = (size_t)N_ * HID_ * 4;
  float* T0 = (float*)alloc(big);
  float* T1 = (float*)alloc(big);
  float* T2 = (float*)alloc(big);
  float* B0 = (float*)alloc(big);
  float* B1 = (float*)alloc(big);
  float* B2 = (float*)alloc(big);
  float* B3 = (float*)alloc(big);

  const _Float16* WsT_h = wsp;
  const _Float16* WsT_l = wsp + 8192;
  auto WTh = [&](int j) { return (const _Float16*)(wsp + 16384 + j * 32768); };
  auto WTl = [&](int j) { return (const _Float16*)(wsp + 16384 + j * 32768 + 16384); };
  // j: 0 g0_Wl, 1 g0_Wr, 2 s1_Wp, 3 s1_Wl, 4 s1_Wr, 5 g2_Wl, 6 g2_Wr, 7 s3_Wp, 8 s3_Wl, 9 s3_Wr

  const int EB = (E_ + 255) / 256;
  const int NB256 = (N_ + 255) / 256;
  const int WB = (N_ + 3) / 4;
  const int GB = (N_ + 63) / 64;

  // ---- CSR build ----
  hipMemsetAsync(deg_cursor, 0, (size_t)N_ * 4, stream);
  hist_kernel<<<EB, 256, 0, stream>>>(ei + E_, deg_cursor, E_);
  scan1_kernel<<<NB256, 256, 0, stream>>>(deg_cursor, rowptr, bscan, N_);
  scan2_kernel<<<1, 256, 0, stream>>>(bscan, NB256);
  scan3_kernel<<<NB256, 256, 0, stream>>>(rowptr, deg_cursor, bscan, N_, E_);
  fill_kernel<<<EB, 256, 0, stream>>>(ei, ei + E_, deg_cursor, csr, E_);

  // ---- weight prep ----
  prep_w_kernel<<<(8192 + 10 * 16384 + 255) / 256, 256, 0, stream>>>(
      W_in, W_res, g0_Wl, g0_Wr, s1_Wp, s1_Wl, s1_Wr, g2_Wl, g2_Wr, s3_Wp, s3_Wl, s3_Wr, wsp);
  addv_kernel<<<1, 256, 0, stream>>>(b_in, b_res, bsumf, HID_);

  // ---- input proj: h = x @ (W_in+W_res) + bsum  -> T2 ----
  gemm16<64, ACT_NONE, false><<<GB, 256, 0, stream>>>(x, WsT_h, WsT_l, nullptr, nullptr,
                                                      nullptr, bsumf, T2, N_);

  // ---- GAT layer 0 (gat + LN + ELU fused) ----
  gemm16<128, ACT_NONE, false><<<GB, 256, 0, stream>>>(T2, WTh(0), WTl(0), nullptr, nullptr,
                                                       nullptr, g0_bl, T0, N_);
  gemm16<128, ACT_NONE, false><<<GB, 256, 0, stream>>>(T2, WTh(1), WTl(1), nullptr, nullptr,
                                                       nullptr, g0_br, T1, N_);
  gat_ln_kernel<<<WB, 256, 0, stream>>>(T0, T1, g0_att, g0_bias, rowptr, csr,
                                        ln_g + 0 * 128, ln_b + 0 * 128, B0, N_);

  // ---- SAGE layer 1 ----
  gemm16<128, ACT_RELU, false><<<GB, 256, 0, stream>>>(B0, WTh(2), WTl(2), nullptr, nullptr,
                                                       nullptr, s1_bp, T0, N_);  // xp
  sage_agg_kernel<<<WB, 256, 0, stream>>>(T0, rowptr, csr, T1, N_);              // mean
  gemm16<128, ACT_NONE, true><<<GB, 256, 0, stream>>>(T1, WTh(3), WTl(3), B0, WTh(4), WTl(4),
                                                      s1_bl, B1, N_);  // mean@Wl + xs0@Wr
  sage_post_kernel<<<WB, 256, 0, stream>>>(B1, ln_g + 1 * 128, ln_b + 1 * 128, N_);

  // ---- GAT layer 2 ----
  gemm16<128, ACT_NONE, false><<<GB, 256, 0, stream>>>(B1, WTh(5), WTl(5), nullptr, nullptr,
                                                       nullptr, g2_bl, T0, N_);
  gemm16<128, ACT_NONE, false><<<GB, 256, 0, stream>>>(B1, WTh(6), WTl(6), nullptr, nullptr,
                                                       nullptr, g2_br, T1, N_);
  gat_ln_kernel<<<WB, 256, 0, stream>>>(T0, T1, g2_att, g2_bias, rowptr, csr,
                                        ln_g + 2 * 128, ln_b + 2 * 128, B2, N_);

  // ---- SAGE layer 3 ----
  gemm16<128, ACT_RELU, false><<<GB, 256, 0, stream>>>(B2, WTh(7), WTl(7), nullptr, nullptr,
                                                       nullptr, s3_bp, T0, N_);
  sage_agg_kernel<<<WB, 256, 0, stream>>>(T0, rowptr, csr, T1, N_);
  gemm16<128, ACT_NONE, true><<<GB, 256, 0, stream>>>(T1, WTh(8), WTl(8), B2, WTh(9), WTl(9),
                                                      s3_bl, B3, N_);
  sage_post_kernel<<<WB, 256, 0, stream>>>(B3, ln_g + 3 * 128, ln_b + 3 * 128, N_);

  // ---- JK max + gate + pool + MLP ----
  hipMemsetAsync(pooled, 0, (size_t)G_ * HID_ * 4, stream);
  hipMemsetAsync(cntf, 0, (size_t)G_ * 4, stream);
  {
    const int chunk = 12;
    int nwaves = (N_ + chunk - 1) / chunk;
    int nblocks = (nwaves + 3) / 4;
    jk_pool_kernel<<<nblocks, 256, 0, stream>>>(B0, B1, B2, B3, Wap, bap, batch,
                                                pooled, cntf, N_, chunk);
  }
  mlp_kernel<<<G_, 128, 0, stream>>>(pooled, cntf, Wc1, bc1, a1, Wc2, bc2, a2, Wc3, bc3, out);
}

// Round 5
// 903.356 us; speedup vs baseline: 1.6420x; 1.1220x over previous
//
#include <hip/hip_runtime.h>
#include <math.h>

constexpr int N_ = 50000;
constexpr int E_ = 800000;
constexpr int IN_ = 64;
constexpr int HID_ = 128;
constexpr int G_ = 64;
constexpr float NEG_ = 0.2f;
constexpr float LOG2E_ = 1.44269504088896340736f;

#define ACT_NONE 0
#define ACT_RELU 1

typedef _Float16 half8 __attribute__((ext_vector_type(8)));
typedef float floatx4 __attribute__((ext_vector_type(4)));

// ---------------- CSR build ----------------
__global__ __launch_bounds__(256) void hist_kernel(const int* __restrict__ dst,
                                                   int* __restrict__ deg, int e) {
  int i = blockIdx.x * 256 + threadIdx.x;
  if (i < e) atomicAdd(&deg[dst[i]], 1);
}

__global__ __launch_bounds__(256) void scan1_kernel(const int* __restrict__ deg,
                                                    int* __restrict__ excl,
                                                    int* __restrict__ bscan, int n) {
  __shared__ int sh[256];
  int t = threadIdx.x;
  int i = blockIdx.x * 256 + t;
  int v = (i < n) ? deg[i] : 0;
  sh[t] = v;
  __syncthreads();
  for (int off = 1; off < 256; off <<= 1) {
    int y = (t >= off) ? sh[t - off] : 0;
    __syncthreads();
    sh[t] += y;
    __syncthreads();
  }
  int incl = sh[t];
  if (i < n) excl[i] = incl - v;
  if (t == 255) bscan[blockIdx.x] = incl;
}

__global__ __launch_bounds__(256) void scan2_kernel(int* __restrict__ data, int nb) {
  __shared__ int sh[256];
  int t = threadIdx.x;
  int v = (t < nb) ? data[t] : 0;
  sh[t] = v;
  __syncthreads();
  for (int off = 1; off < 256; off <<= 1) {
    int y = (t >= off) ? sh[t - off] : 0;
    __syncthreads();
    sh[t] += y;
    __syncthreads();
  }
  if (t < nb) data[t] = sh[t] - v;  // exclusive
}

__global__ __launch_bounds__(256) void scan3_kernel(int* __restrict__ rowptr,
                                                    int* __restrict__ cursor,
                                                    const int* __restrict__ bscan,
                                                    int n, int e) {
  int i = blockIdx.x * 256 + threadIdx.x;
  if (i < n) {
    int v = rowptr[i] + bscan[blockIdx.x];
    rowptr[i] = v;
    cursor[i] = v;
  }
  if (i == n) rowptr[n] = e;
}

__global__ __launch_bounds__(256) void fill_kernel(const int* __restrict__ src,
                                                   const int* __restrict__ dst,
                                                   int* __restrict__ cursor,
                                                   int* __restrict__ csr, int e) {
  int i = blockIdx.x * 256 + threadIdx.x;
  if (i < e) {
    int d = dst[i];
    int p = atomicAdd(&cursor[d], 1);
    csr[p] = src[i];
  }
}

// ---------------- bias sum ----------------
__global__ __launch_bounds__(256) void addv_kernel(const float* __restrict__ a,
                                                   const float* __restrict__ b,
                                                   float* __restrict__ o, int n) {
  int i = blockIdx.x * 256 + threadIdx.x;
  if (i < n) o[i] = a[i] + b[i];
}

// ---------------- weight prep: transpose + fp16 hi/lo split ----------------
__global__ __launch_bounds__(256) void prep_w_kernel(
    const float* __restrict__ W_in, const float* __restrict__ W_res,
    const float* __restrict__ m0, const float* __restrict__ m1,
    const float* __restrict__ m2, const float* __restrict__ m3,
    const float* __restrict__ m4, const float* __restrict__ m5,
    const float* __restrict__ m6, const float* __restrict__ m7,
    const float* __restrict__ m8, const float* __restrict__ m9,
    _Float16* __restrict__ dst) {
  int idx = blockIdx.x * 256 + threadIdx.x;
  if (idx < 8192) {
    int n = idx >> 6, k = idx & 63;
    float v = W_in[k * 128 + n] + W_res[k * 128 + n];
    _Float16 h = (_Float16)v;
    dst[idx] = h;
    dst[8192 + idx] = (_Float16)(v - (float)h);
  } else if (idx < 8192 + 10 * 16384) {
    int r = idx - 8192;
    int j = r >> 14;
    int e = r & 16383;
    int n = e >> 7, k = e & 127;
    const float* S;
    switch (j) {
      case 0: S = m0; break; case 1: S = m1; break; case 2: S = m2; break;
      case 3: S = m3; break; case 4: S = m4; break; case 5: S = m5; break;
      case 6: S = m6; break; case 7: S = m7; break; case 8: S = m8; break;
      default: S = m9; break;
    }
    float v = S[k * 128 + n];
    _Float16 h = (_Float16)v;
    _Float16* base = dst + 16384 + j * 32768;
    base[e] = h;                       // e == n*128+k
    base[16384 + e] = (_Float16)(v - (float)h);
  }
}

// ---------------- fp16 hi/lo split of 8 consecutive floats ----------------
__device__ inline void split8(const float* __restrict__ p, half8& h, half8& l) {
  float4 a = *reinterpret_cast<const float4*>(p);
  float4 b = *reinterpret_cast<const float4*>(p + 4);
  float v0 = a.x, v1 = a.y, v2 = a.z, v3 = a.w;
  float v4 = b.x, v5 = b.y, v6 = b.z, v7 = b.w;
  _Float16 h0 = (_Float16)v0, h1 = (_Float16)v1, h2 = (_Float16)v2, h3 = (_Float16)v3;
  _Float16 h4 = (_Float16)v4, h5 = (_Float16)v5, h6 = (_Float16)v6, h7 = (_Float16)v7;
  h[0] = h0; h[1] = h1; h[2] = h2; h[3] = h3; h[4] = h4; h[5] = h5; h[6] = h6; h[7] = h7;
  l[0] = (_Float16)(v0 - (float)h0); l[1] = (_Float16)(v1 - (float)h1);
  l[2] = (_Float16)(v2 - (float)h2); l[3] = (_Float16)(v3 - (float)h3);
  l[4] = (_Float16)(v4 - (float)h4); l[5] = (_Float16)(v5 - (float)h5);
  l[6] = (_Float16)(v6 - (float)h6); l[7] = (_Float16)(v7 - (float)h7);
}

// ---------------- single MFMA GEMM: C = act(A[M,K]@W + bias) ----------------
template <int K1, int ACT>
__global__ __launch_bounds__(256) void gemm16(const float* __restrict__ A,
                                              const _Float16* __restrict__ Wh,
                                              const _Float16* __restrict__ Wl,
                                              const float* __restrict__ bias,
                                              float* __restrict__ C, int M) {
  const int t = threadIdx.x;
  const int wave = t >> 6, lane = t & 63;
  const int quad = lane >> 4, l16 = lane & 15;
  const int r0 = blockIdx.x * 64 + wave * 16;
  int arow = r0 + l16;
  if (arow >= M) arow = M - 1;

  floatx4 acc[8];
#pragma unroll
  for (int i = 0; i < 8; ++i) acc[i] = (floatx4){0.f, 0.f, 0.f, 0.f};

#pragma unroll
  for (int kk = 0; kk < K1; kk += 32) {
    half8 ah, al;
    split8(A + (size_t)arow * K1 + kk + quad * 8, ah, al);
#pragma unroll
    for (int nt = 0; nt < 8; ++nt) {
      size_t woff = (size_t)(nt * 16 + l16) * K1 + kk + quad * 8;
      half8 wh = *reinterpret_cast<const half8*>(Wh + woff);
      half8 wl = *reinterpret_cast<const half8*>(Wl + woff);
      acc[nt] = __builtin_amdgcn_mfma_f32_16x16x32_f16(ah, wh, acc[nt], 0, 0, 0);
      acc[nt] = __builtin_amdgcn_mfma_f32_16x16x32_f16(ah, wl, acc[nt], 0, 0, 0);
      acc[nt] = __builtin_amdgcn_mfma_f32_16x16x32_f16(al, wh, acc[nt], 0, 0, 0);
    }
  }

#pragma unroll
  for (int nt = 0; nt < 8; ++nt) {
    float b = bias[nt * 16 + l16];
#pragma unroll
    for (int reg = 0; reg < 4; ++reg) {
      int r = r0 + quad * 4 + reg;
      if (r < M) {
        float v = acc[nt][reg] + b;
        if (ACT == ACT_RELU) v = fmaxf(v, 0.f);
        C[(size_t)r * 128 + nt * 16 + l16] = v;
      }
    }
  }
}

// ---------------- dual-output GEMM (GAT): xl = A@W0+b0, xr = A@W1+b1 ----------------
// A read & split ONCE for both outputs.
__global__ __launch_bounds__(256) void gemm_dual_gat(const float* __restrict__ A,
                                                     const _Float16* __restrict__ W0h,
                                                     const _Float16* __restrict__ W0l,
                                                     const _Float16* __restrict__ W1h,
                                                     const _Float16* __restrict__ W1l,
                                                     const float* __restrict__ b0,
                                                     const float* __restrict__ b1,
                                                     float* __restrict__ C0,
                                                     float* __restrict__ C1, int M) {
  const int t = threadIdx.x;
  const int wave = t >> 6, lane = t & 63;
  const int quad = lane >> 4, l16 = lane & 15;
  const int r0 = blockIdx.x * 64 + wave * 16;
  int arow = r0 + l16;
  if (arow >= M) arow = M - 1;

  floatx4 acc0[8], acc1[8];
#pragma unroll
  for (int i = 0; i < 8; ++i) {
    acc0[i] = (floatx4){0.f, 0.f, 0.f, 0.f};
    acc1[i] = (floatx4){0.f, 0.f, 0.f, 0.f};
  }

#pragma unroll
  for (int kk = 0; kk < 128; kk += 32) {
    half8 ah, al;
    split8(A + (size_t)arow * 128 + kk + quad * 8, ah, al);
#pragma unroll
    for (int nt = 0; nt < 8; ++nt) {
      size_t woff = (size_t)(nt * 16 + l16) * 128 + kk + quad * 8;
      half8 w0h = *reinterpret_cast<const half8*>(W0h + woff);
      half8 w0l = *reinterpret_cast<const half8*>(W0l + woff);
      half8 w1h = *reinterpret_cast<const half8*>(W1h + woff);
      half8 w1l = *reinterpret_cast<const half8*>(W1l + woff);
      acc0[nt] = __builtin_amdgcn_mfma_f32_16x16x32_f16(ah, w0h, acc0[nt], 0, 0, 0);
      acc0[nt] = __builtin_amdgcn_mfma_f32_16x16x32_f16(ah, w0l, acc0[nt], 0, 0, 0);
      acc0[nt] = __builtin_amdgcn_mfma_f32_16x16x32_f16(al, w0h, acc0[nt], 0, 0, 0);
      acc1[nt] = __builtin_amdgcn_mfma_f32_16x16x32_f16(ah, w1h, acc1[nt], 0, 0, 0);
      acc1[nt] = __builtin_amdgcn_mfma_f32_16x16x32_f16(ah, w1l, acc1[nt], 0, 0, 0);
      acc1[nt] = __builtin_amdgcn_mfma_f32_16x16x32_f16(al, w1h, acc1[nt], 0, 0, 0);
    }
  }

#pragma unroll
  for (int nt = 0; nt < 8; ++nt) {
    float bb0 = b0[nt * 16 + l16];
    float bb1 = b1[nt * 16 + l16];
#pragma unroll
    for (int reg = 0; reg < 4; ++reg) {
      int r = r0 + quad * 4 + reg;
      if (r < M) {
        C0[(size_t)r * 128 + nt * 16 + l16] = acc0[nt][reg] + bb0;
        C1[(size_t)r * 128 + nt * 16 + l16] = acc1[nt][reg] + bb1;
      }
    }
  }
}

// ---------------- dual-A GEMM (SAGE) + fused L2norm + LN + leaky ----------------
// C = post( A1@W1 + bias + A2@W2 ), post = LN(normalize(row)) then leaky.
__global__ __launch_bounds__(256) void gemm_dual_sage(const float* __restrict__ A1,
                                                      const _Float16* __restrict__ W1h,
                                                      const _Float16* __restrict__ W1l,
                                                      const float* __restrict__ A2,
                                                      const _Float16* __restrict__ W2h,
                                                      const _Float16* __restrict__ W2l,
                                                      const float* __restrict__ bias,
                                                      const float* __restrict__ lng,
                                                      const float* __restrict__ lnb,
                                                      float* __restrict__ C, int M) {
  const int t = threadIdx.x;
  const int wave = t >> 6, lane = t & 63;
  const int quad = lane >> 4, l16 = lane & 15;
  const int r0 = blockIdx.x * 64 + wave * 16;
  int arow = r0 + l16;
  if (arow >= M) arow = M - 1;

  floatx4 acc[8];
#pragma unroll
  for (int i = 0; i < 8; ++i) acc[i] = (floatx4){0.f, 0.f, 0.f, 0.f};

#pragma unroll
  for (int kk = 0; kk < 128; kk += 32) {
    half8 ah, al;
    split8(A1 + (size_t)arow * 128 + kk + quad * 8, ah, al);
#pragma unroll
    for (int nt = 0; nt < 8; ++nt) {
      size_t woff = (size_t)(nt * 16 + l16) * 128 + kk + quad * 8;
      half8 wh = *reinterpret_cast<const half8*>(W1h + woff);
      half8 wl = *reinterpret_cast<const half8*>(W1l + woff);
      acc[nt] = __builtin_amdgcn_mfma_f32_16x16x32_f16(ah, wh, acc[nt], 0, 0, 0);
      acc[nt] = __builtin_amdgcn_mfma_f32_16x16x32_f16(ah, wl, acc[nt], 0, 0, 0);
      acc[nt] = __builtin_amdgcn_mfma_f32_16x16x32_f16(al, wh, acc[nt], 0, 0, 0);
    }
  }
#pragma unroll
  for (int kk = 0; kk < 128; kk += 32) {
    half8 ah, al;
    split8(A2 + (size_t)arow * 128 + kk + quad * 8, ah, al);
#pragma unroll
    for (int nt = 0; nt < 8; ++nt) {
      size_t woff = (size_t)(nt * 16 + l16) * 128 + kk + quad * 8;
      half8 wh = *reinterpret_cast<const half8*>(W2h + woff);
      half8 wl = *reinterpret_cast<const half8*>(W2l + woff);
      acc[nt] = __builtin_amdgcn_mfma_f32_16x16x32_f16(ah, wh, acc[nt], 0, 0, 0);
      acc[nt] = __builtin_amdgcn_mfma_f32_16x16x32_f16(ah, wl, acc[nt], 0, 0, 0);
      acc[nt] = __builtin_amdgcn_mfma_f32_16x16x32_f16(al, wh, acc[nt], 0, 0, 0);
    }
  }

  // epilogue: per row (quad*4+reg): L2-normalize over 128 cols, LN, leaky.
  // Row cols live in-lane over nt (8) x cross-lane over l16 (16 lanes, same quad).
  float gv[8], bvv[8], bb[8];
#pragma unroll
  for (int nt = 0; nt < 8; ++nt) {
    gv[nt] = lng[nt * 16 + l16];
    bvv[nt] = lnb[nt * 16 + l16];
    bb[nt] = bias[nt * 16 + l16];
  }
#pragma unroll
  for (int reg = 0; reg < 4; ++reg) {
    int r = r0 + quad * 4 + reg;
    float v[8];
    float s2 = 0.f;
#pragma unroll
    for (int nt = 0; nt < 8; ++nt) {
      v[nt] = acc[nt][reg] + bb[nt];
      s2 += v[nt] * v[nt];
    }
#pragma unroll
    for (int off = 1; off < 16; off <<= 1) s2 += __shfl_xor(s2, off, 64);
    float inv = 1.f / fmaxf(sqrtf(s2), 1e-12f);
    float s1 = 0.f;
#pragma unroll
    for (int nt = 0; nt < 8; ++nt) {
      v[nt] *= inv;
      s1 += v[nt];
    }
#pragma unroll
    for (int off = 1; off < 16; off <<= 1) s1 += __shfl_xor(s1, off, 64);
    float mu = s1 * (1.f / 128.f);
    // var = mean(v^2) - mu^2 ; mean(v^2) = s2*inv^2/128 = 1/128 (normalized), but
    // recompute exactly like reference: sum v^2 after normalize = 1 (up to clamp)
    float ex2 = (s2 * inv) * inv * (1.f / 128.f);
    float var = ex2 - mu * mu;
    float rstd = rsqrtf(var + 1e-5f);
    if (r < M) {
#pragma unroll
      for (int nt = 0; nt < 8; ++nt) {
        float o = (v[nt] - mu) * rstd * gv[nt] + bvv[nt];
        o = fmaxf(o, NEG_ * o);
        C[(size_t)r * 128 + nt * 16 + l16] = o;
      }
    }
  }
}

// ---------------- GATv2 + LayerNorm + ELU fused: one wave per dst node ----------------
// Online softmax, log2 domain, single exp2 per edge (predicated), prefetched gather.
__global__ __launch_bounds__(256) void gat_ln_kernel(const float* __restrict__ xl,
                                                     const float* __restrict__ xr,
                                                     const float* __restrict__ att,
                                                     const float* __restrict__ gbias,
                                                     const int* __restrict__ rowptr,
                                                     const int* __restrict__ csr,
                                                     const float* __restrict__ lng,
                                                     const float* __restrict__ lnb,
                                                     float* __restrict__ out, int n) {
  int wid = (blockIdx.x * 256 + threadIdx.x) >> 6;
  int lane = threadIdx.x & 63;
  if (wid >= n) return;
  const float2* __restrict__ xl2 = reinterpret_cast<const float2*>(xl);
  const float2 xrv = reinterpret_cast<const float2*>(xr)[wid * 64 + lane];
  const float2 atv = reinterpret_cast<const float2*>(att)[lane];

  float m2, den;
  float2 acc;
  {  // self loop
    float2 xlv = xl2[wid * 64 + lane];
    float a0 = xlv.x + xrv.x, a1 = xlv.y + xrv.y;
    float t0 = fmaxf(a0, NEG_ * a0), t1 = fmaxf(a1, NEG_ * a1);
    float p = t0 * atv.x + t1 * atv.y;
    p += __shfl_xor(p, 1, 64);
    p += __shfl_xor(p, 2, 64);
    p += __shfl_xor(p, 4, 64);
    m2 = p * LOG2E_;
    den = 1.f;
    acc = xlv;
  }
  int beg = rowptr[wid], end = rowptr[wid + 1];
  for (int base = beg; base < end; base += 64) {
    int nb = end - base;
    if (nb > 64) nb = 64;
    int sl = (base + lane < end) ? csr[base + lane] : 0;
    int s0 = __builtin_amdgcn_readlane(sl, 0);
    float2 vbuf = xl2[s0 * 64 + lane];
    for (int j = 0; j < nb; ++j) {
      float2 v = vbuf;
      if (j + 1 < nb) {  // wave-uniform branch: prefetch next gather
        int sn = __builtin_amdgcn_readlane(sl, j + 1);
        vbuf = xl2[sn * 64 + lane];
      }
      float a0 = v.x + xrv.x, a1 = v.y + xrv.y;
      float t0 = fmaxf(a0, NEG_ * a0), t1 = fmaxf(a1, NEG_ * a1);
      float p = t0 * atv.x + t1 * atv.y;
      p += __shfl_xor(p, 1, 64);
      p += __shfl_xor(p, 2, 64);
      p += __shfl_xor(p, 4, 64);
      float p2 = p * LOG2E_;
      float d = p2 - m2;
      float e = exp2f(-fabsf(d));     // single exp2 per edge
      bool gt = d > 0.f;
      float sc = gt ? e : 1.f;
      float w = gt ? 1.f : e;
      m2 = fmaxf(m2, p2);
      den = den * sc + w;
      acc.x = acc.x * sc + w * v.x;
      acc.y = acc.y * sc + w * v.y;
    }
  }
  float inv = 1.f / (den + 1e-16f);
  const float2 bv = reinterpret_cast<const float2*>(gbias)[lane];
  float o0 = acc.x * inv + bv.x;
  float o1 = acc.y * inv + bv.y;
  // fused LayerNorm + ELU
  float s1 = o0 + o1;
  float s2 = o0 * o0 + o1 * o1;
#pragma unroll
  for (int off = 1; off < 64; off <<= 1) {
    s1 += __shfl_xor(s1, off, 64);
    s2 += __shfl_xor(s2, off, 64);
  }
  float mu = s1 * (1.f / 128.f);
  float var = s2 * (1.f / 128.f) - mu * mu;
  float rstd = rsqrtf(var + 1e-5f);
  float2 gvv = reinterpret_cast<const float2*>(lng)[lane];
  float2 lbv = reinterpret_cast<const float2*>(lnb)[lane];
  float e0 = (o0 - mu) * rstd * gvv.x + lbv.x;
  float e1 = (o1 - mu) * rstd * gvv.y + lbv.y;
  e0 = e0 > 0.f ? e0 : exp2f(e0 * LOG2E_) - 1.f;
  e1 = e1 > 0.f ? e1 : exp2f(e1 * LOG2E_) - 1.f;
  reinterpret_cast<float2*>(out)[wid * 64 + lane] = make_float2(e0, e1);
}

// ---------------- SAGE mean aggregation (readlane + 2-way unroll) ----------------
__global__ __launch_bounds__(256) void sage_agg_kernel(const float* __restrict__ xp,
                                                       const int* __restrict__ rowptr,
                                                       const int* __restrict__ csr,
                                                       float* __restrict__ mean, int n) {
  int wid = (blockIdx.x * 256 + threadIdx.x) >> 6;
  int lane = threadIdx.x & 63;
  if (wid >= n) return;
  const float2* __restrict__ xp2 = reinterpret_cast<const float2*>(xp);
  int beg = rowptr[wid], end = rowptr[wid + 1];
  float2 acc0 = make_float2(0.f, 0.f), acc1 = make_float2(0.f, 0.f);
  for (int base = beg; base < end; base += 64) {
    int nb = end - base;
    if (nb > 64) nb = 64;
    int sl = (base + lane < end) ? csr[base + lane] : 0;
    int j = 0;
    for (; j + 2 <= nb; j += 2) {
      int s0 = __builtin_amdgcn_readlane(sl, j);
      int s1i = __builtin_amdgcn_readlane(sl, j + 1);
      float2 v0 = xp2[s0 * 64 + lane];
      float2 v1 = xp2[s1i * 64 + lane];
      acc0.x += v0.x; acc0.y += v0.y;
      acc1.x += v1.x; acc1.y += v1.y;
    }
    if (j < nb) {
      int s0 = __builtin_amdgcn_readlane(sl, j);
      float2 v0 = xp2[s0 * 64 + lane];
      acc0.x += v0.x; acc0.y += v0.y;
    }
  }
  float inv = 1.f / fmaxf((float)(end - beg), 1.f);
  float2 o = make_float2((acc0.x + acc1.x) * inv, (acc0.y + acc1.y) * inv);
  reinterpret_cast<float2*>(mean)[wid * 64 + lane] = o;
}

// ---------------- JK max + sigmoid gate + mean-pool (chunked, few atomics) ----------------
__global__ __launch_bounds__(256) void jk_pool_kernel(const float* __restrict__ x0,
                                                      const float* __restrict__ x1,
                                                      const float* __restrict__ x2,
                                                      const float* __restrict__ x3,
                                                      const float* __restrict__ wap,
                                                      const float* __restrict__ bap,
                                                      const int* __restrict__ batch,
                                                      float* __restrict__ pooled,
                                                      float* __restrict__ cnt, int n,
                                                      int chunk) {
  int wid = (blockIdx.x * 256 + threadIdx.x) >> 6;
  int lane = threadIdx.x & 63;
  int start = wid * chunk;
  if (start >= n) return;
  int end = start + chunk;
  if (end > n) end = n;

  const float2 wv = reinterpret_cast<const float2*>(wap)[lane];
  const float b0 = bap[0];

  int cur = -1;
  float2 acc = make_float2(0.f, 0.f);
  float c = 0.f;

  for (int i = start; i < end; ++i) {
    int off = i * 64 + lane;
    float2 a0 = reinterpret_cast<const float2*>(x0)[off];
    float2 a1 = reinterpret_cast<const float2*>(x1)[off];
    float2 a2 = reinterpret_cast<const float2*>(x2)[off];
    float2 a3 = reinterpret_cast<const float2*>(x3)[off];
    float2 v;
    v.x = fmaxf(fmaxf(a0.x, a1.x), fmaxf(a2.x, a3.x));
    v.y = fmaxf(fmaxf(a0.y, a1.y), fmaxf(a2.y, a3.y));
    float p = v.x * wv.x + v.y * wv.y;
#pragma unroll
    for (int o = 1; o < 64; o <<= 1) p += __shfl_xor(p, o, 64);
    float a = 1.f / (1.f + exp2f(-(p + b0) * LOG2E_));
    int bg = batch[i];
    if (bg != cur) {
      if (cur >= 0) {
        atomicAdd(&pooled[cur * 128 + 2 * lane], acc.x);
        atomicAdd(&pooled[cur * 128 + 2 * lane + 1], acc.y);
        if (lane == 0) atomicAdd(&cnt[cur], c);
      }
      cur = bg;
      acc = make_float2(0.f, 0.f);
      c = 0.f;
    }
    acc.x += v.x * a;
    acc.y += v.y * a;
    c += 1.f;
  }
  if (cur >= 0) {
    atomicAdd(&pooled[cur * 128 + 2 * lane], acc.x);
    atomicAdd(&pooled[cur * 128 + 2 * lane + 1], acc.y);
    if (lane == 0) atomicAdd(&cnt[cur], c);
  }
}

// ---------------- final MLP: one block per graph ----------------
__global__ __launch_bounds__(128) void mlp_kernel(const float* __restrict__ pooled,
                                                  const float* __restrict__ cnt,
                                                  const float* __restrict__ Wc1,
                                                  const float* __restrict__ bc1,
                                                  const float* __restrict__ a1,
                                                  const float* __restrict__ Wc2,
                                                  const float* __restrict__ bc2,
                                                  const float* __restrict__ a2,
                                                  const float* __restrict__ Wc3,
                                                  const float* __restrict__ bc3,
                                                  float* __restrict__ out) {
  __shared__ float sh[128];
  __shared__ float sh2[128];
  __shared__ float sh3[64];
  int g = blockIdx.x, t = threadIdx.x;
  float inv = 1.f / fmaxf(cnt[g], 1.f);
  sh[t] = pooled[g * 128 + t] * inv;
  __syncthreads();
  float z = bc1[t];
  for (int k = 0; k < 128; ++k) z += sh[k] * Wc1[k * 128 + t];
  float al = a1[0];
  z = z >= 0.f ? z : al * z;
  sh2[t] = z;
  __syncthreads();
  if (t < 64) {
    float z2 = bc2[t];
    for (int k = 0; k < 128; ++k) z2 += sh2[k] * Wc2[k * 64 + t];
    float a2v = a2[0];
    z2 = z2 >= 0.f ? z2 : a2v * z2;
    sh3[t] = z2;
  }
  __syncthreads();
  if (t < 2) {
    float o = bc3[t];
    for (int k = 0; k < 64; ++k) o += sh3[k] * Wc3[k * 2 + t];
    out[g * 2 + t] = o;
  }
}

// ================= host =================
extern "C" void kernel_launch(void* const* d_in, const int* in_sizes, int n_in,
                              void* d_out, int out_size, void* d_ws, size_t ws_size,
                              hipStream_t stream) {
  const float* x = (const float*)d_in[0];
  const int* ei = (const int*)d_in[1];
  const int* batch = (const int*)d_in[2];
  const float* W_in = (const float*)d_in[3];
  const float* b_in = (const float*)d_in[4];
  const float* W_res = (const float*)d_in[5];
  const float* b_res = (const float*)d_in[6];
  const float* g0_Wl = (const float*)d_in[7];
  const float* g0_bl = (const float*)d_in[8];
  const float* g0_Wr = (const float*)d_in[9];
  const float* g0_br = (const float*)d_in[10];
  const float* g0_att = (const float*)d_in[11];
  const float* g0_bias = (const float*)d_in[12];
  const float* g2_Wl = (const float*)d_in[13];
  const float* g2_bl = (const float*)d_in[14];
  const float* g2_Wr = (const float*)d_in[15];
  const float* g2_br = (const float*)d_in[16];
  const float* g2_att = (const float*)d_in[17];
  const float* g2_bias = (const float*)d_in[18];
  const float* s1_Wp = (const float*)d_in[19];
  const float* s1_bp = (const float*)d_in[20];
  const float* s1_Wl = (const float*)d_in[21];
  const float* s1_bl = (const float*)d_in[22];
  const float* s1_Wr = (const float*)d_in[23];
  const float* s3_Wp = (const float*)d_in[24];
  const float* s3_bp = (const float*)d_in[25];
  const float* s3_Wl = (const float*)d_in[26];
  const float* s3_bl = (const float*)d_in[27];
  const float* s3_Wr = (const float*)d_in[28];
  const float* ln_g = (const float*)d_in[29];
  const float* ln_b = (const float*)d_in[30];
  const float* Wap = (const float*)d_in[31];
  const float* bap = (const float*)d_in[32];
  const float* Wc1 = (const float*)d_in[33];
  const float* bc1 = (const float*)d_in[34];
  const float* a1 = (const float*)d_in[35];
  const float* Wc2 = (const float*)d_in[36];
  const float* bc2 = (const float*)d_in[37];
  const float* a2 = (const float*)d_in[38];
  const float* Wc3 = (const float*)d_in[39];
  const float* bc3 = (const float*)d_in[40];
  float* out = (float*)d_out;

  char* w = (char*)d_ws;
  auto alloc = [&](size_t bytes) -> void* {
    void* p = (void*)w;
    w += (bytes + 255) & ~(size_t)255;
    return p;
  };
  int* deg_cursor = (int*)alloc((size_t)N_ * 4);
  int* rowptr = (int*)alloc((size_t)(N_ + 1) * 4);
  int* bscan = (int*)alloc(256 * 4);
  int* csr = (int*)alloc((size_t)E_ * 4);
  float* bsumf = (float*)alloc((size_t)HID_ * 4);
  float* pooled = (float*)alloc((size_t)G_ * HID_ * 4);
  float* cntf = (float*)alloc((size_t)G_ * 4);
  _Float16* wsp = (_Float16*)alloc((size_t)(16384 + 10 * 32768) * 2);
  size_t big = (size_t)N_ * HID_ * 4;
  float* T0 = (float*)alloc(big);
  float* T1 = (float*)alloc(big);
  float* T2 = (float*)alloc(big);
  float* B0 = (float*)alloc(big);
  float* B1 = (float*)alloc(big);
  float* B2 = (float*)alloc(big);
  float* B3 = (float*)alloc(big);

  const _Float16* WsT_h = wsp;
  const _Float16* WsT_l = wsp + 8192;
  auto WTh = [&](int j) { return (const _Float16*)(wsp + 16384 + j * 32768); };
  auto WTl = [&](int j) { return (const _Float16*)(wsp + 16384 + j * 32768 + 16384); };
  // j: 0 g0_Wl, 1 g0_Wr, 2 s1_Wp, 3 s1_Wl, 4 s1_Wr, 5 g2_Wl, 6 g2_Wr, 7 s3_Wp, 8 s3_Wl, 9 s3_Wr

  const int EB = (E_ + 255) / 256;
  const int NB256 = (N_ + 255) / 256;
  const int WB = (N_ + 3) / 4;
  const int GB = (N_ + 63) / 64;

  // ---- CSR build ----
  hipMemsetAsync(deg_cursor, 0, (size_t)N_ * 4, stream);
  hist_kernel<<<EB, 256, 0, stream>>>(ei + E_, deg_cursor, E_);
  scan1_kernel<<<NB256, 256, 0, stream>>>(deg_cursor, rowptr, bscan, N_);
  scan2_kernel<<<1, 256, 0, stream>>>(bscan, NB256);
  scan3_kernel<<<NB256, 256, 0, stream>>>(rowptr, deg_cursor, bscan, N_, E_);
  fill_kernel<<<EB, 256, 0, stream>>>(ei, ei + E_, deg_cursor, csr, E_);

  // ---- weight prep ----
  prep_w_kernel<<<(8192 + 10 * 16384 + 255) / 256, 256, 0, stream>>>(
      W_in, W_res, g0_Wl, g0_Wr, s1_Wp, s1_Wl, s1_Wr, g2_Wl, g2_Wr, s3_Wp, s3_Wl, s3_Wr, wsp);
  addv_kernel<<<1, 256, 0, stream>>>(b_in, b_res, bsumf, HID_);

  // ---- input proj: h = x @ (W_in+W_res) + bsum  -> T2 ----
  gemm16<64, ACT_NONE><<<GB, 256, 0, stream>>>(x, WsT_h, WsT_l, bsumf, T2, N_);

  // ---- GAT layer 0 ----
  gemm_dual_gat<<<GB, 256, 0, stream>>>(T2, WTh(0), WTl(0), WTh(1), WTl(1), g0_bl, g0_br,
                                        T0, T1, N_);
  gat_ln_kernel<<<WB, 256, 0, stream>>>(T0, T1, g0_att, g0_bias, rowptr, csr,
                                        ln_g + 0 * 128, ln_b + 0 * 128, B0, N_);

  // ---- SAGE layer 1 ----
  gemm16<128, ACT_RELU><<<GB, 256, 0, stream>>>(B0, WTh(2), WTl(2), s1_bp, T0, N_);  // xp
  sage_agg_kernel<<<WB, 256, 0, stream>>>(T0, rowptr, csr, T1, N_);                  // mean
  gemm_dual_sage<<<GB, 256, 0, stream>>>(T1, WTh(3), WTl(3), B0, WTh(4), WTl(4), s1_bl,
                                         ln_g + 1 * 128, ln_b + 1 * 128, B1, N_);

  // ---- GAT layer 2 ----
  gemm_dual_gat<<<GB, 256, 0, stream>>>(B1, WTh(5), WTl(5), WTh(6), WTl(6), g2_bl, g2_br,
                                        T0, T1, N_);
  gat_ln_kernel<<<WB, 256, 0, stream>>>(T0, T1, g2_att, g2_bias, rowptr, csr,
                                        ln_g + 2 * 128, ln_b + 2 * 128, B2, N_);

  // ---- SAGE layer 3 ----
  gemm16<128, ACT_RELU><<<GB, 256, 0, stream>>>(B2, WTh(7), WTl(7), s3_bp, T0, N_);
  sage_agg_kernel<<<WB, 256, 0, stream>>>(T0, rowptr, csr, T1, N_);
  gemm_dual_sage<<<GB, 256, 0, stream>>>(T1, WTh(8), WTl(8), B2, WTh(9), WTl(9), s3_bl,
                                         ln_g + 3 * 128, ln_b + 3 * 128, B3, N_);

  // ---- JK max + gate + pool + MLP ----
  hipMemsetAsync(pooled, 0, (size_t)G_ * HID_ * 4, stream);
  hipMemsetAsync(cntf, 0, (size_t)G_ * 4, stream);
  {
    const int chunk = 12;
    int nwaves = (N_ + chunk - 1) / chunk;
    int nblocks = (nwaves + 3) / 4;
    jk_pool_kernel<<<nblocks, 256, 0, stream>>>(B0, B1, B2, B3, Wap, bap, batch,
                                                pooled, cntf, N_, chunk);
  }
  mlp_kernel<<<G_, 128, 0, stream>>>(pooled, cntf, Wc1, bc1, a1, Wc2, bc2, a2, Wc3, bc3, out);
}

// Round 6
// 863.568 us; speedup vs baseline: 1.7177x; 1.0461x over previous
//
#include <hip/hip_runtime.h>
#include <math.h>

constexpr int N_ = 50000;
constexpr int E_ = 800000;
constexpr int IN_ = 64;
constexpr int HID_ = 128;
constexpr int G_ = 64;
constexpr float NEG_ = 0.2f;
constexpr float LOG2E_ = 1.44269504088896340736f;

#define ACT_NONE 0
#define ACT_RELU 1

typedef _Float16 half8 __attribute__((ext_vector_type(8)));
typedef _Float16 half2v __attribute__((ext_vector_type(2)));
typedef float floatx4 __attribute__((ext_vector_type(4)));

// ---------------- CSR build ----------------
__global__ __launch_bounds__(256) void hist_kernel(const int* __restrict__ dst,
                                                   int* __restrict__ deg, int e) {
  int i = blockIdx.x * 256 + threadIdx.x;
  if (i < e) atomicAdd(&deg[dst[i]], 1);
}

__global__ __launch_bounds__(256) void scan1_kernel(const int* __restrict__ deg,
                                                    int* __restrict__ excl,
                                                    int* __restrict__ bscan, int n) {
  __shared__ int sh[256];
  int t = threadIdx.x;
  int i = blockIdx.x * 256 + t;
  int v = (i < n) ? deg[i] : 0;
  sh[t] = v;
  __syncthreads();
  for (int off = 1; off < 256; off <<= 1) {
    int y = (t >= off) ? sh[t - off] : 0;
    __syncthreads();
    sh[t] += y;
    __syncthreads();
  }
  int incl = sh[t];
  if (i < n) excl[i] = incl - v;
  if (t == 255) bscan[blockIdx.x] = incl;
}

__global__ __launch_bounds__(256) void scan2_kernel(int* __restrict__ data, int nb) {
  __shared__ int sh[256];
  int t = threadIdx.x;
  int v = (t < nb) ? data[t] : 0;
  sh[t] = v;
  __syncthreads();
  for (int off = 1; off < 256; off <<= 1) {
    int y = (t >= off) ? sh[t - off] : 0;
    __syncthreads();
    sh[t] += y;
    __syncthreads();
  }
  if (t < nb) data[t] = sh[t] - v;  // exclusive
}

__global__ __launch_bounds__(256) void scan3_kernel(int* __restrict__ rowptr,
                                                    int* __restrict__ cursor,
                                                    const int* __restrict__ bscan,
                                                    int n, int e) {
  int i = blockIdx.x * 256 + threadIdx.x;
  if (i < n) {
    int v = rowptr[i] + bscan[blockIdx.x];
    rowptr[i] = v;
    cursor[i] = v;
  }
  if (i == n) rowptr[n] = e;
}

__global__ __launch_bounds__(256) void fill_kernel(const int* __restrict__ src,
                                                   const int* __restrict__ dst,
                                                   int* __restrict__ cursor,
                                                   int* __restrict__ csr, int e) {
  int i = blockIdx.x * 256 + threadIdx.x;
  if (i < e) {
    int d = dst[i];
    int p = atomicAdd(&cursor[d], 1);
    csr[p] = src[i];
  }
}

// ---------------- bias sum ----------------
__global__ __launch_bounds__(256) void addv_kernel(const float* __restrict__ a,
                                                   const float* __restrict__ b,
                                                   float* __restrict__ o, int n) {
  int i = blockIdx.x * 256 + threadIdx.x;
  if (i < n) o[i] = a[i] + b[i];
}

// ---------------- weight prep: transpose + fp16 hi/lo split ----------------
__global__ __launch_bounds__(256) void prep_w_kernel(
    const float* __restrict__ W_in, const float* __restrict__ W_res,
    const float* __restrict__ m0, const float* __restrict__ m1,
    const float* __restrict__ m2, const float* __restrict__ m3,
    const float* __restrict__ m4, const float* __restrict__ m5,
    const float* __restrict__ m6, const float* __restrict__ m7,
    const float* __restrict__ m8, const float* __restrict__ m9,
    _Float16* __restrict__ dst) {
  int idx = blockIdx.x * 256 + threadIdx.x;
  if (idx < 8192) {
    int n = idx >> 6, k = idx & 63;
    float v = W_in[k * 128 + n] + W_res[k * 128 + n];
    _Float16 h = (_Float16)v;
    dst[idx] = h;
    dst[8192 + idx] = (_Float16)(v - (float)h);
  } else if (idx < 8192 + 10 * 16384) {
    int r = idx - 8192;
    int j = r >> 14;
    int e = r & 16383;
    int n = e >> 7, k = e & 127;
    const float* S;
    switch (j) {
      case 0: S = m0; break; case 1: S = m1; break; case 2: S = m2; break;
      case 3: S = m3; break; case 4: S = m4; break; case 5: S = m5; break;
      case 6: S = m6; break; case 7: S = m7; break; case 8: S = m8; break;
      default: S = m9; break;
    }
    float v = S[k * 128 + n];
    _Float16 h = (_Float16)v;
    _Float16* base = dst + 16384 + j * 32768;
    base[e] = h;                       // e == n*128+k
    base[16384 + e] = (_Float16)(v - (float)h);
  }
}

// ---------------- fp16 hi/lo split of 8 consecutive floats ----------------
__device__ inline void split8(const float* __restrict__ p, half8& h, half8& l) {
  float4 a = *reinterpret_cast<const float4*>(p);
  float4 b = *reinterpret_cast<const float4*>(p + 4);
  float v0 = a.x, v1 = a.y, v2 = a.z, v3 = a.w;
  float v4 = b.x, v5 = b.y, v6 = b.z, v7 = b.w;
  _Float16 h0 = (_Float16)v0, h1 = (_Float16)v1, h2 = (_Float16)v2, h3 = (_Float16)v3;
  _Float16 h4 = (_Float16)v4, h5 = (_Float16)v5, h6 = (_Float16)v6, h7 = (_Float16)v7;
  h[0] = h0; h[1] = h1; h[2] = h2; h[3] = h3; h[4] = h4; h[5] = h5; h[6] = h6; h[7] = h7;
  l[0] = (_Float16)(v0 - (float)h0); l[1] = (_Float16)(v1 - (float)h1);
  l[2] = (_Float16)(v2 - (float)h2); l[3] = (_Float16)(v3 - (float)h3);
  l[4] = (_Float16)(v4 - (float)h4); l[5] = (_Float16)(v5 - (float)h5);
  l[6] = (_Float16)(v6 - (float)h6); l[7] = (_Float16)(v7 - (float)h7);
}

// ---------------- single MFMA GEMM: C = act(A[M,K]@W + bias), OutT in {float,_Float16} ----------------
template <int K1, int ACT, typename OutT>
__global__ __launch_bounds__(256) void gemm16(const float* __restrict__ A,
                                              const _Float16* __restrict__ Wh,
                                              const _Float16* __restrict__ Wl,
                                              const float* __restrict__ bias,
                                              OutT* __restrict__ C, int M) {
  const int t = threadIdx.x;
  const int wave = t >> 6, lane = t & 63;
  const int quad = lane >> 4, l16 = lane & 15;
  const int r0 = blockIdx.x * 64 + wave * 16;
  int arow = r0 + l16;
  if (arow >= M) arow = M - 1;

  floatx4 acc[8];
#pragma unroll
  for (int i = 0; i < 8; ++i) acc[i] = (floatx4){0.f, 0.f, 0.f, 0.f};

#pragma unroll
  for (int kk = 0; kk < K1; kk += 32) {
    half8 ah, al;
    split8(A + (size_t)arow * K1 + kk + quad * 8, ah, al);
#pragma unroll
    for (int nt = 0; nt < 8; ++nt) {
      size_t woff = (size_t)(nt * 16 + l16) * K1 + kk + quad * 8;
      half8 wh = *reinterpret_cast<const half8*>(Wh + woff);
      half8 wl = *reinterpret_cast<const half8*>(Wl + woff);
      acc[nt] = __builtin_amdgcn_mfma_f32_16x16x32_f16(ah, wh, acc[nt], 0, 0, 0);
      acc[nt] = __builtin_amdgcn_mfma_f32_16x16x32_f16(ah, wl, acc[nt], 0, 0, 0);
      acc[nt] = __builtin_amdgcn_mfma_f32_16x16x32_f16(al, wh, acc[nt], 0, 0, 0);
    }
  }

#pragma unroll
  for (int nt = 0; nt < 8; ++nt) {
    float b = bias[nt * 16 + l16];
#pragma unroll
    for (int reg = 0; reg < 4; ++reg) {
      int r = r0 + quad * 4 + reg;
      if (r < M) {
        float v = acc[nt][reg] + b;
        if (ACT == ACT_RELU) v = fmaxf(v, 0.f);
        C[(size_t)r * 128 + nt * 16 + l16] = (OutT)v;
      }
    }
  }
}

// ---------------- dual-output GEMM (GAT): xl/xr written as fp16 ----------------
__global__ __launch_bounds__(256) void gemm_dual_gat(const float* __restrict__ A,
                                                     const _Float16* __restrict__ W0h,
                                                     const _Float16* __restrict__ W0l,
                                                     const _Float16* __restrict__ W1h,
                                                     const _Float16* __restrict__ W1l,
                                                     const float* __restrict__ b0,
                                                     const float* __restrict__ b1,
                                                     _Float16* __restrict__ C0,
                                                     _Float16* __restrict__ C1, int M) {
  const int t = threadIdx.x;
  const int wave = t >> 6, lane = t & 63;
  const int quad = lane >> 4, l16 = lane & 15;
  const int r0 = blockIdx.x * 64 + wave * 16;
  int arow = r0 + l16;
  if (arow >= M) arow = M - 1;

  floatx4 acc0[8], acc1[8];
#pragma unroll
  for (int i = 0; i < 8; ++i) {
    acc0[i] = (floatx4){0.f, 0.f, 0.f, 0.f};
    acc1[i] = (floatx4){0.f, 0.f, 0.f, 0.f};
  }

#pragma unroll
  for (int kk = 0; kk < 128; kk += 32) {
    half8 ah, al;
    split8(A + (size_t)arow * 128 + kk + quad * 8, ah, al);
#pragma unroll
    for (int nt = 0; nt < 8; ++nt) {
      size_t woff = (size_t)(nt * 16 + l16) * 128 + kk + quad * 8;
      half8 w0h = *reinterpret_cast<const half8*>(W0h + woff);
      half8 w0l = *reinterpret_cast<const half8*>(W0l + woff);
      half8 w1h = *reinterpret_cast<const half8*>(W1h + woff);
      half8 w1l = *reinterpret_cast<const half8*>(W1l + woff);
      acc0[nt] = __builtin_amdgcn_mfma_f32_16x16x32_f16(ah, w0h, acc0[nt], 0, 0, 0);
      acc0[nt] = __builtin_amdgcn_mfma_f32_16x16x32_f16(ah, w0l, acc0[nt], 0, 0, 0);
      acc0[nt] = __builtin_amdgcn_mfma_f32_16x16x32_f16(al, w0h, acc0[nt], 0, 0, 0);
      acc1[nt] = __builtin_amdgcn_mfma_f32_16x16x32_f16(ah, w1h, acc1[nt], 0, 0, 0);
      acc1[nt] = __builtin_amdgcn_mfma_f32_16x16x32_f16(ah, w1l, acc1[nt], 0, 0, 0);
      acc1[nt] = __builtin_amdgcn_mfma_f32_16x16x32_f16(al, w1h, acc1[nt], 0, 0, 0);
    }
  }

#pragma unroll
  for (int nt = 0; nt < 8; ++nt) {
    float bb0 = b0[nt * 16 + l16];
    float bb1 = b1[nt * 16 + l16];
#pragma unroll
    for (int reg = 0; reg < 4; ++reg) {
      int r = r0 + quad * 4 + reg;
      if (r < M) {
        C0[(size_t)r * 128 + nt * 16 + l16] = (_Float16)(acc0[nt][reg] + bb0);
        C1[(size_t)r * 128 + nt * 16 + l16] = (_Float16)(acc1[nt][reg] + bb1);
      }
    }
  }
}

// ---------------- dual-A GEMM (SAGE) + fused L2norm + LN + leaky ----------------
__global__ __launch_bounds__(256) void gemm_dual_sage(const float* __restrict__ A1,
                                                      const _Float16* __restrict__ W1h,
                                                      const _Float16* __restrict__ W1l,
                                                      const float* __restrict__ A2,
                                                      const _Float16* __restrict__ W2h,
                                                      const _Float16* __restrict__ W2l,
                                                      const float* __restrict__ bias,
                                                      const float* __restrict__ lng,
                                                      const float* __restrict__ lnb,
                                                      float* __restrict__ C, int M) {
  const int t = threadIdx.x;
  const int wave = t >> 6, lane = t & 63;
  const int quad = lane >> 4, l16 = lane & 15;
  const int r0 = blockIdx.x * 64 + wave * 16;
  int arow = r0 + l16;
  if (arow >= M) arow = M - 1;

  floatx4 acc[8];
#pragma unroll
  for (int i = 0; i < 8; ++i) acc[i] = (floatx4){0.f, 0.f, 0.f, 0.f};

#pragma unroll
  for (int kk = 0; kk < 128; kk += 32) {
    half8 ah, al;
    split8(A1 + (size_t)arow * 128 + kk + quad * 8, ah, al);
#pragma unroll
    for (int nt = 0; nt < 8; ++nt) {
      size_t woff = (size_t)(nt * 16 + l16) * 128 + kk + quad * 8;
      half8 wh = *reinterpret_cast<const half8*>(W1h + woff);
      half8 wl = *reinterpret_cast<const half8*>(W1l + woff);
      acc[nt] = __builtin_amdgcn_mfma_f32_16x16x32_f16(ah, wh, acc[nt], 0, 0, 0);
      acc[nt] = __builtin_amdgcn_mfma_f32_16x16x32_f16(ah, wl, acc[nt], 0, 0, 0);
      acc[nt] = __builtin_amdgcn_mfma_f32_16x16x32_f16(al, wh, acc[nt], 0, 0, 0);
    }
  }
#pragma unroll
  for (int kk = 0; kk < 128; kk += 32) {
    half8 ah, al;
    split8(A2 + (size_t)arow * 128 + kk + quad * 8, ah, al);
#pragma unroll
    for (int nt = 0; nt < 8; ++nt) {
      size_t woff = (size_t)(nt * 16 + l16) * 128 + kk + quad * 8;
      half8 wh = *reinterpret_cast<const half8*>(W2h + woff);
      half8 wl = *reinterpret_cast<const half8*>(W2l + woff);
      acc[nt] = __builtin_amdgcn_mfma_f32_16x16x32_f16(ah, wh, acc[nt], 0, 0, 0);
      acc[nt] = __builtin_amdgcn_mfma_f32_16x16x32_f16(ah, wl, acc[nt], 0, 0, 0);
      acc[nt] = __builtin_amdgcn_mfma_f32_16x16x32_f16(al, wh, acc[nt], 0, 0, 0);
    }
  }

  float gv[8], bvv[8], bb[8];
#pragma unroll
  for (int nt = 0; nt < 8; ++nt) {
    gv[nt] = lng[nt * 16 + l16];
    bvv[nt] = lnb[nt * 16 + l16];
    bb[nt] = bias[nt * 16 + l16];
  }
#pragma unroll
  for (int reg = 0; reg < 4; ++reg) {
    int r = r0 + quad * 4 + reg;
    float v[8];
    float s2 = 0.f;
#pragma unroll
    for (int nt = 0; nt < 8; ++nt) {
      v[nt] = acc[nt][reg] + bb[nt];
      s2 += v[nt] * v[nt];
    }
#pragma unroll
    for (int off = 1; off < 16; off <<= 1) s2 += __shfl_xor(s2, off, 64);
    float inv = 1.f / fmaxf(sqrtf(s2), 1e-12f);
    float s1 = 0.f;
#pragma unroll
    for (int nt = 0; nt < 8; ++nt) {
      v[nt] *= inv;
      s1 += v[nt];
    }
#pragma unroll
    for (int off = 1; off < 16; off <<= 1) s1 += __shfl_xor(s1, off, 64);
    float mu = s1 * (1.f / 128.f);
    float ex2 = (s2 * inv) * inv * (1.f / 128.f);
    float var = ex2 - mu * mu;
    float rstd = rsqrtf(var + 1e-5f);
    if (r < M) {
#pragma unroll
      for (int nt = 0; nt < 8; ++nt) {
        float o = (v[nt] - mu) * rstd * gv[nt] + bvv[nt];
        o = fmaxf(o, NEG_ * o);
        C[(size_t)r * 128 + nt * 16 + l16] = o;
      }
    }
  }
}

// ---------------- GATv2 + LN + ELU fused; fp16 xl/xr, self-anchored softmax ----------------
// Per edge (packed fp16): pk_add + pk_mul + pk_max for leaky; fp32 dot (att pre-scaled
// by log2e); 3x shfl head-reduce; w = exp2(p2 - m0_self); den += w; acc += w*v.
__global__ __launch_bounds__(256) void gat_ln_kernel(const _Float16* __restrict__ xl,
                                                     const _Float16* __restrict__ xr,
                                                     const float* __restrict__ att,
                                                     const float* __restrict__ gbias,
                                                     const int* __restrict__ rowptr,
                                                     const int* __restrict__ csr,
                                                     const float* __restrict__ lng,
                                                     const float* __restrict__ lnb,
                                                     float* __restrict__ out, int n) {
  int wid = (blockIdx.x * 256 + threadIdx.x) >> 6;
  int lane = threadIdx.x & 63;
  if (wid >= n) return;
  const half2v* __restrict__ xl2 = reinterpret_cast<const half2v*>(xl);
  const half2v xrv = reinterpret_cast<const half2v*>(xr)[wid * 64 + lane];
  float2 atv = reinterpret_cast<const float2*>(att)[lane];
  atv.x *= LOG2E_;  // scores directly in log2 domain
  atv.y *= LOG2E_;
  const half2v negc = {(_Float16)NEG_, (_Float16)NEG_};

  float m0, den;
  float2 acc;
  {  // self loop: anchor
    half2v xv = xl2[wid * 64 + lane];
    half2v zz = xv + xrv;
    half2v zl = __builtin_elementwise_max(zz, zz * negc);
    float p = (float)zl[0] * atv.x + (float)zl[1] * atv.y;
    p += __shfl_xor(p, 1, 64);
    p += __shfl_xor(p, 2, 64);
    p += __shfl_xor(p, 4, 64);
    m0 = p;
    den = 1.f;
    acc = make_float2((float)xv[0], (float)xv[1]);
  }
  int beg = rowptr[wid], end = rowptr[wid + 1];
  for (int base = beg; base < end; base += 64) {
    int nb = end - base;
    if (nb > 64) nb = 64;
    int sl = (base + lane < end) ? csr[base + lane] : 0;
    int s0 = __builtin_amdgcn_readlane(sl, 0);
    half2v vbuf = xl2[s0 * 64 + lane];
    for (int j = 0; j < nb; ++j) {
      half2v xv = vbuf;
      if (j + 1 < nb) {  // wave-uniform prefetch of next gather
        int sn = __builtin_amdgcn_readlane(sl, j + 1);
        vbuf = xl2[sn * 64 + lane];
      }
      half2v zz = xv + xrv;
      half2v zl = __builtin_elementwise_max(zz, zz * negc);
      float p = (float)zl[0] * atv.x + (float)zl[1] * atv.y;
      p += __shfl_xor(p, 1, 64);
      p += __shfl_xor(p, 2, 64);
      p += __shfl_xor(p, 4, 64);
      float w = exp2f(p - m0);
      den += w;
      acc.x += w * (float)xv[0];
      acc.y += w * (float)xv[1];
    }
  }
  float inv = 1.f / (den + 1e-16f);
  const float2 bv = reinterpret_cast<const float2*>(gbias)[lane];
  float o0 = acc.x * inv + bv.x;
  float o1 = acc.y * inv + bv.y;
  // fused LayerNorm + ELU
  float s1 = o0 + o1;
  float s2 = o0 * o0 + o1 * o1;
#pragma unroll
  for (int off = 1; off < 64; off <<= 1) {
    s1 += __shfl_xor(s1, off, 64);
    s2 += __shfl_xor(s2, off, 64);
  }
  float mu = s1 * (1.f / 128.f);
  float var = s2 * (1.f / 128.f) - mu * mu;
  float rstd = rsqrtf(var + 1e-5f);
  float2 gvv = reinterpret_cast<const float2*>(lng)[lane];
  float2 lbv = reinterpret_cast<const float2*>(lnb)[lane];
  float e0 = (o0 - mu) * rstd * gvv.x + lbv.x;
  float e1 = (o1 - mu) * rstd * gvv.y + lbv.y;
  e0 = e0 > 0.f ? e0 : exp2f(e0 * LOG2E_) - 1.f;
  e1 = e1 > 0.f ? e1 : exp2f(e1 * LOG2E_) - 1.f;
  reinterpret_cast<float2*>(out)[wid * 64 + lane] = make_float2(e0, e1);
}

// ---------------- SAGE mean aggregation (fp16 input, readlane, 2-way unroll) ----------------
__global__ __launch_bounds__(256) void sage_agg_kernel(const _Float16* __restrict__ xp,
                                                       const int* __restrict__ rowptr,
                                                       const int* __restrict__ csr,
                                                       float* __restrict__ mean, int n) {
  int wid = (blockIdx.x * 256 + threadIdx.x) >> 6;
  int lane = threadIdx.x & 63;
  if (wid >= n) return;
  const half2v* __restrict__ xp2 = reinterpret_cast<const half2v*>(xp);
  int beg = rowptr[wid], end = rowptr[wid + 1];
  float2 acc0 = make_float2(0.f, 0.f), acc1 = make_float2(0.f, 0.f);
  for (int base = beg; base < end; base += 64) {
    int nb = end - base;
    if (nb > 64) nb = 64;
    int sl = (base + lane < end) ? csr[base + lane] : 0;
    int j = 0;
    for (; j + 2 <= nb; j += 2) {
      int s0 = __builtin_amdgcn_readlane(sl, j);
      int s1i = __builtin_amdgcn_readlane(sl, j + 1);
      half2v v0 = xp2[s0 * 64 + lane];
      half2v v1 = xp2[s1i * 64 + lane];
      acc0.x += (float)v0[0]; acc0.y += (float)v0[1];
      acc1.x += (float)v1[0]; acc1.y += (float)v1[1];
    }
    if (j < nb) {
      int s0 = __builtin_amdgcn_readlane(sl, j);
      half2v v0 = xp2[s0 * 64 + lane];
      acc0.x += (float)v0[0]; acc0.y += (float)v0[1];
    }
  }
  float inv = 1.f / fmaxf((float)(end - beg), 1.f);
  float2 o = make_float2((acc0.x + acc1.x) * inv, (acc0.y + acc1.y) * inv);
  reinterpret_cast<float2*>(mean)[wid * 64 + lane] = o;
}

// ---------------- JK max + sigmoid gate + mean-pool (chunked, few atomics) ----------------
__global__ __launch_bounds__(256) void jk_pool_kernel(const float* __restrict__ x0,
                                                      const float* __restrict__ x1,
                                                      const float* __restrict__ x2,
                                                      const float* __restrict__ x3,
                                                      const float* __restrict__ wap,
                                                      const float* __restrict__ bap,
                                                      const int* __restrict__ batch,
                                                      float* __restrict__ pooled,
                                                      float* __restrict__ cnt, int n,
                                                      int chunk) {
  int wid = (blockIdx.x * 256 + threadIdx.x) >> 6;
  int lane = threadIdx.x & 63;
  int start = wid * chunk;
  if (start >= n) return;
  int end = start + chunk;
  if (end > n) end = n;

  const float2 wv = reinterpret_cast<const float2*>(wap)[lane];
  const float b0 = bap[0];

  int cur = -1;
  float2 acc = make_float2(0.f, 0.f);
  float c = 0.f;

  for (int i = start; i < end; ++i) {
    int off = i * 64 + lane;
    float2 a0 = reinterpret_cast<const float2*>(x0)[off];
    float2 a1 = reinterpret_cast<const float2*>(x1)[off];
    float2 a2 = reinterpret_cast<const float2*>(x2)[off];
    float2 a3 = reinterpret_cast<const float2*>(x3)[off];
    float2 v;
    v.x = fmaxf(fmaxf(a0.x, a1.x), fmaxf(a2.x, a3.x));
    v.y = fmaxf(fmaxf(a0.y, a1.y), fmaxf(a2.y, a3.y));
    float p = v.x * wv.x + v.y * wv.y;
#pragma unroll
    for (int o = 1; o < 64; o <<= 1) p += __shfl_xor(p, o, 64);
    float a = 1.f / (1.f + exp2f(-(p + b0) * LOG2E_));
    int bg = batch[i];
    if (bg != cur) {
      if (cur >= 0) {
        atomicAdd(&pooled[cur * 128 + 2 * lane], acc.x);
        atomicAdd(&pooled[cur * 128 + 2 * lane + 1], acc.y);
        if (lane == 0) atomicAdd(&cnt[cur], c);
      }
      cur = bg;
      acc = make_float2(0.f, 0.f);
      c = 0.f;
    }
    acc.x += v.x * a;
    acc.y += v.y * a;
    c += 1.f;
  }
  if (cur >= 0) {
    atomicAdd(&pooled[cur * 128 + 2 * lane], acc.x);
    atomicAdd(&pooled[cur * 128 + 2 * lane + 1], acc.y);
    if (lane == 0) atomicAdd(&cnt[cur], c);
  }
}

// ---------------- final MLP: one block per graph ----------------
__global__ __launch_bounds__(128) void mlp_kernel(const float* __restrict__ pooled,
                                                  const float* __restrict__ cnt,
                                                  const float* __restrict__ Wc1,
                                                  const float* __restrict__ bc1,
                                                  const float* __restrict__ a1,
                                                  const float* __restrict__ Wc2,
                                                  const float* __restrict__ bc2,
                                                  const float* __restrict__ a2,
                                                  const float* __restrict__ Wc3,
                                                  const float* __restrict__ bc3,
                                                  float* __restrict__ out) {
  __shared__ float sh[128];
  __shared__ float sh2[128];
  __shared__ float sh3[64];
  int g = blockIdx.x, t = threadIdx.x;
  float inv = 1.f / fmaxf(cnt[g], 1.f);
  sh[t] = pooled[g * 128 + t] * inv;
  __syncthreads();
  float z = bc1[t];
  for (int k = 0; k < 128; ++k) z += sh[k] * Wc1[k * 128 + t];
  float al = a1[0];
  z = z >= 0.f ? z : al * z;
  sh2[t] = z;
  __syncthreads();
  if (t < 64) {
    float z2 = bc2[t];
    for (int k = 0; k < 128; ++k) z2 += sh2[k] * Wc2[k * 64 + t];
    float a2v = a2[0];
    z2 = z2 >= 0.f ? z2 : a2v * z2;
    sh3[t] = z2;
  }
  __syncthreads();
  if (t < 2) {
    float o = bc3[t];
    for (int k = 0; k < 64; ++k) o += sh3[k] * Wc3[k * 2 + t];
    out[g * 2 + t] = o;
  }
}

// ================= host =================
extern "C" void kernel_launch(void* const* d_in, const int* in_sizes, int n_in,
                              void* d_out, int out_size, void* d_ws, size_t ws_size,
                              hipStream_t stream) {
  const float* x = (const float*)d_in[0];
  const int* ei = (const int*)d_in[1];
  const int* batch = (const int*)d_in[2];
  const float* W_in = (const float*)d_in[3];
  const float* b_in = (const float*)d_in[4];
  const float* W_res = (const float*)d_in[5];
  const float* b_res = (const float*)d_in[6];
  const float* g0_Wl = (const float*)d_in[7];
  const float* g0_bl = (const float*)d_in[8];
  const float* g0_Wr = (const float*)d_in[9];
  const float* g0_br = (const float*)d_in[10];
  const float* g0_att = (const float*)d_in[11];
  const float* g0_bias = (const float*)d_in[12];
  const float* g2_Wl = (const float*)d_in[13];
  const float* g2_bl = (const float*)d_in[14];
  const float* g2_Wr = (const float*)d_in[15];
  const float* g2_br = (const float*)d_in[16];
  const float* g2_att = (const float*)d_in[17];
  const float* g2_bias = (const float*)d_in[18];
  const float* s1_Wp = (const float*)d_in[19];
  const float* s1_bp = (const float*)d_in[20];
  const float* s1_Wl = (const float*)d_in[21];
  const float* s1_bl = (const float*)d_in[22];
  const float* s1_Wr = (const float*)d_in[23];
  const float* s3_Wp = (const float*)d_in[24];
  const float* s3_bp = (const float*)d_in[25];
  const float* s3_Wl = (const float*)d_in[26];
  const float* s3_bl = (const float*)d_in[27];
  const float* s3_Wr = (const float*)d_in[28];
  const float* ln_g = (const float*)d_in[29];
  const float* ln_b = (const float*)d_in[30];
  const float* Wap = (const float*)d_in[31];
  const float* bap = (const float*)d_in[32];
  const float* Wc1 = (const float*)d_in[33];
  const float* bc1 = (const float*)d_in[34];
  const float* a1 = (const float*)d_in[35];
  const float* Wc2 = (const float*)d_in[36];
  const float* bc2 = (const float*)d_in[37];
  const float* a2 = (const float*)d_in[38];
  const float* Wc3 = (const float*)d_in[39];
  const float* bc3 = (const float*)d_in[40];
  float* out = (float*)d_out;

  char* w = (char*)d_ws;
  auto alloc = [&](size_t bytes) -> void* {
    void* p = (void*)w;
    w += (bytes + 255) & ~(size_t)255;
    return p;
  };
  int* deg_cursor = (int*)alloc((size_t)N_ * 4);
  int* rowptr = (int*)alloc((size_t)(N_ + 1) * 4);
  int* bscan = (int*)alloc(256 * 4);
  int* csr = (int*)alloc((size_t)E_ * 4);
  float* bsumf = (float*)alloc((size_t)HID_ * 4);
  float* pooled = (float*)alloc((size_t)G_ * HID_ * 4);
  float* cntf = (float*)alloc((size_t)G_ * 4);
  _Float16* wsp = (_Float16*)alloc((size_t)(16384 + 10 * 32768) * 2);
  size_t big = (size_t)N_ * HID_ * 4;
  size_t bigh = (size_t)N_ * HID_ * 2;
  float* T1 = (float*)alloc(big);                 // mean
  float* T2 = (float*)alloc(big);                 // input proj out
  _Float16* H0 = (_Float16*)alloc(bigh);          // xl16 / xp16 (reused per layer)
  _Float16* H1 = (_Float16*)alloc(bigh);          // xr16
  float* B0 = (float*)alloc(big);
  float* B1 = (float*)alloc(big);
  float* B2 = (float*)alloc(big);
  float* B3 = (float*)alloc(big);

  const _Float16* WsT_h = wsp;
  const _Float16* WsT_l = wsp + 8192;
  auto WTh = [&](int j) { return (const _Float16*)(wsp + 16384 + j * 32768); };
  auto WTl = [&](int j) { return (const _Float16*)(wsp + 16384 + j * 32768 + 16384); };
  // j: 0 g0_Wl, 1 g0_Wr, 2 s1_Wp, 3 s1_Wl, 4 s1_Wr, 5 g2_Wl, 6 g2_Wr, 7 s3_Wp, 8 s3_Wl, 9 s3_Wr

  const int EB = (E_ + 255) / 256;
  const int NB256 = (N_ + 255) / 256;
  const int WB = (N_ + 3) / 4;
  const int GB = (N_ + 63) / 64;

  // ---- CSR build ----
  hipMemsetAsync(deg_cursor, 0, (size_t)N_ * 4, stream);
  hist_kernel<<<EB, 256, 0, stream>>>(ei + E_, deg_cursor, E_);
  scan1_kernel<<<NB256, 256, 0, stream>>>(deg_cursor, rowptr, bscan, N_);
  scan2_kernel<<<1, 256, 0, stream>>>(bscan, NB256);
  scan3_kernel<<<NB256, 256, 0, stream>>>(rowptr, deg_cursor, bscan, N_, E_);
  fill_kernel<<<EB, 256, 0, stream>>>(ei, ei + E_, deg_cursor, csr, E_);

  // ---- weight prep ----
  prep_w_kernel<<<(8192 + 10 * 16384 + 255) / 256, 256, 0, stream>>>(
      W_in, W_res, g0_Wl, g0_Wr, s1_Wp, s1_Wl, s1_Wr, g2_Wl, g2_Wr, s3_Wp, s3_Wl, s3_Wr, wsp);
  addv_kernel<<<1, 256, 0, stream>>>(b_in, b_res, bsumf, HID_);

  // ---- input proj: h = x @ (W_in+W_res) + bsum  -> T2 ----
  gemm16<64, ACT_NONE, float><<<GB, 256, 0, stream>>>(x, WsT_h, WsT_l, bsumf, T2, N_);

  // ---- GAT layer 0 ----
  gemm_dual_gat<<<GB, 256, 0, stream>>>(T2, WTh(0), WTl(0), WTh(1), WTl(1), g0_bl, g0_br,
                                        H0, H1, N_);
  gat_ln_kernel<<<WB, 256, 0, stream>>>(H0, H1, g0_att, g0_bias, rowptr, csr,
                                        ln_g + 0 * 128, ln_b + 0 * 128, B0, N_);

  // ---- SAGE layer 1 ----
  gemm16<128, ACT_RELU, _Float16><<<GB, 256, 0, stream>>>(B0, WTh(2), WTl(2), s1_bp, H0, N_);
  sage_agg_kernel<<<WB, 256, 0, stream>>>(H0, rowptr, csr, T1, N_);
  gemm_dual_sage<<<GB, 256, 0, stream>>>(T1, WTh(3), WTl(3), B0, WTh(4), WTl(4), s1_bl,
                                         ln_g + 1 * 128, ln_b + 1 * 128, B1, N_);

  // ---- GAT layer 2 ----
  gemm_dual_gat<<<GB, 256, 0, stream>>>(B1, WTh(5), WTl(5), WTh(6), WTl(6), g2_bl, g2_br,
                                        H0, H1, N_);
  gat_ln_kernel<<<WB, 256, 0, stream>>>(H0, H1, g2_att, g2_bias, rowptr, csr,
                                        ln_g + 2 * 128, ln_b + 2 * 128, B2, N_);

  // ---- SAGE layer 3 ----
  gemm16<128, ACT_RELU, _Float16><<<GB, 256, 0, stream>>>(B2, WTh(7), WTl(7), s3_bp, H0, N_);
  sage_agg_kernel<<<WB, 256, 0, stream>>>(H0, rowptr, csr, T1, N_);
  gemm_dual_sage<<<GB, 256, 0, stream>>>(T1, WTh(8), WTl(8), B2, WTh(9), WTl(9), s3_bl,
                                         ln_g + 3 * 128, ln_b + 3 * 128, B3, N_);

  // ---- JK max + gate + pool + MLP ----
  hipMemsetAsync(pooled, 0, (size_t)G_ * HID_ * 4, stream);
  hipMemsetAsync(cntf, 0, (size_t)G_ * 4, stream);
  {
    const int chunk = 12;
    int nwaves = (N_ + chunk - 1) / chunk;
    int nblocks = (nwaves + 3) / 4;
    jk_pool_kernel<<<nblocks, 256, 0, stream>>>(B0, B1, B2, B3, Wap, bap, batch,
                                                pooled, cntf, N_, chunk);
  }
  mlp_kernel<<<G_, 128, 0, stream>>>(pooled, cntf, Wc1, bc1, a1, Wc2, bc2, a2, Wc3, bc3, out);
}

// Round 7
// 728.780 us; speedup vs baseline: 2.0353x; 1.1850x over previous
//
#include <hip/hip_runtime.h>
#include <math.h>

constexpr int N_ = 50000;
constexpr int E_ = 800000;
constexpr int IN_ = 64;
constexpr int HID_ = 128;
constexpr int G_ = 64;
constexpr float NEG_ = 0.2f;
constexpr float LOG2E_ = 1.44269504088896340736f;

#define ACT_NONE 0
#define ACT_RELU 1

typedef _Float16 half8 __attribute__((ext_vector_type(8)));
typedef _Float16 half2v __attribute__((ext_vector_type(2)));
typedef float floatx4 __attribute__((ext_vector_type(4)));

// ---------------- CSR build ----------------
__global__ __launch_bounds__(256) void hist_kernel(const int* __restrict__ dst,
                                                   int* __restrict__ deg, int e) {
  int i = blockIdx.x * 256 + threadIdx.x;
  if (i < e) atomicAdd(&deg[dst[i]], 1);
}

__global__ __launch_bounds__(256) void scan1_kernel(const int* __restrict__ deg,
                                                    int* __restrict__ excl,
                                                    int* __restrict__ bscan, int n) {
  __shared__ int sh[256];
  int t = threadIdx.x;
  int i = blockIdx.x * 256 + t;
  int v = (i < n) ? deg[i] : 0;
  sh[t] = v;
  __syncthreads();
  for (int off = 1; off < 256; off <<= 1) {
    int y = (t >= off) ? sh[t - off] : 0;
    __syncthreads();
    sh[t] += y;
    __syncthreads();
  }
  int incl = sh[t];
  if (i < n) excl[i] = incl - v;
  if (t == 255) bscan[blockIdx.x] = incl;
}

__global__ __launch_bounds__(256) void scan2_kernel(int* __restrict__ data, int nb) {
  __shared__ int sh[256];
  int t = threadIdx.x;
  int v = (t < nb) ? data[t] : 0;
  sh[t] = v;
  __syncthreads();
  for (int off = 1; off < 256; off <<= 1) {
    int y = (t >= off) ? sh[t - off] : 0;
    __syncthreads();
    sh[t] += y;
    __syncthreads();
  }
  if (t < nb) data[t] = sh[t] - v;  // exclusive
}

__global__ __launch_bounds__(256) void scan3_kernel(int* __restrict__ rowptr,
                                                    int* __restrict__ cursor,
                                                    const int* __restrict__ bscan,
                                                    int n, int e) {
  int i = blockIdx.x * 256 + threadIdx.x;
  if (i < n) {
    int v = rowptr[i] + bscan[blockIdx.x];
    rowptr[i] = v;
    cursor[i] = v;
  }
  if (i == n) rowptr[n] = e;
}

__global__ __launch_bounds__(256) void fill_kernel(const int* __restrict__ src,
                                                   const int* __restrict__ dst,
                                                   int* __restrict__ cursor,
                                                   int* __restrict__ csr, int e) {
  int i = blockIdx.x * 256 + threadIdx.x;
  if (i < e) {
    int d = dst[i];
    int p = atomicAdd(&cursor[d], 1);
    csr[p] = src[i];
  }
}

// ---------------- bias sum ----------------
__global__ __launch_bounds__(256) void addv_kernel(const float* __restrict__ a,
                                                   const float* __restrict__ b,
                                                   float* __restrict__ o, int n) {
  int i = blockIdx.x * 256 + threadIdx.x;
  if (i < n) o[i] = a[i] + b[i];
}

// ---------------- weight prep: transpose + fp16 hi/lo split ----------------
__global__ __launch_bounds__(256) void prep_w_kernel(
    const float* __restrict__ W_in, const float* __restrict__ W_res,
    const float* __restrict__ m0, const float* __restrict__ m1,
    const float* __restrict__ m2, const float* __restrict__ m3,
    const float* __restrict__ m4, const float* __restrict__ m5,
    const float* __restrict__ m6, const float* __restrict__ m7,
    const float* __restrict__ m8, const float* __restrict__ m9,
    _Float16* __restrict__ dst) {
  int idx = blockIdx.x * 256 + threadIdx.x;
  if (idx < 8192) {
    int n = idx >> 6, k = idx & 63;
    float v = W_in[k * 128 + n] + W_res[k * 128 + n];
    _Float16 h = (_Float16)v;
    dst[idx] = h;
    dst[8192 + idx] = (_Float16)(v - (float)h);
  } else if (idx < 8192 + 10 * 16384) {
    int r = idx - 8192;
    int j = r >> 14;
    int e = r & 16383;
    int n = e >> 7, k = e & 127;
    const float* S;
    switch (j) {
      case 0: S = m0; break; case 1: S = m1; break; case 2: S = m2; break;
      case 3: S = m3; break; case 4: S = m4; break; case 5: S = m5; break;
      case 6: S = m6; break; case 7: S = m7; break; case 8: S = m8; break;
      default: S = m9; break;
    }
    float v = S[k * 128 + n];
    _Float16 h = (_Float16)v;
    _Float16* base = dst + 16384 + j * 32768;
    base[e] = h;                       // e == n*128+k
    base[16384 + e] = (_Float16)(v - (float)h);
  }
}

// ---------------- fp16 hi/lo split of 8 floats (register form) ----------------
__device__ inline void split8v(float4 a, float4 b, half8& h, half8& l) {
  float v0 = a.x, v1 = a.y, v2 = a.z, v3 = a.w;
  float v4 = b.x, v5 = b.y, v6 = b.z, v7 = b.w;
  _Float16 h0 = (_Float16)v0, h1 = (_Float16)v1, h2 = (_Float16)v2, h3 = (_Float16)v3;
  _Float16 h4 = (_Float16)v4, h5 = (_Float16)v5, h6 = (_Float16)v6, h7 = (_Float16)v7;
  h[0] = h0; h[1] = h1; h[2] = h2; h[3] = h3; h[4] = h4; h[5] = h5; h[6] = h6; h[7] = h7;
  l[0] = (_Float16)(v0 - (float)h0); l[1] = (_Float16)(v1 - (float)h1);
  l[2] = (_Float16)(v2 - (float)h2); l[3] = (_Float16)(v3 - (float)h3);
  l[4] = (_Float16)(v4 - (float)h4); l[5] = (_Float16)(v5 - (float)h5);
  l[6] = (_Float16)(v6 - (float)h6); l[7] = (_Float16)(v7 - (float)h7);
}

// ================= register-weight GEMMs =================
// Wave owns 2 column tiles (32 cols); weights preloaded to VGPRs once, reused
// across 4 row-tiles (64 rows/block). Per-wave global loads: ~32 W + 8-16 A/tile.

// ---- single: C[M,128] = act(A[M,K1]@W + bias) ----
template <int K1, int ACT, typename OutT>
__global__ __launch_bounds__(256, 2) void gemm_rw(const float* __restrict__ A,
                                                  const _Float16* __restrict__ Wh,
                                                  const _Float16* __restrict__ Wl,
                                                  const float* __restrict__ bias,
                                                  OutT* __restrict__ C, int M) {
  constexpr int KK = K1 / 32;
  const int t = threadIdx.x;
  const int wave = t >> 6, lane = t & 63;
  const int quad = lane >> 4, l16 = lane & 15;
  const int nt0 = wave * 2;

  half8 wh[2][KK], wl[2][KK];
  float bb[2];
  int col[2];
#pragma unroll
  for (int i = 0; i < 2; ++i) {
    col[i] = (nt0 + i) * 16 + l16;
    bb[i] = bias[col[i]];
#pragma unroll
    for (int k = 0; k < KK; ++k) {
      size_t off = (size_t)col[i] * K1 + k * 32 + quad * 8;
      wh[i][k] = *reinterpret_cast<const half8*>(Wh + off);
      wl[i][k] = *reinterpret_cast<const half8*>(Wl + off);
    }
  }
  const int r0 = blockIdx.x * 64;
#pragma unroll
  for (int tt = 0; tt < 4; ++tt) {
    int tb = r0 + tt * 16;
    if (tb >= M) break;
    int arow = tb + l16;
    if (arow >= M) arow = M - 1;
    const float* ap = A + (size_t)arow * K1 + quad * 8;
    float4 a0[KK], a1[KK];
#pragma unroll
    for (int k = 0; k < KK; ++k) {
      a0[k] = *reinterpret_cast<const float4*>(ap + k * 32);
      a1[k] = *reinterpret_cast<const float4*>(ap + k * 32 + 4);
    }
    floatx4 acc[2];
    acc[0] = (floatx4){0.f, 0.f, 0.f, 0.f};
    acc[1] = (floatx4){0.f, 0.f, 0.f, 0.f};
#pragma unroll
    for (int k = 0; k < KK; ++k) {
      half8 ah, al;
      split8v(a0[k], a1[k], ah, al);
      acc[0] = __builtin_amdgcn_mfma_f32_16x16x32_f16(ah, wh[0][k], acc[0], 0, 0, 0);
      acc[0] = __builtin_amdgcn_mfma_f32_16x16x32_f16(ah, wl[0][k], acc[0], 0, 0, 0);
      acc[0] = __builtin_amdgcn_mfma_f32_16x16x32_f16(al, wh[0][k], acc[0], 0, 0, 0);
      acc[1] = __builtin_amdgcn_mfma_f32_16x16x32_f16(ah, wh[1][k], acc[1], 0, 0, 0);
      acc[1] = __builtin_amdgcn_mfma_f32_16x16x32_f16(ah, wl[1][k], acc[1], 0, 0, 0);
      acc[1] = __builtin_amdgcn_mfma_f32_16x16x32_f16(al, wh[1][k], acc[1], 0, 0, 0);
    }
#pragma unroll
    for (int i = 0; i < 2; ++i) {
#pragma unroll
      for (int reg = 0; reg < 4; ++reg) {
        int r = tb + quad * 4 + reg;
        if (r < M) {
          float v = acc[i][reg] + bb[i];
          if (ACT == ACT_RELU) v = fmaxf(v, 0.f);
          C[(size_t)r * 128 + col[i]] = (OutT)v;
        }
      }
    }
  }
}

// ---- dual-output (GAT): C0 = A@W0+b0, C1 = A@W1+b1, fp16 outputs ----
__global__ __launch_bounds__(256, 2) void gemm_rw_dual_gat(const float* __restrict__ A,
                                                           const _Float16* __restrict__ W0h,
                                                           const _Float16* __restrict__ W0l,
                                                           const _Float16* __restrict__ W1h,
                                                           const _Float16* __restrict__ W1l,
                                                           const float* __restrict__ b0,
                                                           const float* __restrict__ b1,
                                                           _Float16* __restrict__ C0,
                                                           _Float16* __restrict__ C1, int M) {
  const int t = threadIdx.x;
  const int wave = t >> 6, lane = t & 63;
  const int quad = lane >> 4, l16 = lane & 15;
  const int nt0 = wave * 2;

  half8 w0h[2][4], w0l[2][4], w1h[2][4], w1l[2][4];
  float bb0[2], bb1[2];
  int col[2];
#pragma unroll
  for (int i = 0; i < 2; ++i) {
    col[i] = (nt0 + i) * 16 + l16;
    bb0[i] = b0[col[i]];
    bb1[i] = b1[col[i]];
#pragma unroll
    for (int k = 0; k < 4; ++k) {
      size_t off = (size_t)col[i] * 128 + k * 32 + quad * 8;
      w0h[i][k] = *reinterpret_cast<const half8*>(W0h + off);
      w0l[i][k] = *reinterpret_cast<const half8*>(W0l + off);
      w1h[i][k] = *reinterpret_cast<const half8*>(W1h + off);
      w1l[i][k] = *reinterpret_cast<const half8*>(W1l + off);
    }
  }
  const int r0 = blockIdx.x * 64;
#pragma unroll
  for (int tt = 0; tt < 4; ++tt) {
    int tb = r0 + tt * 16;
    if (tb >= M) break;
    int arow = tb + l16;
    if (arow >= M) arow = M - 1;
    const float* ap = A + (size_t)arow * 128 + quad * 8;
    float4 a0[4], a1[4];
#pragma unroll
    for (int k = 0; k < 4; ++k) {
      a0[k] = *reinterpret_cast<const float4*>(ap + k * 32);
      a1[k] = *reinterpret_cast<const float4*>(ap + k * 32 + 4);
    }
    floatx4 acc0[2], acc1[2];
    acc0[0] = (floatx4){0.f, 0.f, 0.f, 0.f};
    acc0[1] = (floatx4){0.f, 0.f, 0.f, 0.f};
    acc1[0] = (floatx4){0.f, 0.f, 0.f, 0.f};
    acc1[1] = (floatx4){0.f, 0.f, 0.f, 0.f};
#pragma unroll
    for (int k = 0; k < 4; ++k) {
      half8 ah, al;
      split8v(a0[k], a1[k], ah, al);
#pragma unroll
      for (int i = 0; i < 2; ++i) {
        acc0[i] = __builtin_amdgcn_mfma_f32_16x16x32_f16(ah, w0h[i][k], acc0[i], 0, 0, 0);
        acc0[i] = __builtin_amdgcn_mfma_f32_16x16x32_f16(ah, w0l[i][k], acc0[i], 0, 0, 0);
        acc0[i] = __builtin_amdgcn_mfma_f32_16x16x32_f16(al, w0h[i][k], acc0[i], 0, 0, 0);
        acc1[i] = __builtin_amdgcn_mfma_f32_16x16x32_f16(ah, w1h[i][k], acc1[i], 0, 0, 0);
        acc1[i] = __builtin_amdgcn_mfma_f32_16x16x32_f16(ah, w1l[i][k], acc1[i], 0, 0, 0);
        acc1[i] = __builtin_amdgcn_mfma_f32_16x16x32_f16(al, w1h[i][k], acc1[i], 0, 0, 0);
      }
    }
#pragma unroll
    for (int i = 0; i < 2; ++i) {
#pragma unroll
      for (int reg = 0; reg < 4; ++reg) {
        int r = tb + quad * 4 + reg;
        if (r < M) {
          C0[(size_t)r * 128 + col[i]] = (_Float16)(acc0[i][reg] + bb0[i]);
          C1[(size_t)r * 128 + col[i]] = (_Float16)(acc1[i][reg] + bb1[i]);
        }
      }
    }
  }
}

// ---- dual-A (SAGE): C = post(A1@W1 + bias + A2@W2); post = LN(L2norm(row)) + leaky ----
// Row reductions span 4 waves (each owns 32 cols) -> LDS partial reduce per tile.
__global__ __launch_bounds__(256, 2) void gemm_rw_dual_sage(const float* __restrict__ A1,
                                                            const _Float16* __restrict__ W1h,
                                                            const _Float16* __restrict__ W1l,
                                                            const float* __restrict__ A2,
                                                            const _Float16* __restrict__ W2h,
                                                            const _Float16* __restrict__ W2l,
                                                            const float* __restrict__ bias,
                                                            const float* __restrict__ lng,
                                                            const float* __restrict__ lnb,
                                                            float* __restrict__ C, int M) {
  const int t = threadIdx.x;
  const int wave = t >> 6, lane = t & 63;
  const int quad = lane >> 4, l16 = lane & 15;
  const int nt0 = wave * 2;

  half8 w1h[2][4], w1l[2][4], w2h[2][4], w2l[2][4];
  float bb[2], gg[2], lb[2];
  int col[2];
#pragma unroll
  for (int i = 0; i < 2; ++i) {
    col[i] = (nt0 + i) * 16 + l16;
    bb[i] = bias[col[i]];
    gg[i] = lng[col[i]];
    lb[i] = lnb[col[i]];
#pragma unroll
    for (int k = 0; k < 4; ++k) {
      size_t off = (size_t)col[i] * 128 + k * 32 + quad * 8;
      w1h[i][k] = *reinterpret_cast<const half8*>(W1h + off);
      w1l[i][k] = *reinterpret_cast<const half8*>(W1l + off);
      w2h[i][k] = *reinterpret_cast<const half8*>(W2h + off);
      w2l[i][k] = *reinterpret_cast<const half8*>(W2l + off);
    }
  }
  __shared__ float2 red[2][4][16];  // [tile parity][wave][row]
  const int r0 = blockIdx.x * 64;
#pragma unroll 1
  for (int tt = 0; tt < 4; ++tt) {
    int tb = r0 + tt * 16;
    if (tb >= M) break;
    int arow = tb + l16;
    if (arow >= M) arow = M - 1;
    const float* ap1 = A1 + (size_t)arow * 128 + quad * 8;
    const float* ap2 = A2 + (size_t)arow * 128 + quad * 8;
    float4 a0[4], a1[4], c0[4], c1[4];
#pragma unroll
    for (int k = 0; k < 4; ++k) {
      a0[k] = *reinterpret_cast<const float4*>(ap1 + k * 32);
      a1[k] = *reinterpret_cast<const float4*>(ap1 + k * 32 + 4);
      c0[k] = *reinterpret_cast<const float4*>(ap2 + k * 32);
      c1[k] = *reinterpret_cast<const float4*>(ap2 + k * 32 + 4);
    }
    floatx4 acc[2];
    acc[0] = (floatx4){0.f, 0.f, 0.f, 0.f};
    acc[1] = (floatx4){0.f, 0.f, 0.f, 0.f};
#pragma unroll
    for (int k = 0; k < 4; ++k) {
      half8 ah, al;
      split8v(a0[k], a1[k], ah, al);
#pragma unroll
      for (int i = 0; i < 2; ++i) {
        acc[i] = __builtin_amdgcn_mfma_f32_16x16x32_f16(ah, w1h[i][k], acc[i], 0, 0, 0);
        acc[i] = __builtin_amdgcn_mfma_f32_16x16x32_f16(ah, w1l[i][k], acc[i], 0, 0, 0);
        acc[i] = __builtin_amdgcn_mfma_f32_16x16x32_f16(al, w1h[i][k], acc[i], 0, 0, 0);
      }
    }
#pragma unroll
    for (int k = 0; k < 4; ++k) {
      half8 ah, al;
      split8v(c0[k], c1[k], ah, al);
#pragma unroll
      for (int i = 0; i < 2; ++i) {
        acc[i] = __builtin_amdgcn_mfma_f32_16x16x32_f16(ah, w2h[i][k], acc[i], 0, 0, 0);
        acc[i] = __builtin_amdgcn_mfma_f32_16x16x32_f16(ah, w2l[i][k], acc[i], 0, 0, 0);
        acc[i] = __builtin_amdgcn_mfma_f32_16x16x32_f16(al, w2h[i][k], acc[i], 0, 0, 0);
      }
    }
    // per-row partial (s1, s2) over this wave's 32 cols
    float v0[4], v1[4], p1[4], p2[4];
#pragma unroll
    for (int reg = 0; reg < 4; ++reg) {
      v0[reg] = acc[0][reg] + bb[0];
      v1[reg] = acc[1][reg] + bb[1];
      p1[reg] = v0[reg] + v1[reg];
      p2[reg] = v0[reg] * v0[reg] + v1[reg] * v1[reg];
    }
#pragma unroll
    for (int off = 1; off < 16; off <<= 1) {
#pragma unroll
      for (int reg = 0; reg < 4; ++reg) {
        p1[reg] += __shfl_xor(p1[reg], off, 64);
        p2[reg] += __shfl_xor(p2[reg], off, 64);
      }
    }
    int par = tt & 1;
    if (l16 == 0) {
#pragma unroll
      for (int reg = 0; reg < 4; ++reg)
        red[par][wave][quad * 4 + reg] = make_float2(p1[reg], p2[reg]);
    }
    __syncthreads();
#pragma unroll
    for (int reg = 0; reg < 4; ++reg) {
      int rr = quad * 4 + reg;
      float2 q0 = red[par][0][rr], q1 = red[par][1][rr];
      float2 q2 = red[par][2][rr], q3 = red[par][3][rr];
      float s1 = q0.x + q1.x + q2.x + q3.x;
      float s2 = q0.y + q1.y + q2.y + q3.y;
      float inv = 1.f / fmaxf(sqrtf(s2), 1e-12f);
      float mu = s1 * inv * (1.f / 128.f);
      float ex2 = (s2 * inv) * inv * (1.f / 128.f);
      float rstd = rsqrtf(ex2 - mu * mu + 1e-5f);
      int r = tb + rr;
      if (r < M) {
        float o0 = (v0[reg] * inv - mu) * rstd * gg[0] + lb[0];
        float o1 = (v1[reg] * inv - mu) * rstd * gg[1] + lb[1];
        o0 = fmaxf(o0, NEG_ * o0);
        o1 = fmaxf(o1, NEG_ * o1);
        C[(size_t)r * 128 + col[0]] = o0;
        C[(size_t)r * 128 + col[1]] = o1;
      }
    }
  }
}

// ---------------- GATv2 + LN + ELU fused; fp16 xl/xr, self-anchored softmax ----------------
__global__ __launch_bounds__(256) void gat_ln_kernel(const _Float16* __restrict__ xl,
                                                     const _Float16* __restrict__ xr,
                                                     const float* __restrict__ att,
                                                     const float* __restrict__ gbias,
                                                     const int* __restrict__ rowptr,
                                                     const int* __restrict__ csr,
                                                     const float* __restrict__ lng,
                                                     const float* __restrict__ lnb,
                                                     float* __restrict__ out, int n) {
  int wid = (blockIdx.x * 256 + threadIdx.x) >> 6;
  int lane = threadIdx.x & 63;
  if (wid >= n) return;
  const half2v* __restrict__ xl2 = reinterpret_cast<const half2v*>(xl);
  const half2v xrv = reinterpret_cast<const half2v*>(xr)[wid * 64 + lane];
  float2 atv = reinterpret_cast<const float2*>(att)[lane];
  atv.x *= LOG2E_;
  atv.y *= LOG2E_;
  const half2v negc = {(_Float16)NEG_, (_Float16)NEG_};

  float m0, den;
  float2 acc;
  {  // self loop: anchor
    half2v xv = xl2[wid * 64 + lane];
    half2v zz = xv + xrv;
    half2v zl = __builtin_elementwise_max(zz, zz * negc);
    float p = (float)zl[0] * atv.x + (float)zl[1] * atv.y;
    p += __shfl_xor(p, 1, 64);
    p += __shfl_xor(p, 2, 64);
    p += __shfl_xor(p, 4, 64);
    m0 = p;
    den = 1.f;
    acc = make_float2((float)xv[0], (float)xv[1]);
  }
  int beg = rowptr[wid], end = rowptr[wid + 1];
  for (int base = beg; base < end; base += 64) {
    int nb = end - base;
    if (nb > 64) nb = 64;
    int sl = (base + lane < end) ? csr[base + lane] : 0;
    int s0 = __builtin_amdgcn_readlane(sl, 0);
    half2v vbuf = xl2[s0 * 64 + lane];
    for (int j = 0; j < nb; ++j) {
      half2v xv = vbuf;
      if (j + 1 < nb) {
        int sn = __builtin_amdgcn_readlane(sl, j + 1);
        vbuf = xl2[sn * 64 + lane];
      }
      half2v zz = xv + xrv;
      half2v zl = __builtin_elementwise_max(zz, zz * negc);
      float p = (float)zl[0] * atv.x + (float)zl[1] * atv.y;
      p += __shfl_xor(p, 1, 64);
      p += __shfl_xor(p, 2, 64);
      p += __shfl_xor(p, 4, 64);
      float w = exp2f(p - m0);
      den += w;
      acc.x += w * (float)xv[0];
      acc.y += w * (float)xv[1];
    }
  }
  float inv = 1.f / (den + 1e-16f);
  const float2 bv = reinterpret_cast<const float2*>(gbias)[lane];
  float o0 = acc.x * inv + bv.x;
  float o1 = acc.y * inv + bv.y;
  float s1 = o0 + o1;
  float s2 = o0 * o0 + o1 * o1;
#pragma unroll
  for (int off = 1; off < 64; off <<= 1) {
    s1 += __shfl_xor(s1, off, 64);
    s2 += __shfl_xor(s2, off, 64);
  }
  float mu = s1 * (1.f / 128.f);
  float var = s2 * (1.f / 128.f) - mu * mu;
  float rstd = rsqrtf(var + 1e-5f);
  float2 gvv = reinterpret_cast<const float2*>(lng)[lane];
  float2 lbv = reinterpret_cast<const float2*>(lnb)[lane];
  float e0 = (o0 - mu) * rstd * gvv.x + lbv.x;
  float e1 = (o1 - mu) * rstd * gvv.y + lbv.y;
  e0 = e0 > 0.f ? e0 : exp2f(e0 * LOG2E_) - 1.f;
  e1 = e1 > 0.f ? e1 : exp2f(e1 * LOG2E_) - 1.f;
  reinterpret_cast<float2*>(out)[wid * 64 + lane] = make_float2(e0, e1);
}

// ---------------- SAGE mean aggregation (fp16 input, readlane, 2-way unroll) ----------------
__global__ __launch_bounds__(256) void sage_agg_kernel(const _Float16* __restrict__ xp,
                                                       const int* __restrict__ rowptr,
                                                       const int* __restrict__ csr,
                                                       float* __restrict__ mean, int n) {
  int wid = (blockIdx.x * 256 + threadIdx.x) >> 6;
  int lane = threadIdx.x & 63;
  if (wid >= n) return;
  const half2v* __restrict__ xp2 = reinterpret_cast<const half2v*>(xp);
  int beg = rowptr[wid], end = rowptr[wid + 1];
  float2 acc0 = make_float2(0.f, 0.f), acc1 = make_float2(0.f, 0.f);
  for (int base = beg; base < end; base += 64) {
    int nb = end - base;
    if (nb > 64) nb = 64;
    int sl = (base + lane < end) ? csr[base + lane] : 0;
    int j = 0;
    for (; j + 2 <= nb; j += 2) {
      int s0 = __builtin_amdgcn_readlane(sl, j);
      int s1i = __builtin_amdgcn_readlane(sl, j + 1);
      half2v v0 = xp2[s0 * 64 + lane];
      half2v v1 = xp2[s1i * 64 + lane];
      acc0.x += (float)v0[0]; acc0.y += (float)v0[1];
      acc1.x += (float)v1[0]; acc1.y += (float)v1[1];
    }
    if (j < nb) {
      int s0 = __builtin_amdgcn_readlane(sl, j);
      half2v v0 = xp2[s0 * 64 + lane];
      acc0.x += (float)v0[0]; acc0.y += (float)v0[1];
    }
  }
  float inv = 1.f / fmaxf((float)(end - beg), 1.f);
  float2 o = make_float2((acc0.x + acc1.x) * inv, (acc0.y + acc1.y) * inv);
  reinterpret_cast<float2*>(mean)[wid * 64 + lane] = o;
}

// ---------------- JK max + sigmoid gate + mean-pool (chunked, few atomics) ----------------
__global__ __launch_bounds__(256) void jk_pool_kernel(const float* __restrict__ x0,
                                                      const float* __restrict__ x1,
                                                      const float* __restrict__ x2,
                                                      const float* __restrict__ x3,
                                                      const float* __restrict__ wap,
                                                      const float* __restrict__ bap,
                                                      const int* __restrict__ batch,
                                                      float* __restrict__ pooled,
                                                      float* __restrict__ cnt, int n,
                                                      int chunk) {
  int wid = (blockIdx.x * 256 + threadIdx.x) >> 6;
  int lane = threadIdx.x & 63;
  int start = wid * chunk;
  if (start >= n) return;
  int end = start + chunk;
  if (end > n) end = n;

  const float2 wv = reinterpret_cast<const float2*>(wap)[lane];
  const float b0 = bap[0];

  int cur = -1;
  float2 acc = make_float2(0.f, 0.f);
  float c = 0.f;

  for (int i = start; i < end; ++i) {
    int off = i * 64 + lane;
    float2 a0 = reinterpret_cast<const float2*>(x0)[off];
    float2 a1 = reinterpret_cast<const float2*>(x1)[off];
    float2 a2 = reinterpret_cast<const float2*>(x2)[off];
    float2 a3 = reinterpret_cast<const float2*>(x3)[off];
    float2 v;
    v.x = fmaxf(fmaxf(a0.x, a1.x), fmaxf(a2.x, a3.x));
    v.y = fmaxf(fmaxf(a0.y, a1.y), fmaxf(a2.y, a3.y));
    float p = v.x * wv.x + v.y * wv.y;
#pragma unroll
    for (int o = 1; o < 64; o <<= 1) p += __shfl_xor(p, o, 64);
    float a = 1.f / (1.f + exp2f(-(p + b0) * LOG2E_));
    int bg = batch[i];
    if (bg != cur) {
      if (cur >= 0) {
        atomicAdd(&pooled[cur * 128 + 2 * lane], acc.x);
        atomicAdd(&pooled[cur * 128 + 2 * lane + 1], acc.y);
        if (lane == 0) atomicAdd(&cnt[cur], c);
      }
      cur = bg;
      acc = make_float2(0.f, 0.f);
      c = 0.f;
    }
    acc.x += v.x * a;
    acc.y += v.y * a;
    c += 1.f;
  }
  if (cur >= 0) {
    atomicAdd(&pooled[cur * 128 + 2 * lane], acc.x);
    atomicAdd(&pooled[cur * 128 + 2 * lane + 1], acc.y);
    if (lane == 0) atomicAdd(&cnt[cur], c);
  }
}

// ---------------- final MLP: one block per graph ----------------
__global__ __launch_bounds__(128) void mlp_kernel(const float* __restrict__ pooled,
                                                  const float* __restrict__ cnt,
                                                  const float* __restrict__ Wc1,
                                                  const float* __restrict__ bc1,
                                                  const float* __restrict__ a1,
                                                  const float* __restrict__ Wc2,
                                                  const float* __restrict__ bc2,
                                                  const float* __restrict__ a2,
                                                  const float* __restrict__ Wc3,
                                                  const float* __restrict__ bc3,
                                                  float* __restrict__ out) {
  __shared__ float sh[128];
  __shared__ float sh2[128];
  __shared__ float sh3[64];
  int g = blockIdx.x, t = threadIdx.x;
  float inv = 1.f / fmaxf(cnt[g], 1.f);
  sh[t] = pooled[g * 128 + t] * inv;
  __syncthreads();
  float z = bc1[t];
  for (int k = 0; k < 128; ++k) z += sh[k] * Wc1[k * 128 + t];
  float al = a1[0];
  z = z >= 0.f ? z : al * z;
  sh2[t] = z;
  __syncthreads();
  if (t < 64) {
    float z2 = bc2[t];
    for (int k = 0; k < 128; ++k) z2 += sh2[k] * Wc2[k * 64 + t];
    float a2v = a2[0];
    z2 = z2 >= 0.f ? z2 : a2v * z2;
    sh3[t] = z2;
  }
  __syncthreads();
  if (t < 2) {
    float o = bc3[t];
    for (int k = 0; k < 64; ++k) o += sh3[k] * Wc3[k * 2 + t];
    out[g * 2 + t] = o;
  }
}

// ================= host =================
extern "C" void kernel_launch(void* const* d_in, const int* in_sizes, int n_in,
                              void* d_out, int out_size, void* d_ws, size_t ws_size,
                              hipStream_t stream) {
  const float* x = (const float*)d_in[0];
  const int* ei = (const int*)d_in[1];
  const int* batch = (const int*)d_in[2];
  const float* W_in = (const float*)d_in[3];
  const float* b_in = (const float*)d_in[4];
  const float* W_res = (const float*)d_in[5];
  const float* b_res = (const float*)d_in[6];
  const float* g0_Wl = (const float*)d_in[7];
  const float* g0_bl = (const float*)d_in[8];
  const float* g0_Wr = (const float*)d_in[9];
  const float* g0_br = (const float*)d_in[10];
  const float* g0_att = (const float*)d_in[11];
  const float* g0_bias = (const float*)d_in[12];
  const float* g2_Wl = (const float*)d_in[13];
  const float* g2_bl = (const float*)d_in[14];
  const float* g2_Wr = (const float*)d_in[15];
  const float* g2_br = (const float*)d_in[16];
  const float* g2_att = (const float*)d_in[17];
  const float* g2_bias = (const float*)d_in[18];
  const float* s1_Wp = (const float*)d_in[19];
  const float* s1_bp = (const float*)d_in[20];
  const float* s1_Wl = (const float*)d_in[21];
  const float* s1_bl = (const float*)d_in[22];
  const float* s1_Wr = (const float*)d_in[23];
  const float* s3_Wp = (const float*)d_in[24];
  const float* s3_bp = (const float*)d_in[25];
  const float* s3_Wl = (const float*)d_in[26];
  const float* s3_bl = (const float*)d_in[27];
  const float* s3_Wr = (const float*)d_in[28];
  const float* ln_g = (const float*)d_in[29];
  const float* ln_b = (const float*)d_in[30];
  const float* Wap = (const float*)d_in[31];
  const float* bap = (const float*)d_in[32];
  const float* Wc1 = (const float*)d_in[33];
  const float* bc1 = (const float*)d_in[34];
  const float* a1 = (const float*)d_in[35];
  const float* Wc2 = (const float*)d_in[36];
  const float* bc2 = (const float*)d_in[37];
  const float* a2 = (const float*)d_in[38];
  const float* Wc3 = (const float*)d_in[39];
  const float* bc3 = (const float*)d_in[40];
  float* out = (float*)d_out;

  char* w = (char*)d_ws;
  auto alloc = [&](size_t bytes) -> void* {
    void* p = (void*)w;
    w += (bytes + 255) & ~(size_t)255;
    return p;
  };
  int* deg_cursor = (int*)alloc((size_t)N_ * 4);
  int* rowptr = (int*)alloc((size_t)(N_ + 1) * 4);
  int* bscan = (int*)alloc(256 * 4);
  int* csr = (int*)alloc((size_t)E_ * 4);
  float* bsumf = (float*)alloc((size_t)HID_ * 4);
  float* pooled = (float*)alloc((size_t)G_ * HID_ * 4);
  float* cntf = (float*)alloc((size_t)G_ * 4);
  _Float16* wsp = (_Float16*)alloc((size_t)(16384 + 10 * 32768) * 2);
  size_t big = (size_t)N_ * HID_ * 4;
  size_t bigh = (size_t)N_ * HID_ * 2;
  float* T1 = (float*)alloc(big);                 // mean
  float* T2 = (float*)alloc(big);                 // input proj out
  _Float16* H0 = (_Float16*)alloc(bigh);          // xl16 / xp16 (reused per layer)
  _Float16* H1 = (_Float16*)alloc(bigh);          // xr16
  float* B0 = (float*)alloc(big);
  float* B1 = (float*)alloc(big);
  float* B2 = (float*)alloc(big);
  float* B3 = (float*)alloc(big);

  const _Float16* WsT_h = wsp;
  const _Float16* WsT_l = wsp + 8192;
  auto WTh = [&](int j) { return (const _Float16*)(wsp + 16384 + j * 32768); };
  auto WTl = [&](int j) { return (const _Float16*)(wsp + 16384 + j * 32768 + 16384); };
  // j: 0 g0_Wl, 1 g0_Wr, 2 s1_Wp, 3 s1_Wl, 4 s1_Wr, 5 g2_Wl, 6 g2_Wr, 7 s3_Wp, 8 s3_Wl, 9 s3_Wr

  const int EB = (E_ + 255) / 256;
  const int NB256 = (N_ + 255) / 256;
  const int WB = (N_ + 3) / 4;
  const int GB = (N_ + 63) / 64;   // 64 rows per block for gemm_rw*

  // ---- CSR build ----
  hipMemsetAsync(deg_cursor, 0, (size_t)N_ * 4, stream);
  hist_kernel<<<EB, 256, 0, stream>>>(ei + E_, deg_cursor, E_);
  scan1_kernel<<<NB256, 256, 0, stream>>>(deg_cursor, rowptr, bscan, N_);
  scan2_kernel<<<1, 256, 0, stream>>>(bscan, NB256);
  scan3_kernel<<<NB256, 256, 0, stream>>>(rowptr, deg_cursor, bscan, N_, E_);
  fill_kernel<<<EB, 256, 0, stream>>>(ei, ei + E_, deg_cursor, csr, E_);

  // ---- weight prep ----
  prep_w_kernel<<<(8192 + 10 * 16384 + 255) / 256, 256, 0, stream>>>(
      W_in, W_res, g0_Wl, g0_Wr, s1_Wp, s1_Wl, s1_Wr, g2_Wl, g2_Wr, s3_Wp, s3_Wl, s3_Wr, wsp);
  addv_kernel<<<1, 256, 0, stream>>>(b_in, b_res, bsumf, HID_);

  // ---- input proj: h = x @ (W_in+W_res) + bsum  -> T2 ----
  gemm_rw<64, ACT_NONE, float><<<GB, 256, 0, stream>>>(x, WsT_h, WsT_l, bsumf, T2, N_);

  // ---- GAT layer 0 ----
  gemm_rw_dual_gat<<<GB, 256, 0, stream>>>(T2, WTh(0), WTl(0), WTh(1), WTl(1), g0_bl, g0_br,
                                           H0, H1, N_);
  gat_ln_kernel<<<WB, 256, 0, stream>>>(H0, H1, g0_att, g0_bias, rowptr, csr,
                                        ln_g + 0 * 128, ln_b + 0 * 128, B0, N_);

  // ---- SAGE layer 1 ----
  gemm_rw<128, ACT_RELU, _Float16><<<GB, 256, 0, stream>>>(B0, WTh(2), WTl(2), s1_bp, H0, N_);
  sage_agg_kernel<<<WB, 256, 0, stream>>>(H0, rowptr, csr, T1, N_);
  gemm_rw_dual_sage<<<GB, 256, 0, stream>>>(T1, WTh(3), WTl(3), B0, WTh(4), WTl(4), s1_bl,
                                            ln_g + 1 * 128, ln_b + 1 * 128, B1, N_);

  // ---- GAT layer 2 ----
  gemm_rw_dual_gat<<<GB, 256, 0, stream>>>(B1, WTh(5), WTl(5), WTh(6), WTl(6), g2_bl, g2_br,
                                           H0, H1, N_);
  gat_ln_kernel<<<WB, 256, 0, stream>>>(H0, H1, g2_att, g2_bias, rowptr, csr,
                                        ln_g + 2 * 128, ln_b + 2 * 128, B2, N_);

  // ---- SAGE layer 3 ----
  gemm_rw<128, ACT_RELU, _Float16><<<GB, 256, 0, stream>>>(B2, WTh(7), WTl(7), s3_bp, H0, N_);
  sage_agg_kernel<<<WB, 256, 0, stream>>>(H0, rowptr, csr, T1, N_);
  gemm_rw_dual_sage<<<GB, 256, 0, stream>>>(T1, WTh(8), WTl(8), B2, WTh(9), WTl(9), s3_bl,
                                            ln_g + 3 * 128, ln_b + 3 * 128, B3, N_);

  // ---- JK max + gate + pool + MLP ----
  hipMemsetAsync(pooled, 0, (size_t)G_ * HID_ * 4, stream);
  hipMemsetAsync(cntf, 0, (size_t)G_ * 4, stream);
  {
    const int chunk = 12;
    int nwaves = (N_ + chunk - 1) / chunk;
    int nblocks = (nwaves + 3) / 4;
    jk_pool_kernel<<<nblocks, 256, 0, stream>>>(B0, B1, B2, B3, Wap, bap, batch,
                                                pooled, cntf, N_, chunk);
  }
  mlp_kernel<<<G_, 128, 0, stream>>>(pooled, cntf, Wc1, bc1, a1, Wc2, bc2, a2, Wc3, bc3, out);
}

// Round 8
// 720.704 us; speedup vs baseline: 2.0582x; 1.0112x over previous
//
#include <hip/hip_runtime.h>
#include <math.h>

constexpr int N_ = 50000;
constexpr int E_ = 800000;
constexpr int IN_ = 64;
constexpr int HID_ = 128;
constexpr int G_ = 64;
constexpr float NEG_ = 0.2f;
constexpr float LOG2E_ = 1.44269504088896340736f;

#define ACT_NONE 0
#define ACT_RELU 1

typedef _Float16 half8 __attribute__((ext_vector_type(8)));
typedef _Float16 half2v __attribute__((ext_vector_type(2)));
typedef float floatx4 __attribute__((ext_vector_type(4)));

// ---------------- CSR build ----------------
__global__ __launch_bounds__(256) void hist_kernel(const int* __restrict__ dst,
                                                   int* __restrict__ deg, int e) {
  int i = blockIdx.x * 256 + threadIdx.x;
  if (i < e) atomicAdd(&deg[dst[i]], 1);
}

__global__ __launch_bounds__(256) void scan1_kernel(const int* __restrict__ deg,
                                                    int* __restrict__ excl,
                                                    int* __restrict__ bscan, int n) {
  __shared__ int sh[256];
  int t = threadIdx.x;
  int i = blockIdx.x * 256 + t;
  int v = (i < n) ? deg[i] : 0;
  sh[t] = v;
  __syncthreads();
  for (int off = 1; off < 256; off <<= 1) {
    int y = (t >= off) ? sh[t - off] : 0;
    __syncthreads();
    sh[t] += y;
    __syncthreads();
  }
  int incl = sh[t];
  if (i < n) excl[i] = incl - v;
  if (t == 255) bscan[blockIdx.x] = incl;
}

__global__ __launch_bounds__(256) void scan2_kernel(int* __restrict__ data, int nb) {
  __shared__ int sh[256];
  int t = threadIdx.x;
  int v = (t < nb) ? data[t] : 0;
  sh[t] = v;
  __syncthreads();
  for (int off = 1; off < 256; off <<= 1) {
    int y = (t >= off) ? sh[t - off] : 0;
    __syncthreads();
    sh[t] += y;
    __syncthreads();
  }
  if (t < nb) data[t] = sh[t] - v;  // exclusive
}

__global__ __launch_bounds__(256) void scan3_kernel(int* __restrict__ rowptr,
                                                    int* __restrict__ cursor,
                                                    const int* __restrict__ bscan,
                                                    int n, int e) {
  int i = blockIdx.x * 256 + threadIdx.x;
  if (i < n) {
    int v = rowptr[i] + bscan[blockIdx.x];
    rowptr[i] = v;
    cursor[i] = v;
  }
  if (i == n) rowptr[n] = e;
}

__global__ __launch_bounds__(256) void fill_kernel(const int* __restrict__ src,
                                                   const int* __restrict__ dst,
                                                   int* __restrict__ cursor,
                                                   int* __restrict__ csr, int e) {
  int i = blockIdx.x * 256 + threadIdx.x;
  if (i < e) {
    int d = dst[i];
    int p = atomicAdd(&cursor[d], 1);
    csr[p] = src[i];
  }
}

// ---------------- bias sum ----------------
__global__ __launch_bounds__(256) void addv_kernel(const float* __restrict__ a,
                                                   const float* __restrict__ b,
                                                   float* __restrict__ o, int n) {
  int i = blockIdx.x * 256 + threadIdx.x;
  if (i < n) o[i] = a[i] + b[i];
}

// ---------------- weight prep: transpose + fp16 hi/lo split ----------------
__global__ __launch_bounds__(256) void prep_w_kernel(
    const float* __restrict__ W_in, const float* __restrict__ W_res,
    const float* __restrict__ m0, const float* __restrict__ m1,
    const float* __restrict__ m2, const float* __restrict__ m3,
    const float* __restrict__ m4, const float* __restrict__ m5,
    const float* __restrict__ m6, const float* __restrict__ m7,
    const float* __restrict__ m8, const float* __restrict__ m9,
    _Float16* __restrict__ dst) {
  int idx = blockIdx.x * 256 + threadIdx.x;
  if (idx < 8192) {
    int n = idx >> 6, k = idx & 63;
    float v = W_in[k * 128 + n] + W_res[k * 128 + n];
    _Float16 h = (_Float16)v;
    dst[idx] = h;
    dst[8192 + idx] = (_Float16)(v - (float)h);
  } else if (idx < 8192 + 10 * 16384) {
    int r = idx - 8192;
    int j = r >> 14;
    int e = r & 16383;
    int n = e >> 7, k = e & 127;
    const float* S;
    switch (j) {
      case 0: S = m0; break; case 1: S = m1; break; case 2: S = m2; break;
      case 3: S = m3; break; case 4: S = m4; break; case 5: S = m5; break;
      case 6: S = m6; break; case 7: S = m7; break; case 8: S = m8; break;
      default: S = m9; break;
    }
    float v = S[k * 128 + n];
    _Float16 h = (_Float16)v;
    _Float16* base = dst + 16384 + j * 32768;
    base[e] = h;                       // e == n*128+k
    base[16384 + e] = (_Float16)(v - (float)h);
  }
}

// ---------------- fp16 hi/lo split of 8 floats (register form) ----------------
__device__ inline void split8v(float4 a, float4 b, half8& h, half8& l) {
  float v0 = a.x, v1 = a.y, v2 = a.z, v3 = a.w;
  float v4 = b.x, v5 = b.y, v6 = b.z, v7 = b.w;
  _Float16 h0 = (_Float16)v0, h1 = (_Float16)v1, h2 = (_Float16)v2, h3 = (_Float16)v3;
  _Float16 h4 = (_Float16)v4, h5 = (_Float16)v5, h6 = (_Float16)v6, h7 = (_Float16)v7;
  h[0] = h0; h[1] = h1; h[2] = h2; h[3] = h3; h[4] = h4; h[5] = h5; h[6] = h6; h[7] = h7;
  l[0] = (_Float16)(v0 - (float)h0); l[1] = (_Float16)(v1 - (float)h1);
  l[2] = (_Float16)(v2 - (float)h2); l[3] = (_Float16)(v3 - (float)h3);
  l[4] = (_Float16)(v4 - (float)h4); l[5] = (_Float16)(v5 - (float)h5);
  l[6] = (_Float16)(v6 - (float)h6); l[7] = (_Float16)(v7 - (float)h7);
}

// ================= register-weight GEMMs (unchanged from R7) =================
template <int K1, int ACT, typename OutT>
__global__ __launch_bounds__(256, 2) void gemm_rw(const float* __restrict__ A,
                                                  const _Float16* __restrict__ Wh,
                                                  const _Float16* __restrict__ Wl,
                                                  const float* __restrict__ bias,
                                                  OutT* __restrict__ C, int M) {
  constexpr int KK = K1 / 32;
  const int t = threadIdx.x;
  const int wave = t >> 6, lane = t & 63;
  const int quad = lane >> 4, l16 = lane & 15;
  const int nt0 = wave * 2;

  half8 wh[2][KK], wl[2][KK];
  float bb[2];
  int col[2];
#pragma unroll
  for (int i = 0; i < 2; ++i) {
    col[i] = (nt0 + i) * 16 + l16;
    bb[i] = bias[col[i]];
#pragma unroll
    for (int k = 0; k < KK; ++k) {
      size_t off = (size_t)col[i] * K1 + k * 32 + quad * 8;
      wh[i][k] = *reinterpret_cast<const half8*>(Wh + off);
      wl[i][k] = *reinterpret_cast<const half8*>(Wl + off);
    }
  }
  const int r0 = blockIdx.x * 64;
#pragma unroll
  for (int tt = 0; tt < 4; ++tt) {
    int tb = r0 + tt * 16;
    if (tb >= M) break;
    int arow = tb + l16;
    if (arow >= M) arow = M - 1;
    const float* ap = A + (size_t)arow * K1 + quad * 8;
    float4 a0[KK], a1[KK];
#pragma unroll
    for (int k = 0; k < KK; ++k) {
      a0[k] = *reinterpret_cast<const float4*>(ap + k * 32);
      a1[k] = *reinterpret_cast<const float4*>(ap + k * 32 + 4);
    }
    floatx4 acc[2];
    acc[0] = (floatx4){0.f, 0.f, 0.f, 0.f};
    acc[1] = (floatx4){0.f, 0.f, 0.f, 0.f};
#pragma unroll
    for (int k = 0; k < KK; ++k) {
      half8 ah, al;
      split8v(a0[k], a1[k], ah, al);
      acc[0] = __builtin_amdgcn_mfma_f32_16x16x32_f16(ah, wh[0][k], acc[0], 0, 0, 0);
      acc[0] = __builtin_amdgcn_mfma_f32_16x16x32_f16(ah, wl[0][k], acc[0], 0, 0, 0);
      acc[0] = __builtin_amdgcn_mfma_f32_16x16x32_f16(al, wh[0][k], acc[0], 0, 0, 0);
      acc[1] = __builtin_amdgcn_mfma_f32_16x16x32_f16(ah, wh[1][k], acc[1], 0, 0, 0);
      acc[1] = __builtin_amdgcn_mfma_f32_16x16x32_f16(ah, wl[1][k], acc[1], 0, 0, 0);
      acc[1] = __builtin_amdgcn_mfma_f32_16x16x32_f16(al, wh[1][k], acc[1], 0, 0, 0);
    }
#pragma unroll
    for (int i = 0; i < 2; ++i) {
#pragma unroll
      for (int reg = 0; reg < 4; ++reg) {
        int r = tb + quad * 4 + reg;
        if (r < M) {
          float v = acc[i][reg] + bb[i];
          if (ACT == ACT_RELU) v = fmaxf(v, 0.f);
          C[(size_t)r * 128 + col[i]] = (OutT)v;
        }
      }
    }
  }
}

__global__ __launch_bounds__(256, 2) void gemm_rw_dual_gat(const float* __restrict__ A,
                                                           const _Float16* __restrict__ W0h,
                                                           const _Float16* __restrict__ W0l,
                                                           const _Float16* __restrict__ W1h,
                                                           const _Float16* __restrict__ W1l,
                                                           const float* __restrict__ b0,
                                                           const float* __restrict__ b1,
                                                           _Float16* __restrict__ C0,
                                                           _Float16* __restrict__ C1, int M) {
  const int t = threadIdx.x;
  const int wave = t >> 6, lane = t & 63;
  const int quad = lane >> 4, l16 = lane & 15;
  const int nt0 = wave * 2;

  half8 w0h[2][4], w0l[2][4], w1h[2][4], w1l[2][4];
  float bb0[2], bb1[2];
  int col[2];
#pragma unroll
  for (int i = 0; i < 2; ++i) {
    col[i] = (nt0 + i) * 16 + l16;
    bb0[i] = b0[col[i]];
    bb1[i] = b1[col[i]];
#pragma unroll
    for (int k = 0; k < 4; ++k) {
      size_t off = (size_t)col[i] * 128 + k * 32 + quad * 8;
      w0h[i][k] = *reinterpret_cast<const half8*>(W0h + off);
      w0l[i][k] = *reinterpret_cast<const half8*>(W0l + off);
      w1h[i][k] = *reinterpret_cast<const half8*>(W1h + off);
      w1l[i][k] = *reinterpret_cast<const half8*>(W1l + off);
    }
  }
  const int r0 = blockIdx.x * 64;
#pragma unroll
  for (int tt = 0; tt < 4; ++tt) {
    int tb = r0 + tt * 16;
    if (tb >= M) break;
    int arow = tb + l16;
    if (arow >= M) arow = M - 1;
    const float* ap = A + (size_t)arow * 128 + quad * 8;
    float4 a0[4], a1[4];
#pragma unroll
    for (int k = 0; k < 4; ++k) {
      a0[k] = *reinterpret_cast<const float4*>(ap + k * 32);
      a1[k] = *reinterpret_cast<const float4*>(ap + k * 32 + 4);
    }
    floatx4 acc0[2], acc1[2];
    acc0[0] = (floatx4){0.f, 0.f, 0.f, 0.f};
    acc0[1] = (floatx4){0.f, 0.f, 0.f, 0.f};
    acc1[0] = (floatx4){0.f, 0.f, 0.f, 0.f};
    acc1[1] = (floatx4){0.f, 0.f, 0.f, 0.f};
#pragma unroll
    for (int k = 0; k < 4; ++k) {
      half8 ah, al;
      split8v(a0[k], a1[k], ah, al);
#pragma unroll
      for (int i = 0; i < 2; ++i) {
        acc0[i] = __builtin_amdgcn_mfma_f32_16x16x32_f16(ah, w0h[i][k], acc0[i], 0, 0, 0);
        acc0[i] = __builtin_amdgcn_mfma_f32_16x16x32_f16(ah, w0l[i][k], acc0[i], 0, 0, 0);
        acc0[i] = __builtin_amdgcn_mfma_f32_16x16x32_f16(al, w0h[i][k], acc0[i], 0, 0, 0);
        acc1[i] = __builtin_amdgcn_mfma_f32_16x16x32_f16(ah, w1h[i][k], acc1[i], 0, 0, 0);
        acc1[i] = __builtin_amdgcn_mfma_f32_16x16x32_f16(ah, w1l[i][k], acc1[i], 0, 0, 0);
        acc1[i] = __builtin_amdgcn_mfma_f32_16x16x32_f16(al, w1h[i][k], acc1[i], 0, 0, 0);
      }
    }
#pragma unroll
    for (int i = 0; i < 2; ++i) {
#pragma unroll
      for (int reg = 0; reg < 4; ++reg) {
        int r = tb + quad * 4 + reg;
        if (r < M) {
          C0[(size_t)r * 128 + col[i]] = (_Float16)(acc0[i][reg] + bb0[i]);
          C1[(size_t)r * 128 + col[i]] = (_Float16)(acc1[i][reg] + bb1[i]);
        }
      }
    }
  }
}

__global__ __launch_bounds__(256, 2) void gemm_rw_dual_sage(const float* __restrict__ A1,
                                                            const _Float16* __restrict__ W1h,
                                                            const _Float16* __restrict__ W1l,
                                                            const float* __restrict__ A2,
                                                            const _Float16* __restrict__ W2h,
                                                            const _Float16* __restrict__ W2l,
                                                            const float* __restrict__ bias,
                                                            const float* __restrict__ lng,
                                                            const float* __restrict__ lnb,
                                                            float* __restrict__ C, int M) {
  const int t = threadIdx.x;
  const int wave = t >> 6, lane = t & 63;
  const int quad = lane >> 4, l16 = lane & 15;
  const int nt0 = wave * 2;

  half8 w1h[2][4], w1l[2][4], w2h[2][4], w2l[2][4];
  float bb[2], gg[2], lb[2];
  int col[2];
#pragma unroll
  for (int i = 0; i < 2; ++i) {
    col[i] = (nt0 + i) * 16 + l16;
    bb[i] = bias[col[i]];
    gg[i] = lng[col[i]];
    lb[i] = lnb[col[i]];
#pragma unroll
    for (int k = 0; k < 4; ++k) {
      size_t off = (size_t)col[i] * 128 + k * 32 + quad * 8;
      w1h[i][k] = *reinterpret_cast<const half8*>(W1h + off);
      w1l[i][k] = *reinterpret_cast<const half8*>(W1l + off);
      w2h[i][k] = *reinterpret_cast<const half8*>(W2h + off);
      w2l[i][k] = *reinterpret_cast<const half8*>(W2l + off);
    }
  }
  __shared__ float2 red[2][4][16];  // [tile parity][wave][row]
  const int r0 = blockIdx.x * 64;
#pragma unroll 1
  for (int tt = 0; tt < 4; ++tt) {
    int tb = r0 + tt * 16;
    if (tb >= M) break;
    int arow = tb + l16;
    if (arow >= M) arow = M - 1;
    const float* ap1 = A1 + (size_t)arow * 128 + quad * 8;
    const float* ap2 = A2 + (size_t)arow * 128 + quad * 8;
    float4 a0[4], a1[4], c0[4], c1[4];
#pragma unroll
    for (int k = 0; k < 4; ++k) {
      a0[k] = *reinterpret_cast<const float4*>(ap1 + k * 32);
      a1[k] = *reinterpret_cast<const float4*>(ap1 + k * 32 + 4);
      c0[k] = *reinterpret_cast<const float4*>(ap2 + k * 32);
      c1[k] = *reinterpret_cast<const float4*>(ap2 + k * 32 + 4);
    }
    floatx4 acc[2];
    acc[0] = (floatx4){0.f, 0.f, 0.f, 0.f};
    acc[1] = (floatx4){0.f, 0.f, 0.f, 0.f};
#pragma unroll
    for (int k = 0; k < 4; ++k) {
      half8 ah, al;
      split8v(a0[k], a1[k], ah, al);
#pragma unroll
      for (int i = 0; i < 2; ++i) {
        acc[i] = __builtin_amdgcn_mfma_f32_16x16x32_f16(ah, w1h[i][k], acc[i], 0, 0, 0);
        acc[i] = __builtin_amdgcn_mfma_f32_16x16x32_f16(ah, w1l[i][k], acc[i], 0, 0, 0);
        acc[i] = __builtin_amdgcn_mfma_f32_16x16x32_f16(al, w1h[i][k], acc[i], 0, 0, 0);
      }
    }
#pragma unroll
    for (int k = 0; k < 4; ++k) {
      half8 ah, al;
      split8v(c0[k], c1[k], ah, al);
#pragma unroll
      for (int i = 0; i < 2; ++i) {
        acc[i] = __builtin_amdgcn_mfma_f32_16x16x32_f16(ah, w2h[i][k], acc[i], 0, 0, 0);
        acc[i] = __builtin_amdgcn_mfma_f32_16x16x32_f16(ah, w2l[i][k], acc[i], 0, 0, 0);
        acc[i] = __builtin_amdgcn_mfma_f32_16x16x32_f16(al, w2h[i][k], acc[i], 0, 0, 0);
      }
    }
    float v0[4], v1[4], p1[4], p2[4];
#pragma unroll
    for (int reg = 0; reg < 4; ++reg) {
      v0[reg] = acc[0][reg] + bb[0];
      v1[reg] = acc[1][reg] + bb[1];
      p1[reg] = v0[reg] + v1[reg];
      p2[reg] = v0[reg] * v0[reg] + v1[reg] * v1[reg];
    }
#pragma unroll
    for (int off = 1; off < 16; off <<= 1) {
#pragma unroll
      for (int reg = 0; reg < 4; ++reg) {
        p1[reg] += __shfl_xor(p1[reg], off, 64);
        p2[reg] += __shfl_xor(p2[reg], off, 64);
      }
    }
    int par = tt & 1;
    if (l16 == 0) {
#pragma unroll
      for (int reg = 0; reg < 4; ++reg)
        red[par][wave][quad * 4 + reg] = make_float2(p1[reg], p2[reg]);
    }
    __syncthreads();
#pragma unroll
    for (int reg = 0; reg < 4; ++reg) {
      int rr = quad * 4 + reg;
      float2 q0 = red[par][0][rr], q1 = red[par][1][rr];
      float2 q2 = red[par][2][rr], q3 = red[par][3][rr];
      float s1 = q0.x + q1.x + q2.x + q3.x;
      float s2 = q0.y + q1.y + q2.y + q3.y;
      float inv = 1.f / fmaxf(sqrtf(s2), 1e-12f);
      float mu = s1 * inv * (1.f / 128.f);
      float ex2 = (s2 * inv) * inv * (1.f / 128.f);
      float rstd = rsqrtf(ex2 - mu * mu + 1e-5f);
      int r = tb + rr;
      if (r < M) {
        float o0 = (v0[reg] * inv - mu) * rstd * gg[0] + lb[0];
        float o1 = (v1[reg] * inv - mu) * rstd * gg[1] + lb[1];
        o0 = fmaxf(o0, NEG_ * o0);
        o1 = fmaxf(o1, NEG_ * o1);
        C[(size_t)r * 128 + col[0]] = o0;
        C[(size_t)r * 128 + col[1]] = o1;
      }
    }
  }
}

// ---------------- GATv2 + LN + ELU; lane = (head, edge-slot), in-lane 16-ch dot ----------------
// 8 heads x 8 edge slots per wave; each lane gathers its head's 16 fp16 channels
// (2x dwordx4), computes the head dot entirely in-lane, no per-edge cross-lane ops.
// Self-anchored softmax (w = exp2(p - p_self)); e-slot reduce once per node.
__global__ __launch_bounds__(256) void gat_ln_kernel(const _Float16* __restrict__ xl,
                                                     const _Float16* __restrict__ xr,
                                                     const float* __restrict__ att,
                                                     const float* __restrict__ gbias,
                                                     const int* __restrict__ rowptr,
                                                     const int* __restrict__ csr,
                                                     const float* __restrict__ lng,
                                                     const float* __restrict__ lnb,
                                                     float* __restrict__ out, int n) {
  int wid = (blockIdx.x * 256 + threadIdx.x) >> 6;
  int lane = threadIdx.x & 63;
  if (wid >= n) return;
  const int h = lane >> 3, e = lane & 7;
  const _Float16* __restrict__ xh = xl + h * 16;  // per-lane head base

  // per-lane head data
  const half8* xrp = reinterpret_cast<const half8*>(xr + (size_t)wid * 128 + h * 16);
  half8 xr0 = xrp[0], xr1 = xrp[1];
  float attf[16];
#pragma unroll
  for (int i = 0; i < 16; ++i) attf[i] = att[h * 16 + i] * LOG2E_;
  const half8 negc = {(_Float16)NEG_, (_Float16)NEG_, (_Float16)NEG_, (_Float16)NEG_,
                      (_Float16)NEG_, (_Float16)NEG_, (_Float16)NEG_, (_Float16)NEG_};

  // self loop: anchor + init (only e==0 contributes the self term)
  float m0, den;
  float acc[16];
  {
    const half8* sp = reinterpret_cast<const half8*>(xh + (size_t)wid * 128);
    half8 s0 = sp[0], s1 = sp[1];
    half8 z0 = s0 + xr0, z1 = s1 + xr1;
    z0 = __builtin_elementwise_max(z0, z0 * negc);
    z1 = __builtin_elementwise_max(z1, z1 * negc);
    float p = 0.f;
#pragma unroll
    for (int i = 0; i < 8; ++i) {
      p += (float)z0[i] * attf[i];
      p += (float)z1[i] * attf[8 + i];
    }
    m0 = p;
    float w = (e == 0) ? 1.f : 0.f;
    den = w;
#pragma unroll
    for (int i = 0; i < 8; ++i) {
      acc[i] = w * (float)s0[i];
      acc[8 + i] = w * (float)s1[i];
    }
  }

  int beg = rowptr[wid], end = rowptr[wid + 1];
  for (int base = beg; base < end; base += 8) {
    int idx = base + e;
    bool valid = idx < end;
    int ci = valid ? idx : end - 1;
    int s = csr[ci];
    const half8* gp = reinterpret_cast<const half8*>(xh + (size_t)s * 128);
    half8 x0 = gp[0], x1 = gp[1];
    half8 z0 = x0 + xr0, z1 = x1 + xr1;
    z0 = __builtin_elementwise_max(z0, z0 * negc);
    z1 = __builtin_elementwise_max(z1, z1 * negc);
    float p = 0.f;
#pragma unroll
    for (int i = 0; i < 8; ++i) {
      p += (float)z0[i] * attf[i];
      p += (float)z1[i] * attf[8 + i];
    }
    float w = valid ? exp2f(p - m0) : 0.f;
    den += w;
#pragma unroll
    for (int i = 0; i < 8; ++i) {
      acc[i] += w * (float)x0[i];
      acc[8 + i] += w * (float)x1[i];
    }
  }

  // reduce across the 8 edge slots (lanes differing in low 3 bits)
#pragma unroll
  for (int off = 1; off < 8; off <<= 1) {
    den += __shfl_xor(den, off, 64);
#pragma unroll
    for (int i = 0; i < 16; ++i) acc[i] += __shfl_xor(acc[i], off, 64);
  }

  float inv = 1.f / (den + 1e-16f);
  int c = h * 16 + 2 * e;  // this lane's 2 output channels
  float2 bv = reinterpret_cast<const float2*>(gbias + c)[0];
  float o0 = acc[2 * e] * inv + bv.x;
  float o1 = acc[2 * e + 1] * inv + bv.y;
  // fused LayerNorm + ELU (each lane owns exactly its 2 channels)
  float s1 = o0 + o1;
  float s2 = o0 * o0 + o1 * o1;
#pragma unroll
  for (int off = 1; off < 64; off <<= 1) {
    s1 += __shfl_xor(s1, off, 64);
    s2 += __shfl_xor(s2, off, 64);
  }
  float mu = s1 * (1.f / 128.f);
  float var = s2 * (1.f / 128.f) - mu * mu;
  float rstd = rsqrtf(var + 1e-5f);
  float2 gvv = reinterpret_cast<const float2*>(lng + c)[0];
  float2 lbv = reinterpret_cast<const float2*>(lnb + c)[0];
  float e0 = (o0 - mu) * rstd * gvv.x + lbv.x;
  float e1 = (o1 - mu) * rstd * gvv.y + lbv.y;
  e0 = e0 > 0.f ? e0 : exp2f(e0 * LOG2E_) - 1.f;
  e1 = e1 > 0.f ? e1 : exp2f(e1 * LOG2E_) - 1.f;
  *reinterpret_cast<float2*>(out + (size_t)wid * 128 + c) = make_float2(e0, e1);
}

// ---------------- SAGE mean aggregation; lane = (16-ch group, edge-slot) ----------------
__global__ __launch_bounds__(256) void sage_agg_kernel(const _Float16* __restrict__ xp,
                                                       const int* __restrict__ rowptr,
                                                       const int* __restrict__ csr,
                                                       float* __restrict__ mean, int n) {
  int wid = (blockIdx.x * 256 + threadIdx.x) >> 6;
  int lane = threadIdx.x & 63;
  if (wid >= n) return;
  const int g = lane >> 3, e = lane & 7;
  const _Float16* __restrict__ xg = xp + g * 16;

  float acc[16];
#pragma unroll
  for (int i = 0; i < 16; ++i) acc[i] = 0.f;

  int beg = rowptr[wid], end = rowptr[wid + 1];
  for (int base = beg; base < end; base += 8) {
    int idx = base + e;
    bool valid = idx < end;
    int ci = valid ? idx : end - 1;
    int s = csr[ci];
    const half8* gp = reinterpret_cast<const half8*>(xg + (size_t)s * 128);
    half8 x0 = gp[0], x1 = gp[1];
    float w = valid ? 1.f : 0.f;
#pragma unroll
    for (int i = 0; i < 8; ++i) {
      acc[i] += w * (float)x0[i];
      acc[8 + i] += w * (float)x1[i];
    }
  }
#pragma unroll
  for (int off = 1; off < 8; off <<= 1) {
#pragma unroll
    for (int i = 0; i < 16; ++i) acc[i] += __shfl_xor(acc[i], off, 64);
  }
  float inv = 1.f / fmaxf((float)(end - beg), 1.f);
  int c = g * 16 + 2 * e;
  *reinterpret_cast<float2*>(mean + (size_t)wid * 128 + c) =
      make_float2(acc[2 * e] * inv, acc[2 * e + 1] * inv);
}

// ---------------- JK max + sigmoid gate + mean-pool (chunked, few atomics) ----------------
__global__ __launch_bounds__(256) void jk_pool_kernel(const float* __restrict__ x0,
                                                      const float* __restrict__ x1,
                                                      const float* __restrict__ x2,
                                                      const float* __restrict__ x3,
                                                      const float* __restrict__ wap,
                                                      const float* __restrict__ bap,
                                                      const int* __restrict__ batch,
                                                      float* __restrict__ pooled,
                                                      float* __restrict__ cnt, int n,
                                                      int chunk) {
  int wid = (blockIdx.x * 256 + threadIdx.x) >> 6;
  int lane = threadIdx.x & 63;
  int start = wid * chunk;
  if (start >= n) return;
  int end = start + chunk;
  if (end > n) end = n;

  const float2 wv = reinterpret_cast<const float2*>(wap)[lane];
  const float b0 = bap[0];

  int cur = -1;
  float2 acc = make_float2(0.f, 0.f);
  float c = 0.f;

  for (int i = start; i < end; ++i) {
    int off = i * 64 + lane;
    float2 a0 = reinterpret_cast<const float2*>(x0)[off];
    float2 a1 = reinterpret_cast<const float2*>(x1)[off];
    float2 a2 = reinterpret_cast<const float2*>(x2)[off];
    float2 a3 = reinterpret_cast<const float2*>(x3)[off];
    float2 v;
    v.x = fmaxf(fmaxf(a0.x, a1.x), fmaxf(a2.x, a3.x));
    v.y = fmaxf(fmaxf(a0.y, a1.y), fmaxf(a2.y, a3.y));
    float p = v.x * wv.x + v.y * wv.y;
#pragma unroll
    for (int o = 1; o < 64; o <<= 1) p += __shfl_xor(p, o, 64);
    float a = 1.f / (1.f + exp2f(-(p + b0) * LOG2E_));
    int bg = batch[i];
    if (bg != cur) {
      if (cur >= 0) {
        atomicAdd(&pooled[cur * 128 + 2 * lane], acc.x);
        atomicAdd(&pooled[cur * 128 + 2 * lane + 1], acc.y);
        if (lane == 0) atomicAdd(&cnt[cur], c);
      }
      cur = bg;
      acc = make_float2(0.f, 0.f);
      c = 0.f;
    }
    acc.x += v.x * a;
    acc.y += v.y * a;
    c += 1.f;
  }
  if (cur >= 0) {
    atomicAdd(&pooled[cur * 128 + 2 * lane], acc.x);
    atomicAdd(&pooled[cur * 128 + 2 * lane + 1], acc.y);
    if (lane == 0) atomicAdd(&cnt[cur], c);
  }
}

// ---------------- final MLP: one block per graph ----------------
__global__ __launch_bounds__(128) void mlp_kernel(const float* __restrict__ pooled,
                                                  const float* __restrict__ cnt,
                                                  const float* __restrict__ Wc1,
                                                  const float* __restrict__ bc1,
                                                  const float* __restrict__ a1,
                                                  const float* __restrict__ Wc2,
                                                  const float* __restrict__ bc2,
                                                  const float* __restrict__ a2,
                                                  const float* __restrict__ Wc3,
                                                  const float* __restrict__ bc3,
                                                  float* __restrict__ out) {
  __shared__ float sh[128];
  __shared__ float sh2[128];
  __shared__ float sh3[64];
  int g = blockIdx.x, t = threadIdx.x;
  float inv = 1.f / fmaxf(cnt[g], 1.f);
  sh[t] = pooled[g * 128 + t] * inv;
  __syncthreads();
  float z = bc1[t];
  for (int k = 0; k < 128; ++k) z += sh[k] * Wc1[k * 128 + t];
  float al = a1[0];
  z = z >= 0.f ? z : al * z;
  sh2[t] = z;
  __syncthreads();
  if (t < 64) {
    float z2 = bc2[t];
    for (int k = 0; k < 128; ++k) z2 += sh2[k] * Wc2[k * 64 + t];
    float a2v = a2[0];
    z2 = z2 >= 0.f ? z2 : a2v * z2;
    sh3[t] = z2;
  }
  __syncthreads();
  if (t < 2) {
    float o = bc3[t];
    for (int k = 0; k < 64; ++k) o += sh3[k] * Wc3[k * 2 + t];
    out[g * 2 + t] = o;
  }
}

// ================= host =================
extern "C" void kernel_launch(void* const* d_in, const int* in_sizes, int n_in,
                              void* d_out, int out_size, void* d_ws, size_t ws_size,
                              hipStream_t stream) {
  const float* x = (const float*)d_in[0];
  const int* ei = (const int*)d_in[1];
  const int* batch = (const int*)d_in[2];
  const float* W_in = (const float*)d_in[3];
  const float* b_in = (const float*)d_in[4];
  const float* W_res = (const float*)d_in[5];
  const float* b_res = (const float*)d_in[6];
  const float* g0_Wl = (const float*)d_in[7];
  const float* g0_bl = (const float*)d_in[8];
  const float* g0_Wr = (const float*)d_in[9];
  const float* g0_br = (const float*)d_in[10];
  const float* g0_att = (const float*)d_in[11];
  const float* g0_bias = (const float*)d_in[12];
  const float* g2_Wl = (const float*)d_in[13];
  const float* g2_bl = (const float*)d_in[14];
  const float* g2_Wr = (const float*)d_in[15];
  const float* g2_br = (const float*)d_in[16];
  const float* g2_att = (const float*)d_in[17];
  const float* g2_bias = (const float*)d_in[18];
  const float* s1_Wp = (const float*)d_in[19];
  const float* s1_bp = (const float*)d_in[20];
  const float* s1_Wl = (const float*)d_in[21];
  const float* s1_bl = (const float*)d_in[22];
  const float* s1_Wr = (const float*)d_in[23];
  const float* s3_Wp = (const float*)d_in[24];
  const float* s3_bp = (const float*)d_in[25];
  const float* s3_Wl = (const float*)d_in[26];
  const float* s3_bl = (const float*)d_in[27];
  const float* s3_Wr = (const float*)d_in[28];
  const float* ln_g = (const float*)d_in[29];
  const float* ln_b = (const float*)d_in[30];
  const float* Wap = (const float*)d_in[31];
  const float* bap = (const float*)d_in[32];
  const float* Wc1 = (const float*)d_in[33];
  const float* bc1 = (const float*)d_in[34];
  const float* a1 = (const float*)d_in[35];
  const float* Wc2 = (const float*)d_in[36];
  const float* bc2 = (const float*)d_in[37];
  const float* a2 = (const float*)d_in[38];
  const float* Wc3 = (const float*)d_in[39];
  const float* bc3 = (const float*)d_in[40];
  float* out = (float*)d_out;

  char* w = (char*)d_ws;
  auto alloc = [&](size_t bytes) -> void* {
    void* p = (void*)w;
    w += (bytes + 255) & ~(size_t)255;
    return p;
  };
  int* deg_cursor = (int*)alloc((size_t)N_ * 4);
  int* rowptr = (int*)alloc((size_t)(N_ + 1) * 4);
  int* bscan = (int*)alloc(256 * 4);
  int* csr = (int*)alloc((size_t)E_ * 4);
  float* bsumf = (float*)alloc((size_t)HID_ * 4);
  float* pooled = (float*)alloc((size_t)G_ * HID_ * 4);
  float* cntf = (float*)alloc((size_t)G_ * 4);
  _Float16* wsp = (_Float16*)alloc((size_t)(16384 + 10 * 32768) * 2);
  size_t big = (size_t)N_ * HID_ * 4;
  size_t bigh = (size_t)N_ * HID_ * 2;
  float* T1 = (float*)alloc(big);                 // mean
  float* T2 = (float*)alloc(big);                 // input proj out
  _Float16* H0 = (_Float16*)alloc(bigh);          // xl16 / xp16 (reused per layer)
  _Float16* H1 = (_Float16*)alloc(bigh);          // xr16
  float* B0 = (float*)alloc(big);
  float* B1 = (float*)alloc(big);
  float* B2 = (float*)alloc(big);
  float* B3 = (float*)alloc(big);

  const _Float16* WsT_h = wsp;
  const _Float16* WsT_l = wsp + 8192;
  auto WTh = [&](int j) { return (const _Float16*)(wsp + 16384 + j * 32768); };
  auto WTl = [&](int j) { return (const _Float16*)(wsp + 16384 + j * 32768 + 16384); };
  // j: 0 g0_Wl, 1 g0_Wr, 2 s1_Wp, 3 s1_Wl, 4 s1_Wr, 5 g2_Wl, 6 g2_Wr, 7 s3_Wp, 8 s3_Wl, 9 s3_Wr

  const int EB = (E_ + 255) / 256;
  const int NB256 = (N_ + 255) / 256;
  const int WB = (N_ + 3) / 4;
  const int GB = (N_ + 63) / 64;

  // ---- CSR build ----
  hipMemsetAsync(deg_cursor, 0, (size_t)N_ * 4, stream);
  hist_kernel<<<EB, 256, 0, stream>>>(ei + E_, deg_cursor, E_);
  scan1_kernel<<<NB256, 256, 0, stream>>>(deg_cursor, rowptr, bscan, N_);
  scan2_kernel<<<1, 256, 0, stream>>>(bscan, NB256);
  scan3_kernel<<<NB256, 256, 0, stream>>>(rowptr, deg_cursor, bscan, N_, E_);
  fill_kernel<<<EB, 256, 0, stream>>>(ei, ei + E_, deg_cursor, csr, E_);

  // ---- weight prep ----
  prep_w_kernel<<<(8192 + 10 * 16384 + 255) / 256, 256, 0, stream>>>(
      W_in, W_res, g0_Wl, g0_Wr, s1_Wp, s1_Wl, s1_Wr, g2_Wl, g2_Wr, s3_Wp, s3_Wl, s3_Wr, wsp);
  addv_kernel<<<1, 256, 0, stream>>>(b_in, b_res, bsumf, HID_);

  // ---- input proj: h = x @ (W_in+W_res) + bsum  -> T2 ----
  gemm_rw<64, ACT_NONE, float><<<GB, 256, 0, stream>>>(x, WsT_h, WsT_l, bsumf, T2, N_);

  // ---- GAT layer 0 ----
  gemm_rw_dual_gat<<<GB, 256, 0, stream>>>(T2, WTh(0), WTl(0), WTh(1), WTl(1), g0_bl, g0_br,
                                           H0, H1, N_);
  gat_ln_kernel<<<WB, 256, 0, stream>>>(H0, H1, g0_att, g0_bias, rowptr, csr,
                                        ln_g + 0 * 128, ln_b + 0 * 128, B0, N_);

  // ---- SAGE layer 1 ----
  gemm_rw<128, ACT_RELU, _Float16><<<GB, 256, 0, stream>>>(B0, WTh(2), WTl(2), s1_bp, H0, N_);
  sage_agg_kernel<<<WB, 256, 0, stream>>>(H0, rowptr, csr, T1, N_);
  gemm_rw_dual_sage<<<GB, 256, 0, stream>>>(T1, WTh(3), WTl(3), B0, WTh(4), WTl(4), s1_bl,
                                            ln_g + 1 * 128, ln_b + 1 * 128, B1, N_);

  // ---- GAT layer 2 ----
  gemm_rw_dual_gat<<<GB, 256, 0, stream>>>(B1, WTh(5), WTl(5), WTh(6), WTl(6), g2_bl, g2_br,
                                           H0, H1, N_);
  gat_ln_kernel<<<WB, 256, 0, stream>>>(H0, H1, g2_att, g2_bias, rowptr, csr,
                                        ln_g + 2 * 128, ln_b + 2 * 128, B2, N_);

  // ---- SAGE layer 3 ----
  gemm_rw<128, ACT_RELU, _Float16><<<GB, 256, 0, stream>>>(B2, WTh(7), WTl(7), s3_bp, H0, N_);
  sage_agg_kernel<<<WB, 256, 0, stream>>>(H0, rowptr, csr, T1, N_);
  gemm_rw_dual_sage<<<GB, 256, 0, stream>>>(T1, WTh(8), WTl(8), B2, WTh(9), WTl(9), s3_bl,
                                            ln_g + 3 * 128, ln_b + 3 * 128, B3, N_);

  // ---- JK max + gate + pool + MLP ----
  hipMemsetAsync(pooled, 0, (size_t)G_ * HID_ * 4, stream);
  hipMemsetAsync(cntf, 0, (size_t)G_ * 4, stream);
  {
    const int chunk = 12;
    int nwaves = (N_ + chunk - 1) / chunk;
    int nblocks = (nwaves + 3) / 4;
    jk_pool_kernel<<<nblocks, 256, 0, stream>>>(B0, B1, B2, B3, Wap, bap, batch,
                                                pooled, cntf, N_, chunk);
  }
  mlp_kernel<<<G_, 128, 0, stream>>>(pooled, cntf, Wc1, bc1, a1, Wc2, bc2, a2, Wc3, bc3, out);
}

// Round 9
// 714.486 us; speedup vs baseline: 2.0761x; 1.0087x over previous
//
#include <hip/hip_runtime.h>
#include <math.h>

constexpr int N_ = 50000;
constexpr int E_ = 800000;
constexpr int IN_ = 64;
constexpr int HID_ = 128;
constexpr int G_ = 64;
constexpr float NEG_ = 0.2f;
constexpr float LOG2E_ = 1.44269504088896340736f;

#define ACT_NONE 0
#define ACT_RELU 1

typedef _Float16 half8 __attribute__((ext_vector_type(8)));
typedef _Float16 half2v __attribute__((ext_vector_type(2)));
typedef float floatx4 __attribute__((ext_vector_type(4)));

// ---------------- CSR build ----------------
__global__ __launch_bounds__(256) void hist_kernel(const int* __restrict__ dst,
                                                   int* __restrict__ deg, int e) {
  int i = blockIdx.x * 256 + threadIdx.x;
  if (i < e) atomicAdd(&deg[dst[i]], 1);
}

__global__ __launch_bounds__(256) void scan1_kernel(const int* __restrict__ deg,
                                                    int* __restrict__ excl,
                                                    int* __restrict__ bscan, int n) {
  __shared__ int sh[256];
  int t = threadIdx.x;
  int i = blockIdx.x * 256 + t;
  int v = (i < n) ? deg[i] : 0;
  sh[t] = v;
  __syncthreads();
  for (int off = 1; off < 256; off <<= 1) {
    int y = (t >= off) ? sh[t - off] : 0;
    __syncthreads();
    sh[t] += y;
    __syncthreads();
  }
  int incl = sh[t];
  if (i < n) excl[i] = incl - v;
  if (t == 255) bscan[blockIdx.x] = incl;
}

__global__ __launch_bounds__(256) void scan2_kernel(int* __restrict__ data, int nb) {
  __shared__ int sh[256];
  int t = threadIdx.x;
  int v = (t < nb) ? data[t] : 0;
  sh[t] = v;
  __syncthreads();
  for (int off = 1; off < 256; off <<= 1) {
    int y = (t >= off) ? sh[t - off] : 0;
    __syncthreads();
    sh[t] += y;
    __syncthreads();
  }
  if (t < nb) data[t] = sh[t] - v;  // exclusive
}

__global__ __launch_bounds__(256) void scan3_kernel(int* __restrict__ rowptr,
                                                    int* __restrict__ cursor,
                                                    const int* __restrict__ bscan,
                                                    int n, int e) {
  int i = blockIdx.x * 256 + threadIdx.x;
  if (i < n) {
    int v = rowptr[i] + bscan[blockIdx.x];
    rowptr[i] = v;
    cursor[i] = v;
  }
  if (i == n) rowptr[n] = e;
}

__global__ __launch_bounds__(256) void fill_kernel(const int* __restrict__ src,
                                                   const int* __restrict__ dst,
                                                   int* __restrict__ cursor,
                                                   int* __restrict__ csr, int e) {
  int i = blockIdx.x * 256 + threadIdx.x;
  if (i < e) {
    int d = dst[i];
    int p = atomicAdd(&cursor[d], 1);
    csr[p] = src[i];
  }
}

// ---------------- bias sum ----------------
__global__ __launch_bounds__(256) void addv_kernel(const float* __restrict__ a,
                                                   const float* __restrict__ b,
                                                   float* __restrict__ o, int n) {
  int i = blockIdx.x * 256 + threadIdx.x;
  if (i < n) o[i] = a[i] + b[i];
}

// ---------------- weight prep: transpose + fp16 hi/lo split ----------------
__global__ __launch_bounds__(256) void prep_w_kernel(
    const float* __restrict__ W_in, const float* __restrict__ W_res,
    const float* __restrict__ m0, const float* __restrict__ m1,
    const float* __restrict__ m2, const float* __restrict__ m3,
    const float* __restrict__ m4, const float* __restrict__ m5,
    const float* __restrict__ m6, const float* __restrict__ m7,
    const float* __restrict__ m8, const float* __restrict__ m9,
    _Float16* __restrict__ dst) {
  int idx = blockIdx.x * 256 + threadIdx.x;
  if (idx < 8192) {
    int n = idx >> 6, k = idx & 63;
    float v = W_in[k * 128 + n] + W_res[k * 128 + n];
    _Float16 h = (_Float16)v;
    dst[idx] = h;
    dst[8192 + idx] = (_Float16)(v - (float)h);
  } else if (idx < 8192 + 10 * 16384) {
    int r = idx - 8192;
    int j = r >> 14;
    int e = r & 16383;
    int n = e >> 7, k = e & 127;
    const float* S;
    switch (j) {
      case 0: S = m0; break; case 1: S = m1; break; case 2: S = m2; break;
      case 3: S = m3; break; case 4: S = m4; break; case 5: S = m5; break;
      case 6: S = m6; break; case 7: S = m7; break; case 8: S = m8; break;
      default: S = m9; break;
    }
    float v = S[k * 128 + n];
    _Float16 h = (_Float16)v;
    _Float16* base = dst + 16384 + j * 32768;
    base[e] = h;                       // e == n*128+k
    base[16384 + e] = (_Float16)(v - (float)h);
  }
}

// ---------------- fp16 hi/lo split of 8 floats (register form) ----------------
__device__ inline void split8v(float4 a, float4 b, half8& h, half8& l) {
  float v0 = a.x, v1 = a.y, v2 = a.z, v3 = a.w;
  float v4 = b.x, v5 = b.y, v6 = b.z, v7 = b.w;
  _Float16 h0 = (_Float16)v0, h1 = (_Float16)v1, h2 = (_Float16)v2, h3 = (_Float16)v3;
  _Float16 h4 = (_Float16)v4, h5 = (_Float16)v5, h6 = (_Float16)v6, h7 = (_Float16)v7;
  h[0] = h0; h[1] = h1; h[2] = h2; h[3] = h3; h[4] = h4; h[5] = h5; h[6] = h6; h[7] = h7;
  l[0] = (_Float16)(v0 - (float)h0); l[1] = (_Float16)(v1 - (float)h1);
  l[2] = (_Float16)(v2 - (float)h2); l[3] = (_Float16)(v3 - (float)h3);
  l[4] = (_Float16)(v4 - (float)h4); l[5] = (_Float16)(v5 - (float)h5);
  l[6] = (_Float16)(v6 - (float)h6); l[7] = (_Float16)(v7 - (float)h7);
}

// ================= register-weight GEMMs (unchanged) =================
template <int K1, int ACT, typename OutT>
__global__ __launch_bounds__(256, 2) void gemm_rw(const float* __restrict__ A,
                                                  const _Float16* __restrict__ Wh,
                                                  const _Float16* __restrict__ Wl,
                                                  const float* __restrict__ bias,
                                                  OutT* __restrict__ C, int M) {
  constexpr int KK = K1 / 32;
  const int t = threadIdx.x;
  const int wave = t >> 6, lane = t & 63;
  const int quad = lane >> 4, l16 = lane & 15;
  const int nt0 = wave * 2;

  half8 wh[2][KK], wl[2][KK];
  float bb[2];
  int col[2];
#pragma unroll
  for (int i = 0; i < 2; ++i) {
    col[i] = (nt0 + i) * 16 + l16;
    bb[i] = bias[col[i]];
#pragma unroll
    for (int k = 0; k < KK; ++k) {
      size_t off = (size_t)col[i] * K1 + k * 32 + quad * 8;
      wh[i][k] = *reinterpret_cast<const half8*>(Wh + off);
      wl[i][k] = *reinterpret_cast<const half8*>(Wl + off);
    }
  }
  const int r0 = blockIdx.x * 64;
#pragma unroll
  for (int tt = 0; tt < 4; ++tt) {
    int tb = r0 + tt * 16;
    if (tb >= M) break;
    int arow = tb + l16;
    if (arow >= M) arow = M - 1;
    const float* ap = A + (size_t)arow * K1 + quad * 8;
    float4 a0[KK], a1[KK];
#pragma unroll
    for (int k = 0; k < KK; ++k) {
      a0[k] = *reinterpret_cast<const float4*>(ap + k * 32);
      a1[k] = *reinterpret_cast<const float4*>(ap + k * 32 + 4);
    }
    floatx4 acc[2];
    acc[0] = (floatx4){0.f, 0.f, 0.f, 0.f};
    acc[1] = (floatx4){0.f, 0.f, 0.f, 0.f};
#pragma unroll
    for (int k = 0; k < KK; ++k) {
      half8 ah, al;
      split8v(a0[k], a1[k], ah, al);
      acc[0] = __builtin_amdgcn_mfma_f32_16x16x32_f16(ah, wh[0][k], acc[0], 0, 0, 0);
      acc[0] = __builtin_amdgcn_mfma_f32_16x16x32_f16(ah, wl[0][k], acc[0], 0, 0, 0);
      acc[0] = __builtin_amdgcn_mfma_f32_16x16x32_f16(al, wh[0][k], acc[0], 0, 0, 0);
      acc[1] = __builtin_amdgcn_mfma_f32_16x16x32_f16(ah, wh[1][k], acc[1], 0, 0, 0);
      acc[1] = __builtin_amdgcn_mfma_f32_16x16x32_f16(ah, wl[1][k], acc[1], 0, 0, 0);
      acc[1] = __builtin_amdgcn_mfma_f32_16x16x32_f16(al, wh[1][k], acc[1], 0, 0, 0);
    }
#pragma unroll
    for (int i = 0; i < 2; ++i) {
#pragma unroll
      for (int reg = 0; reg < 4; ++reg) {
        int r = tb + quad * 4 + reg;
        if (r < M) {
          float v = acc[i][reg] + bb[i];
          if (ACT == ACT_RELU) v = fmaxf(v, 0.f);
          C[(size_t)r * 128 + col[i]] = (OutT)v;
        }
      }
    }
  }
}

__global__ __launch_bounds__(256, 2) void gemm_rw_dual_gat(const float* __restrict__ A,
                                                           const _Float16* __restrict__ W0h,
                                                           const _Float16* __restrict__ W0l,
                                                           const _Float16* __restrict__ W1h,
                                                           const _Float16* __restrict__ W1l,
                                                           const float* __restrict__ b0,
                                                           const float* __restrict__ b1,
                                                           _Float16* __restrict__ C0,
                                                           _Float16* __restrict__ C1, int M) {
  const int t = threadIdx.x;
  const int wave = t >> 6, lane = t & 63;
  const int quad = lane >> 4, l16 = lane & 15;
  const int nt0 = wave * 2;

  half8 w0h[2][4], w0l[2][4], w1h[2][4], w1l[2][4];
  float bb0[2], bb1[2];
  int col[2];
#pragma unroll
  for (int i = 0; i < 2; ++i) {
    col[i] = (nt0 + i) * 16 + l16;
    bb0[i] = b0[col[i]];
    bb1[i] = b1[col[i]];
#pragma unroll
    for (int k = 0; k < 4; ++k) {
      size_t off = (size_t)col[i] * 128 + k * 32 + quad * 8;
      w0h[i][k] = *reinterpret_cast<const half8*>(W0h + off);
      w0l[i][k] = *reinterpret_cast<const half8*>(W0l + off);
      w1h[i][k] = *reinterpret_cast<const half8*>(W1h + off);
      w1l[i][k] = *reinterpret_cast<const half8*>(W1l + off);
    }
  }
  const int r0 = blockIdx.x * 64;
#pragma unroll
  for (int tt = 0; tt < 4; ++tt) {
    int tb = r0 + tt * 16;
    if (tb >= M) break;
    int arow = tb + l16;
    if (arow >= M) arow = M - 1;
    const float* ap = A + (size_t)arow * 128 + quad * 8;
    float4 a0[4], a1[4];
#pragma unroll
    for (int k = 0; k < 4; ++k) {
      a0[k] = *reinterpret_cast<const float4*>(ap + k * 32);
      a1[k] = *reinterpret_cast<const float4*>(ap + k * 32 + 4);
    }
    floatx4 acc0[2], acc1[2];
    acc0[0] = (floatx4){0.f, 0.f, 0.f, 0.f};
    acc0[1] = (floatx4){0.f, 0.f, 0.f, 0.f};
    acc1[0] = (floatx4){0.f, 0.f, 0.f, 0.f};
    acc1[1] = (floatx4){0.f, 0.f, 0.f, 0.f};
#pragma unroll
    for (int k = 0; k < 4; ++k) {
      half8 ah, al;
      split8v(a0[k], a1[k], ah, al);
#pragma unroll
      for (int i = 0; i < 2; ++i) {
        acc0[i] = __builtin_amdgcn_mfma_f32_16x16x32_f16(ah, w0h[i][k], acc0[i], 0, 0, 0);
        acc0[i] = __builtin_amdgcn_mfma_f32_16x16x32_f16(ah, w0l[i][k], acc0[i], 0, 0, 0);
        acc0[i] = __builtin_amdgcn_mfma_f32_16x16x32_f16(al, w0h[i][k], acc0[i], 0, 0, 0);
        acc1[i] = __builtin_amdgcn_mfma_f32_16x16x32_f16(ah, w1h[i][k], acc1[i], 0, 0, 0);
        acc1[i] = __builtin_amdgcn_mfma_f32_16x16x32_f16(ah, w1l[i][k], acc1[i], 0, 0, 0);
        acc1[i] = __builtin_amdgcn_mfma_f32_16x16x32_f16(al, w1h[i][k], acc1[i], 0, 0, 0);
      }
    }
#pragma unroll
    for (int i = 0; i < 2; ++i) {
#pragma unroll
      for (int reg = 0; reg < 4; ++reg) {
        int r = tb + quad * 4 + reg;
        if (r < M) {
          C0[(size_t)r * 128 + col[i]] = (_Float16)(acc0[i][reg] + bb0[i]);
          C1[(size_t)r * 128 + col[i]] = (_Float16)(acc1[i][reg] + bb1[i]);
        }
      }
    }
  }
}

__global__ __launch_bounds__(256, 2) void gemm_rw_dual_sage(const float* __restrict__ A1,
                                                            const _Float16* __restrict__ W1h,
                                                            const _Float16* __restrict__ W1l,
                                                            const float* __restrict__ A2,
                                                            const _Float16* __restrict__ W2h,
                                                            const _Float16* __restrict__ W2l,
                                                            const float* __restrict__ bias,
                                                            const float* __restrict__ lng,
                                                            const float* __restrict__ lnb,
                                                            float* __restrict__ C, int M) {
  const int t = threadIdx.x;
  const int wave = t >> 6, lane = t & 63;
  const int quad = lane >> 4, l16 = lane & 15;
  const int nt0 = wave * 2;

  half8 w1h[2][4], w1l[2][4], w2h[2][4], w2l[2][4];
  float bb[2], gg[2], lb[2];
  int col[2];
#pragma unroll
  for (int i = 0; i < 2; ++i) {
    col[i] = (nt0 + i) * 16 + l16;
    bb[i] = bias[col[i]];
    gg[i] = lng[col[i]];
    lb[i] = lnb[col[i]];
#pragma unroll
    for (int k = 0; k < 4; ++k) {
      size_t off = (size_t)col[i] * 128 + k * 32 + quad * 8;
      w1h[i][k] = *reinterpret_cast<const half8*>(W1h + off);
      w1l[i][k] = *reinterpret_cast<const half8*>(W1l + off);
      w2h[i][k] = *reinterpret_cast<const half8*>(W2h + off);
      w2l[i][k] = *reinterpret_cast<const half8*>(W2l + off);
    }
  }
  __shared__ float2 red[2][4][16];  // [tile parity][wave][row]
  const int r0 = blockIdx.x * 64;
#pragma unroll 1
  for (int tt = 0; tt < 4; ++tt) {
    int tb = r0 + tt * 16;
    if (tb >= M) break;
    int arow = tb + l16;
    if (arow >= M) arow = M - 1;
    const float* ap1 = A1 + (size_t)arow * 128 + quad * 8;
    const float* ap2 = A2 + (size_t)arow * 128 + quad * 8;
    float4 a0[4], a1[4], c0[4], c1[4];
#pragma unroll
    for (int k = 0; k < 4; ++k) {
      a0[k] = *reinterpret_cast<const float4*>(ap1 + k * 32);
      a1[k] = *reinterpret_cast<const float4*>(ap1 + k * 32 + 4);
      c0[k] = *reinterpret_cast<const float4*>(ap2 + k * 32);
      c1[k] = *reinterpret_cast<const float4*>(ap2 + k * 32 + 4);
    }
    floatx4 acc[2];
    acc[0] = (floatx4){0.f, 0.f, 0.f, 0.f};
    acc[1] = (floatx4){0.f, 0.f, 0.f, 0.f};
#pragma unroll
    for (int k = 0; k < 4; ++k) {
      half8 ah, al;
      split8v(a0[k], a1[k], ah, al);
#pragma unroll
      for (int i = 0; i < 2; ++i) {
        acc[i] = __builtin_amdgcn_mfma_f32_16x16x32_f16(ah, w1h[i][k], acc[i], 0, 0, 0);
        acc[i] = __builtin_amdgcn_mfma_f32_16x16x32_f16(ah, w1l[i][k], acc[i], 0, 0, 0);
        acc[i] = __builtin_amdgcn_mfma_f32_16x16x32_f16(al, w1h[i][k], acc[i], 0, 0, 0);
      }
    }
#pragma unroll
    for (int k = 0; k < 4; ++k) {
      half8 ah, al;
      split8v(c0[k], c1[k], ah, al);
#pragma unroll
      for (int i = 0; i < 2; ++i) {
        acc[i] = __builtin_amdgcn_mfma_f32_16x16x32_f16(ah, w2h[i][k], acc[i], 0, 0, 0);
        acc[i] = __builtin_amdgcn_mfma_f32_16x16x32_f16(ah, w2l[i][k], acc[i], 0, 0, 0);
        acc[i] = __builtin_amdgcn_mfma_f32_16x16x32_f16(al, w2h[i][k], acc[i], 0, 0, 0);
      }
    }
    float v0[4], v1[4], p1[4], p2[4];
#pragma unroll
    for (int reg = 0; reg < 4; ++reg) {
      v0[reg] = acc[0][reg] + bb[0];
      v1[reg] = acc[1][reg] + bb[1];
      p1[reg] = v0[reg] + v1[reg];
      p2[reg] = v0[reg] * v0[reg] + v1[reg] * v1[reg];
    }
#pragma unroll
    for (int off = 1; off < 16; off <<= 1) {
#pragma unroll
      for (int reg = 0; reg < 4; ++reg) {
        p1[reg] += __shfl_xor(p1[reg], off, 64);
        p2[reg] += __shfl_xor(p2[reg], off, 64);
      }
    }
    int par = tt & 1;
    if (l16 == 0) {
#pragma unroll
      for (int reg = 0; reg < 4; ++reg)
        red[par][wave][quad * 4 + reg] = make_float2(p1[reg], p2[reg]);
    }
    __syncthreads();
#pragma unroll
    for (int reg = 0; reg < 4; ++reg) {
      int rr = quad * 4 + reg;
      float2 q0 = red[par][0][rr], q1 = red[par][1][rr];
      float2 q2 = red[par][2][rr], q3 = red[par][3][rr];
      float s1 = q0.x + q1.x + q2.x + q3.x;
      float s2 = q0.y + q1.y + q2.y + q3.y;
      float inv = 1.f / fmaxf(sqrtf(s2), 1e-12f);
      float mu = s1 * inv * (1.f / 128.f);
      float ex2 = (s2 * inv) * inv * (1.f / 128.f);
      float rstd = rsqrtf(ex2 - mu * mu + 1e-5f);
      int r = tb + rr;
      if (r < M) {
        float o0 = (v0[reg] * inv - mu) * rstd * gg[0] + lb[0];
        float o1 = (v1[reg] * inv - mu) * rstd * gg[1] + lb[1];
        o0 = fmaxf(o0, NEG_ * o0);
        o1 = fmaxf(o1, NEG_ * o1);
        C[(size_t)r * 128 + col[0]] = o0;
        C[(size_t)r * 128 + col[1]] = o1;
      }
    }
  }
}

// ---------------- GATv2 + LN + ELU; lane=(head, edge-slot); packed fp16 + v_dot2 ----------------
// Rows loaded as 2x uint4 (dwordx4), each dword bitcast to half2 (pure register
// aliasing). Score math: 8x (pk_add + pk_mul + pk_max + v_dot2_f32_f16). att in
// fp16 with log2e pre-folded (softmax scale-invariant). Accumulate fp32 (fma_mix).
__global__ __launch_bounds__(256) void gat_ln_kernel(const _Float16* __restrict__ xl,
                                                     const _Float16* __restrict__ xr,
                                                     const float* __restrict__ att,
                                                     const float* __restrict__ gbias,
                                                     const int* __restrict__ rowptr,
                                                     const int* __restrict__ csr,
                                                     const float* __restrict__ lng,
                                                     const float* __restrict__ lnb,
                                                     float* __restrict__ out, int n) {
  int wid = (blockIdx.x * 256 + threadIdx.x) >> 6;
  int lane = threadIdx.x & 63;
  if (wid >= n) return;
  const int h = lane >> 3, e = lane & 7;
  const char* __restrict__ xbase = (const char*)(xl + h * 16);  // per-lane head base

  // per-lane head data: xr (8x half2), att (8x half2, log2e folded)
  half2v xr2[8], at2[8];
  {
    const uint4* xrp = reinterpret_cast<const uint4*>(xr + (size_t)wid * 128 + h * 16);
    uint4 u0 = xrp[0], u1 = xrp[1];
    unsigned uu[8] = {u0.x, u0.y, u0.z, u0.w, u1.x, u1.y, u1.z, u1.w};
#pragma unroll
    for (int i = 0; i < 8; ++i) xr2[i] = __builtin_bit_cast(half2v, uu[i]);
    const float2* ap = reinterpret_cast<const float2*>(att + h * 16);
#pragma unroll
    for (int i = 0; i < 8; ++i) {
      float2 a = ap[i];
      at2[i][0] = (_Float16)(a.x * LOG2E_);
      at2[i][1] = (_Float16)(a.y * LOG2E_);
    }
  }
  const half2v negc = {(_Float16)NEG_, (_Float16)NEG_};

  // self loop: anchor + init (only e==0 contributes)
  float m0, den;
  float acc[16];
  {
    const uint4* sp = reinterpret_cast<const uint4*>(xbase + (size_t)wid * 256);
    uint4 u0 = sp[0], u1 = sp[1];
    unsigned uu[8] = {u0.x, u0.y, u0.z, u0.w, u1.x, u1.y, u1.z, u1.w};
    float p = 0.f;
#pragma unroll
    for (int i = 0; i < 8; ++i) {
      half2v x = __builtin_bit_cast(half2v, uu[i]);
      half2v z = x + xr2[i];
      half2v zl = __builtin_elementwise_max(z, z * negc);
      p = __builtin_amdgcn_fdot2(zl, at2[i], p, false);
    }
    m0 = p;
    float w = (e == 0) ? 1.f : 0.f;
    den = w;
#pragma unroll
    for (int i = 0; i < 8; ++i) {
      half2v x = __builtin_bit_cast(half2v, uu[i]);
      acc[2 * i] = w * (float)x[0];
      acc[2 * i + 1] = w * (float)x[1];
    }
  }

  int beg = rowptr[wid], end = rowptr[wid + 1];
  for (int base = beg; base < end; base += 8) {
    int idx = base + e;
    bool valid = idx < end;
    int ci = valid ? idx : end - 1;
    int s = csr[ci];
    const uint4* gp = reinterpret_cast<const uint4*>(xbase + (size_t)s * 256);
    uint4 u0 = gp[0], u1 = gp[1];
    unsigned uu[8] = {u0.x, u0.y, u0.z, u0.w, u1.x, u1.y, u1.z, u1.w};
    float p = 0.f;
#pragma unroll
    for (int i = 0; i < 8; ++i) {
      half2v x = __builtin_bit_cast(half2v, uu[i]);
      half2v z = x + xr2[i];
      half2v zl = __builtin_elementwise_max(z, z * negc);
      p = __builtin_amdgcn_fdot2(zl, at2[i], p, false);
    }
    float w = valid ? exp2f(p - m0) : 0.f;
    den += w;
#pragma unroll
    for (int i = 0; i < 8; ++i) {
      half2v x = __builtin_bit_cast(half2v, uu[i]);
      acc[2 * i] += w * (float)x[0];
      acc[2 * i + 1] += w * (float)x[1];
    }
  }

  // reduce across the 8 edge slots (lanes differing in low 3 bits)
#pragma unroll
  for (int off = 1; off < 8; off <<= 1) {
    den += __shfl_xor(den, off, 64);
#pragma unroll
    for (int i = 0; i < 16; ++i) acc[i] += __shfl_xor(acc[i], off, 64);
  }

  float inv = 1.f / (den + 1e-16f);
  int c = h * 16 + 2 * e;  // this lane's 2 output channels
  float2 bv = reinterpret_cast<const float2*>(gbias + c)[0];
  float o0 = acc[2 * e] * inv + bv.x;
  float o1 = acc[2 * e + 1] * inv + bv.y;
  // fused LayerNorm + ELU (each lane owns exactly its 2 channels)
  float s1 = o0 + o1;
  float s2 = o0 * o0 + o1 * o1;
#pragma unroll
  for (int off = 1; off < 64; off <<= 1) {
    s1 += __shfl_xor(s1, off, 64);
    s2 += __shfl_xor(s2, off, 64);
  }
  float mu = s1 * (1.f / 128.f);
  float var = s2 * (1.f / 128.f) - mu * mu;
  float rstd = rsqrtf(var + 1e-5f);
  float2 gvv = reinterpret_cast<const float2*>(lng + c)[0];
  float2 lbv = reinterpret_cast<const float2*>(lnb + c)[0];
  float e0 = (o0 - mu) * rstd * gvv.x + lbv.x;
  float e1 = (o1 - mu) * rstd * gvv.y + lbv.y;
  e0 = e0 > 0.f ? e0 : exp2f(e0 * LOG2E_) - 1.f;
  e1 = e1 > 0.f ? e1 : exp2f(e1 * LOG2E_) - 1.f;
  *reinterpret_cast<float2*>(out + (size_t)wid * 128 + c) = make_float2(e0, e1);
}

// ---------------- SAGE mean aggregation; lane = (16-ch group, edge-slot) ----------------
__global__ __launch_bounds__(256) void sage_agg_kernel(const _Float16* __restrict__ xp,
                                                       const int* __restrict__ rowptr,
                                                       const int* __restrict__ csr,
                                                       float* __restrict__ mean, int n) {
  int wid = (blockIdx.x * 256 + threadIdx.x) >> 6;
  int lane = threadIdx.x & 63;
  if (wid >= n) return;
  const int g = lane >> 3, e = lane & 7;
  const char* __restrict__ xbase = (const char*)(xp + g * 16);

  float acc[16];
#pragma unroll
  for (int i = 0; i < 16; ++i) acc[i] = 0.f;

  int beg = rowptr[wid], end = rowptr[wid + 1];
  for (int base = beg; base < end; base += 8) {
    int idx = base + e;
    bool valid = idx < end;
    int ci = valid ? idx : end - 1;
    int s = csr[ci];
    const uint4* gp = reinterpret_cast<const uint4*>(xbase + (size_t)s * 256);
    uint4 u0 = gp[0], u1 = gp[1];
    unsigned uu[8] = {u0.x, u0.y, u0.z, u0.w, u1.x, u1.y, u1.z, u1.w};
    float w = valid ? 1.f : 0.f;
#pragma unroll
    for (int i = 0; i < 8; ++i) {
      half2v x = __builtin_bit_cast(half2v, uu[i]);
      acc[2 * i] += w * (float)x[0];
      acc[2 * i + 1] += w * (float)x[1];
    }
  }
#pragma unroll
  for (int off = 1; off < 8; off <<= 1) {
#pragma unroll
    for (int i = 0; i < 16; ++i) acc[i] += __shfl_xor(acc[i], off, 64);
  }
  float inv = 1.f / fmaxf((float)(end - beg), 1.f);
  int c = g * 16 + 2 * e;
  *reinterpret_cast<float2*>(mean + (size_t)wid * 128 + c) =
      make_float2(acc[2 * e] * inv, acc[2 * e + 1] * inv);
}

// ---------------- JK max + sigmoid gate + mean-pool (chunked, few atomics) ----------------
__global__ __launch_bounds__(256) void jk_pool_kernel(const float* __restrict__ x0,
                                                      const float* __restrict__ x1,
                                                      const float* __restrict__ x2,
                                                      const float* __restrict__ x3,
                                                      const float* __restrict__ wap,
                                                      const float* __restrict__ bap,
                                                      const int* __restrict__ batch,
                                                      float* __restrict__ pooled,
                                                      float* __restrict__ cnt, int n,
                                                      int chunk) {
  int wid = (blockIdx.x * 256 + threadIdx.x) >> 6;
  int lane = threadIdx.x & 63;
  int start = wid * chunk;
  if (start >= n) return;
  int end = start + chunk;
  if (end > n) end = n;

  const float2 wv = reinterpret_cast<const float2*>(wap)[lane];
  const float b0 = bap[0];

  int cur = -1;
  float2 acc = make_float2(0.f, 0.f);
  float c = 0.f;

  for (int i = start; i < end; ++i) {
    int off = i * 64 + lane;
    float2 a0 = reinterpret_cast<const float2*>(x0)[off];
    float2 a1 = reinterpret_cast<const float2*>(x1)[off];
    float2 a2 = reinterpret_cast<const float2*>(x2)[off];
    float2 a3 = reinterpret_cast<const float2*>(x3)[off];
    float2 v;
    v.x = fmaxf(fmaxf(a0.x, a1.x), fmaxf(a2.x, a3.x));
    v.y = fmaxf(fmaxf(a0.y, a1.y), fmaxf(a2.y, a3.y));
    float p = v.x * wv.x + v.y * wv.y;
#pragma unroll
    for (int o = 1; o < 64; o <<= 1) p += __shfl_xor(p, o, 64);
    float a = 1.f / (1.f + exp2f(-(p + b0) * LOG2E_));
    int bg = batch[i];
    if (bg != cur) {
      if (cur >= 0) {
        atomicAdd(&pooled[cur * 128 + 2 * lane], acc.x);
        atomicAdd(&pooled[cur * 128 + 2 * lane + 1], acc.y);
        if (lane == 0) atomicAdd(&cnt[cur], c);
      }
      cur = bg;
      acc = make_float2(0.f, 0.f);
      c = 0.f;
    }
    acc.x += v.x * a;
    acc.y += v.y * a;
    c += 1.f;
  }
  if (cur >= 0) {
    atomicAdd(&pooled[cur * 128 + 2 * lane], acc.x);
    atomicAdd(&pooled[cur * 128 + 2 * lane + 1], acc.y);
    if (lane == 0) atomicAdd(&cnt[cur], c);
  }
}

// ---------------- final MLP: one block per graph ----------------
__global__ __launch_bounds__(128) void mlp_kernel(const float* __restrict__ pooled,
                                                  const float* __restrict__ cnt,
                                                  const float* __restrict__ Wc1,
                                                  const float* __restrict__ bc1,
                                                  const float* __restrict__ a1,
                                                  const float* __restrict__ Wc2,
                                                  const float* __restrict__ bc2,
                                                  const float* __restrict__ a2,
                                                  const float* __restrict__ Wc3,
                                                  const float* __restrict__ bc3,
                                                  float* __restrict__ out) {
  __shared__ float sh[128];
  __shared__ float sh2[128];
  __shared__ float sh3[64];
  int g = blockIdx.x, t = threadIdx.x;
  float inv = 1.f / fmaxf(cnt[g], 1.f);
  sh[t] = pooled[g * 128 + t] * inv;
  __syncthreads();
  float z = bc1[t];
  for (int k = 0; k < 128; ++k) z += sh[k] * Wc1[k * 128 + t];
  float al = a1[0];
  z = z >= 0.f ? z : al * z;
  sh2[t] = z;
  __syncthreads();
  if (t < 64) {
    float z2 = bc2[t];
    for (int k = 0; k < 128; ++k) z2 += sh2[k] * Wc2[k * 64 + t];
    float a2v = a2[0];
    z2 = z2 >= 0.f ? z2 : a2v * z2;
    sh3[t] = z2;
  }
  __syncthreads();
  if (t < 2) {
    float o = bc3[t];
    for (int k = 0; k < 64; ++k) o += sh3[k] * Wc3[k * 2 + t];
    out[g * 2 + t] = o;
  }
}

// ================= host =================
extern "C" void kernel_launch(void* const* d_in, const int* in_sizes, int n_in,
                              void* d_out, int out_size, void* d_ws, size_t ws_size,
                              hipStream_t stream) {
  const float* x = (const float*)d_in[0];
  const int* ei = (const int*)d_in[1];
  const int* batch = (const int*)d_in[2];
  const float* W_in = (const float*)d_in[3];
  const float* b_in = (const float*)d_in[4];
  const float* W_res = (const float*)d_in[5];
  const float* b_res = (const float*)d_in[6];
  const float* g0_Wl = (const float*)d_in[7];
  const float* g0_bl = (const float*)d_in[8];
  const float* g0_Wr = (const float*)d_in[9];
  const float* g0_br = (const float*)d_in[10];
  const float* g0_att = (const float*)d_in[11];
  const float* g0_bias = (const float*)d_in[12];
  const float* g2_Wl = (const float*)d_in[13];
  const float* g2_bl = (const float*)d_in[14];
  const float* g2_Wr = (const float*)d_in[15];
  const float* g2_br = (const float*)d_in[16];
  const float* g2_att = (const float*)d_in[17];
  const float* g2_bias = (const float*)d_in[18];
  const float* s1_Wp = (const float*)d_in[19];
  const float* s1_bp = (const float*)d_in[20];
  const float* s1_Wl = (const float*)d_in[21];
  const float* s1_bl = (const float*)d_in[22];
  const float* s1_Wr = (const float*)d_in[23];
  const float* s3_Wp = (const float*)d_in[24];
  const float* s3_bp = (const float*)d_in[25];
  const float* s3_Wl = (const float*)d_in[26];
  const float* s3_bl = (const float*)d_in[27];
  const float* s3_Wr = (const float*)d_in[28];
  const float* ln_g = (const float*)d_in[29];
  const float* ln_b = (const float*)d_in[30];
  const float* Wap = (const float*)d_in[31];
  const float* bap = (const float*)d_in[32];
  const float* Wc1 = (const float*)d_in[33];
  const float* bc1 = (const float*)d_in[34];
  const float* a1 = (const float*)d_in[35];
  const float* Wc2 = (const float*)d_in[36];
  const float* bc2 = (const float*)d_in[37];
  const float* a2 = (const float*)d_in[38];
  const float* Wc3 = (const float*)d_in[39];
  const float* bc3 = (const float*)d_in[40];
  float* out = (float*)d_out;

  char* w = (char*)d_ws;
  auto alloc = [&](size_t bytes) -> void* {
    void* p = (void*)w;
    w += (bytes + 255) & ~(size_t)255;
    return p;
  };
  int* deg_cursor = (int*)alloc((size_t)N_ * 4);
  int* rowptr = (int*)alloc((size_t)(N_ + 1) * 4);
  int* bscan = (int*)alloc(256 * 4);
  int* csr = (int*)alloc((size_t)E_ * 4);
  float* bsumf = (float*)alloc((size_t)HID_ * 4);
  float* pooled = (float*)alloc((size_t)G_ * HID_ * 4);
  float* cntf = (float*)alloc((size_t)G_ * 4);
  _Float16* wsp = (_Float16*)alloc((size_t)(16384 + 10 * 32768) * 2);
  size_t big = (size_t)N_ * HID_ * 4;
  size_t bigh = (size_t)N_ * HID_ * 2;
  float* T1 = (float*)alloc(big);                 // mean
  float* T2 = (float*)alloc(big);                 // input proj out
  _Float16* H0 = (_Float16*)alloc(bigh);          // xl16 / xp16 (reused per layer)
  _Float16* H1 = (_Float16*)alloc(bigh);          // xr16
  float* B0 = (float*)alloc(big);
  float* B1 = (float*)alloc(big);
  float* B2 = (float*)alloc(big);
  float* B3 = (float*)alloc(big);

  const _Float16* WsT_h = wsp;
  const _Float16* WsT_l = wsp + 8192;
  auto WTh = [&](int j) { return (const _Float16*)(wsp + 16384 + j * 32768); };
  auto WTl = [&](int j) { return (const _Float16*)(wsp + 16384 + j * 32768 + 16384); };
  // j: 0 g0_Wl, 1 g0_Wr, 2 s1_Wp, 3 s1_Wl, 4 s1_Wr, 5 g2_Wl, 6 g2_Wr, 7 s3_Wp, 8 s3_Wl, 9 s3_Wr

  const int EB = (E_ + 255) / 256;
  const int NB256 = (N_ + 255) / 256;
  const int WB = (N_ + 3) / 4;
  const int GB = (N_ + 63) / 64;

  // ---- CSR build ----
  hipMemsetAsync(deg_cursor, 0, (size_t)N_ * 4, stream);
  hist_kernel<<<EB, 256, 0, stream>>>(ei + E_, deg_cursor, E_);
  scan1_kernel<<<NB256, 256, 0, stream>>>(deg_cursor, rowptr, bscan, N_);
  scan2_kernel<<<1, 256, 0, stream>>>(bscan, NB256);
  scan3_kernel<<<NB256, 256, 0, stream>>>(rowptr, deg_cursor, bscan, N_, E_);
  fill_kernel<<<EB, 256, 0, stream>>>(ei, ei + E_, deg_cursor, csr, E_);

  // ---- weight prep ----
  prep_w_kernel<<<(8192 + 10 * 16384 + 255) / 256, 256, 0, stream>>>(
      W_in, W_res, g0_Wl, g0_Wr, s1_Wp, s1_Wl, s1_Wr, g2_Wl, g2_Wr, s3_Wp, s3_Wl, s3_Wr, wsp);
  addv_kernel<<<1, 256, 0, stream>>>(b_in, b_res, bsumf, HID_);

  // ---- input proj: h = x @ (W_in+W_res) + bsum  -> T2 ----
  gemm_rw<64, ACT_NONE, float><<<GB, 256, 0, stream>>>(x, WsT_h, WsT_l, bsumf, T2, N_);

  // ---- GAT layer 0 ----
  gemm_rw_dual_gat<<<GB, 256, 0, stream>>>(T2, WTh(0), WTl(0), WTh(1), WTl(1), g0_bl, g0_br,
                                           H0, H1, N_);
  gat_ln_kernel<<<WB, 256, 0, stream>>>(H0, H1, g0_att, g0_bias, rowptr, csr,
                                        ln_g + 0 * 128, ln_b + 0 * 128, B0, N_);

  // ---- SAGE layer 1 ----
  gemm_rw<128, ACT_RELU, _Float16><<<GB, 256, 0, stream>>>(B0, WTh(2), WTl(2), s1_bp, H0, N_);
  sage_agg_kernel<<<WB, 256, 0, stream>>>(H0, rowptr, csr, T1, N_);
  gemm_rw_dual_sage<<<GB, 256, 0, stream>>>(T1, WTh(3), WTl(3), B0, WTh(4), WTl(4), s1_bl,
                                            ln_g + 1 * 128, ln_b + 1 * 128, B1, N_);

  // ---- GAT layer 2 ----
  gemm_rw_dual_gat<<<GB, 256, 0, stream>>>(B1, WTh(5), WTl(5), WTh(6), WTl(6), g2_bl, g2_br,
                                           H0, H1, N_);
  gat_ln_kernel<<<WB, 256, 0, stream>>>(H0, H1, g2_att, g2_bias, rowptr, csr,
                                        ln_g + 2 * 128, ln_b + 2 * 128, B2, N_);

  // ---- SAGE layer 3 ----
  gemm_rw<128, ACT_RELU, _Float16><<<GB, 256, 0, stream>>>(B2, WTh(7), WTl(7), s3_bp, H0, N_);
  sage_agg_kernel<<<WB, 256, 0, stream>>>(H0, rowptr, csr, T1, N_);
  gemm_rw_dual_sage<<<GB, 256, 0, stream>>>(T1, WTh(8), WTl(8), B2, WTh(9), WTl(9), s3_bl,
                                            ln_g + 3 * 128, ln_b + 3 * 128, B3, N_);

  // ---- JK max + gate + pool + MLP ----
  hipMemsetAsync(pooled, 0, (size_t)G_ * HID_ * 4, stream);
  hipMemsetAsync(cntf, 0, (size_t)G_ * 4, stream);
  {
    const int chunk = 12;
    int nwaves = (N_ + chunk - 1) / chunk;
    int nblocks = (nwaves + 3) / 4;
    jk_pool_kernel<<<nblocks, 256, 0, stream>>>(B0, B1, B2, B3, Wap, bap, batch,
                                                pooled, cntf, N_, chunk);
  }
  mlp_kernel<<<G_, 128, 0, stream>>>(pooled, cntf, Wc1, bc1, a1, Wc2, bc2, a2, Wc3, bc3, out);
}

// Round 10
// 710.368 us; speedup vs baseline: 2.0881x; 1.0058x over previous
//
#include <hip/hip_runtime.h>
#include <math.h>

constexpr int N_ = 50000;
constexpr int E_ = 800000;
constexpr int IN_ = 64;
constexpr int HID_ = 128;
constexpr int G_ = 64;
constexpr float NEG_ = 0.2f;
constexpr float LOG2E_ = 1.44269504088896340736f;

#define ACT_NONE 0
#define ACT_RELU 1

typedef _Float16 half8 __attribute__((ext_vector_type(8)));
typedef _Float16 half2v __attribute__((ext_vector_type(2)));
typedef float floatx4 __attribute__((ext_vector_type(4)));

// ---------------- CSR build ----------------
__global__ __launch_bounds__(256) void hist_kernel(const int* __restrict__ dst,
                                                   int* __restrict__ deg, int e) {
  int i = blockIdx.x * 256 + threadIdx.x;
  if (i < e) atomicAdd(&deg[dst[i]], 1);
}

__global__ __launch_bounds__(256) void scan1_kernel(const int* __restrict__ deg,
                                                    int* __restrict__ excl,
                                                    int* __restrict__ bscan, int n) {
  __shared__ int sh[256];
  int t = threadIdx.x;
  int i = blockIdx.x * 256 + t;
  int v = (i < n) ? deg[i] : 0;
  sh[t] = v;
  __syncthreads();
  for (int off = 1; off < 256; off <<= 1) {
    int y = (t >= off) ? sh[t - off] : 0;
    __syncthreads();
    sh[t] += y;
    __syncthreads();
  }
  int incl = sh[t];
  if (i < n) excl[i] = incl - v;
  if (t == 255) bscan[blockIdx.x] = incl;
}

__global__ __launch_bounds__(256) void scan2_kernel(int* __restrict__ data, int nb) {
  __shared__ int sh[256];
  int t = threadIdx.x;
  int v = (t < nb) ? data[t] : 0;
  sh[t] = v;
  __syncthreads();
  for (int off = 1; off < 256; off <<= 1) {
    int y = (t >= off) ? sh[t - off] : 0;
    __syncthreads();
    sh[t] += y;
    __syncthreads();
  }
  if (t < nb) data[t] = sh[t] - v;  // exclusive
}

__global__ __launch_bounds__(256) void scan3_kernel(int* __restrict__ rowptr,
                                                    int* __restrict__ cursor,
                                                    const int* __restrict__ bscan,
                                                    int n, int e) {
  int i = blockIdx.x * 256 + threadIdx.x;
  if (i < n) {
    int v = rowptr[i] + bscan[blockIdx.x];
    rowptr[i] = v;
    cursor[i] = v;
  }
  if (i == n) rowptr[n] = e;
}

__global__ __launch_bounds__(256) void fill_kernel(const int* __restrict__ src,
                                                   const int* __restrict__ dst,
                                                   int* __restrict__ cursor,
                                                   int* __restrict__ csr, int e) {
  int i = blockIdx.x * 256 + threadIdx.x;
  if (i < e) {
    int d = dst[i];
    int p = atomicAdd(&cursor[d], 1);
    csr[p] = src[i];
  }
}

// ---------------- weight prep: transpose + fp16 hi/lo split (+ bias sum fused) ----------------
__global__ __launch_bounds__(256) void prep_w_kernel(
    const float* __restrict__ W_in, const float* __restrict__ W_res,
    const float* __restrict__ b_in, const float* __restrict__ b_res,
    const float* __restrict__ m0, const float* __restrict__ m1,
    const float* __restrict__ m2, const float* __restrict__ m3,
    const float* __restrict__ m4, const float* __restrict__ m5,
    const float* __restrict__ m6, const float* __restrict__ m7,
    const float* __restrict__ m8, const float* __restrict__ m9,
    _Float16* __restrict__ dst, float* __restrict__ bsum) {
  int idx = blockIdx.x * 256 + threadIdx.x;
  if (idx < 8192) {
    int n = idx >> 6, k = idx & 63;
    float v = W_in[k * 128 + n] + W_res[k * 128 + n];
    _Float16 h = (_Float16)v;
    dst[idx] = h;
    dst[8192 + idx] = (_Float16)(v - (float)h);
  } else if (idx < 8192 + 10 * 16384) {
    int r = idx - 8192;
    int j = r >> 14;
    int e = r & 16383;
    int n = e >> 7, k = e & 127;
    const float* S;
    switch (j) {
      case 0: S = m0; break; case 1: S = m1; break; case 2: S = m2; break;
      case 3: S = m3; break; case 4: S = m4; break; case 5: S = m5; break;
      case 6: S = m6; break; case 7: S = m7; break; case 8: S = m8; break;
      default: S = m9; break;
    }
    float v = S[k * 128 + n];
    _Float16 h = (_Float16)v;
    _Float16* base = dst + 16384 + j * 32768;
    base[e] = h;                       // e == n*128+k
    base[16384 + e] = (_Float16)(v - (float)h);
  } else if (idx < 8192 + 10 * 16384 + 128) {
    int k = idx - (8192 + 10 * 16384);
    bsum[k] = b_in[k] + b_res[k];
  }
}

// ---------------- fp16 hi/lo split of 8 floats (register form) ----------------
__device__ inline void split8v(float4 a, float4 b, half8& h, half8& l) {
  float v0 = a.x, v1 = a.y, v2 = a.z, v3 = a.w;
  float v4 = b.x, v5 = b.y, v6 = b.z, v7 = b.w;
  _Float16 h0 = (_Float16)v0, h1 = (_Float16)v1, h2 = (_Float16)v2, h3 = (_Float16)v3;
  _Float16 h4 = (_Float16)v4, h5 = (_Float16)v5, h6 = (_Float16)v6, h7 = (_Float16)v7;
  h[0] = h0; h[1] = h1; h[2] = h2; h[3] = h3; h[4] = h4; h[5] = h5; h[6] = h6; h[7] = h7;
  l[0] = (_Float16)(v0 - (float)h0); l[1] = (_Float16)(v1 - (float)h1);
  l[2] = (_Float16)(v2 - (float)h2); l[3] = (_Float16)(v3 - (float)h3);
  l[4] = (_Float16)(v4 - (float)h4); l[5] = (_Float16)(v5 - (float)h5);
  l[6] = (_Float16)(v6 - (float)h6); l[7] = (_Float16)(v7 - (float)h7);
}

// ================= register-weight GEMMs (unchanged) =================
template <int K1, int ACT, typename OutT>
__global__ __launch_bounds__(256, 2) void gemm_rw(const float* __restrict__ A,
                                                  const _Float16* __restrict__ Wh,
                                                  const _Float16* __restrict__ Wl,
                                                  const float* __restrict__ bias,
                                                  OutT* __restrict__ C, int M) {
  constexpr int KK = K1 / 32;
  const int t = threadIdx.x;
  const int wave = t >> 6, lane = t & 63;
  const int quad = lane >> 4, l16 = lane & 15;
  const int nt0 = wave * 2;

  half8 wh[2][KK], wl[2][KK];
  float bb[2];
  int col[2];
#pragma unroll
  for (int i = 0; i < 2; ++i) {
    col[i] = (nt0 + i) * 16 + l16;
    bb[i] = bias[col[i]];
#pragma unroll
    for (int k = 0; k < KK; ++k) {
      size_t off = (size_t)col[i] * K1 + k * 32 + quad * 8;
      wh[i][k] = *reinterpret_cast<const half8*>(Wh + off);
      wl[i][k] = *reinterpret_cast<const half8*>(Wl + off);
    }
  }
  const int r0 = blockIdx.x * 64;
#pragma unroll
  for (int tt = 0; tt < 4; ++tt) {
    int tb = r0 + tt * 16;
    if (tb >= M) break;
    int arow = tb + l16;
    if (arow >= M) arow = M - 1;
    const float* ap = A + (size_t)arow * K1 + quad * 8;
    float4 a0[KK], a1[KK];
#pragma unroll
    for (int k = 0; k < KK; ++k) {
      a0[k] = *reinterpret_cast<const float4*>(ap + k * 32);
      a1[k] = *reinterpret_cast<const float4*>(ap + k * 32 + 4);
    }
    floatx4 acc[2];
    acc[0] = (floatx4){0.f, 0.f, 0.f, 0.f};
    acc[1] = (floatx4){0.f, 0.f, 0.f, 0.f};
#pragma unroll
    for (int k = 0; k < KK; ++k) {
      half8 ah, al;
      split8v(a0[k], a1[k], ah, al);
      acc[0] = __builtin_amdgcn_mfma_f32_16x16x32_f16(ah, wh[0][k], acc[0], 0, 0, 0);
      acc[0] = __builtin_amdgcn_mfma_f32_16x16x32_f16(ah, wl[0][k], acc[0], 0, 0, 0);
      acc[0] = __builtin_amdgcn_mfma_f32_16x16x32_f16(al, wh[0][k], acc[0], 0, 0, 0);
      acc[1] = __builtin_amdgcn_mfma_f32_16x16x32_f16(ah, wh[1][k], acc[1], 0, 0, 0);
      acc[1] = __builtin_amdgcn_mfma_f32_16x16x32_f16(ah, wl[1][k], acc[1], 0, 0, 0);
      acc[1] = __builtin_amdgcn_mfma_f32_16x16x32_f16(al, wh[1][k], acc[1], 0, 0, 0);
    }
#pragma unroll
    for (int i = 0; i < 2; ++i) {
#pragma unroll
      for (int reg = 0; reg < 4; ++reg) {
        int r = tb + quad * 4 + reg;
        if (r < M) {
          float v = acc[i][reg] + bb[i];
          if (ACT == ACT_RELU) v = fmaxf(v, 0.f);
          C[(size_t)r * 128 + col[i]] = (OutT)v;
        }
      }
    }
  }
}

__global__ __launch_bounds__(256, 2) void gemm_rw_dual_gat(const float* __restrict__ A,
                                                           const _Float16* __restrict__ W0h,
                                                           const _Float16* __restrict__ W0l,
                                                           const _Float16* __restrict__ W1h,
                                                           const _Float16* __restrict__ W1l,
                                                           const float* __restrict__ b0,
                                                           const float* __restrict__ b1,
                                                           _Float16* __restrict__ C0,
                                                           _Float16* __restrict__ C1, int M) {
  const int t = threadIdx.x;
  const int wave = t >> 6, lane = t & 63;
  const int quad = lane >> 4, l16 = lane & 15;
  const int nt0 = wave * 2;

  half8 w0h[2][4], w0l[2][4], w1h[2][4], w1l[2][4];
  float bb0[2], bb1[2];
  int col[2];
#pragma unroll
  for (int i = 0; i < 2; ++i) {
    col[i] = (nt0 + i) * 16 + l16;
    bb0[i] = b0[col[i]];
    bb1[i] = b1[col[i]];
#pragma unroll
    for (int k = 0; k < 4; ++k) {
      size_t off = (size_t)col[i] * 128 + k * 32 + quad * 8;
      w0h[i][k] = *reinterpret_cast<const half8*>(W0h + off);
      w0l[i][k] = *reinterpret_cast<const half8*>(W0l + off);
      w1h[i][k] = *reinterpret_cast<const half8*>(W1h + off);
      w1l[i][k] = *reinterpret_cast<const half8*>(W1l + off);
    }
  }
  const int r0 = blockIdx.x * 64;
#pragma unroll
  for (int tt = 0; tt < 4; ++tt) {
    int tb = r0 + tt * 16;
    if (tb >= M) break;
    int arow = tb + l16;
    if (arow >= M) arow = M - 1;
    const float* ap = A + (size_t)arow * 128 + quad * 8;
    float4 a0[4], a1[4];
#pragma unroll
    for (int k = 0; k < 4; ++k) {
      a0[k] = *reinterpret_cast<const float4*>(ap + k * 32);
      a1[k] = *reinterpret_cast<const float4*>(ap + k * 32 + 4);
    }
    floatx4 acc0[2], acc1[2];
    acc0[0] = (floatx4){0.f, 0.f, 0.f, 0.f};
    acc0[1] = (floatx4){0.f, 0.f, 0.f, 0.f};
    acc1[0] = (floatx4){0.f, 0.f, 0.f, 0.f};
    acc1[1] = (floatx4){0.f, 0.f, 0.f, 0.f};
#pragma unroll
    for (int k = 0; k < 4; ++k) {
      half8 ah, al;
      split8v(a0[k], a1[k], ah, al);
#pragma unroll
      for (int i = 0; i < 2; ++i) {
        acc0[i] = __builtin_amdgcn_mfma_f32_16x16x32_f16(ah, w0h[i][k], acc0[i], 0, 0, 0);
        acc0[i] = __builtin_amdgcn_mfma_f32_16x16x32_f16(ah, w0l[i][k], acc0[i], 0, 0, 0);
        acc0[i] = __builtin_amdgcn_mfma_f32_16x16x32_f16(al, w0h[i][k], acc0[i], 0, 0, 0);
        acc1[i] = __builtin_amdgcn_mfma_f32_16x16x32_f16(ah, w1h[i][k], acc1[i], 0, 0, 0);
        acc1[i] = __builtin_amdgcn_mfma_f32_16x16x32_f16(ah, w1l[i][k], acc1[i], 0, 0, 0);
        acc1[i] = __builtin_amdgcn_mfma_f32_16x16x32_f16(al, w1h[i][k], acc1[i], 0, 0, 0);
      }
    }
#pragma unroll
    for (int i = 0; i < 2; ++i) {
#pragma unroll
      for (int reg = 0; reg < 4; ++reg) {
        int r = tb + quad * 4 + reg;
        if (r < M) {
          C0[(size_t)r * 128 + col[i]] = (_Float16)(acc0[i][reg] + bb0[i]);
          C1[(size_t)r * 128 + col[i]] = (_Float16)(acc1[i][reg] + bb1[i]);
        }
      }
    }
  }
}

__global__ __launch_bounds__(256, 2) void gemm_rw_dual_sage(const float* __restrict__ A1,
                                                            const _Float16* __restrict__ W1h,
                                                            const _Float16* __restrict__ W1l,
                                                            const float* __restrict__ A2,
                                                            const _Float16* __restrict__ W2h,
                                                            const _Float16* __restrict__ W2l,
                                                            const float* __restrict__ bias,
                                                            const float* __restrict__ lng,
                                                            const float* __restrict__ lnb,
                                                            float* __restrict__ C, int M) {
  const int t = threadIdx.x;
  const int wave = t >> 6, lane = t & 63;
  const int quad = lane >> 4, l16 = lane & 15;
  const int nt0 = wave * 2;

  half8 w1h[2][4], w1l[2][4], w2h[2][4], w2l[2][4];
  float bb[2], gg[2], lb[2];
  int col[2];
#pragma unroll
  for (int i = 0; i < 2; ++i) {
    col[i] = (nt0 + i) * 16 + l16;
    bb[i] = bias[col[i]];
    gg[i] = lng[col[i]];
    lb[i] = lnb[col[i]];
#pragma unroll
    for (int k = 0; k < 4; ++k) {
      size_t off = (size_t)col[i] * 128 + k * 32 + quad * 8;
      w1h[i][k] = *reinterpret_cast<const half8*>(W1h + off);
      w1l[i][k] = *reinterpret_cast<const half8*>(W1l + off);
      w2h[i][k] = *reinterpret_cast<const half8*>(W2h + off);
      w2l[i][k] = *reinterpret_cast<const half8*>(W2l + off);
    }
  }
  __shared__ float2 red[2][4][16];  // [tile parity][wave][row]
  const int r0 = blockIdx.x * 64;
#pragma unroll 1
  for (int tt = 0; tt < 4; ++tt) {
    int tb = r0 + tt * 16;
    if (tb >= M) break;
    int arow = tb + l16;
    if (arow >= M) arow = M - 1;
    const float* ap1 = A1 + (size_t)arow * 128 + quad * 8;
    const float* ap2 = A2 + (size_t)arow * 128 + quad * 8;
    float4 a0[4], a1[4], c0[4], c1[4];
#pragma unroll
    for (int k = 0; k < 4; ++k) {
      a0[k] = *reinterpret_cast<const float4*>(ap1 + k * 32);
      a1[k] = *reinterpret_cast<const float4*>(ap1 + k * 32 + 4);
      c0[k] = *reinterpret_cast<const float4*>(ap2 + k * 32);
      c1[k] = *reinterpret_cast<const float4*>(ap2 + k * 32 + 4);
    }
    floatx4 acc[2];
    acc[0] = (floatx4){0.f, 0.f, 0.f, 0.f};
    acc[1] = (floatx4){0.f, 0.f, 0.f, 0.f};
#pragma unroll
    for (int k = 0; k < 4; ++k) {
      half8 ah, al;
      split8v(a0[k], a1[k], ah, al);
#pragma unroll
      for (int i = 0; i < 2; ++i) {
        acc[i] = __builtin_amdgcn_mfma_f32_16x16x32_f16(ah, w1h[i][k], acc[i], 0, 0, 0);
        acc[i] = __builtin_amdgcn_mfma_f32_16x16x32_f16(ah, w1l[i][k], acc[i], 0, 0, 0);
        acc[i] = __builtin_amdgcn_mfma_f32_16x16x32_f16(al, w1h[i][k], acc[i], 0, 0, 0);
      }
    }
#pragma unroll
    for (int k = 0; k < 4; ++k) {
      half8 ah, al;
      split8v(c0[k], c1[k], ah, al);
#pragma unroll
      for (int i = 0; i < 2; ++i) {
        acc[i] = __builtin_amdgcn_mfma_f32_16x16x32_f16(ah, w2h[i][k], acc[i], 0, 0, 0);
        acc[i] = __builtin_amdgcn_mfma_f32_16x16x32_f16(ah, w2l[i][k], acc[i], 0, 0, 0);
        acc[i] = __builtin_amdgcn_mfma_f32_16x16x32_f16(al, w2h[i][k], acc[i], 0, 0, 0);
      }
    }
    float v0[4], v1[4], p1[4], p2[4];
#pragma unroll
    for (int reg = 0; reg < 4; ++reg) {
      v0[reg] = acc[0][reg] + bb[0];
      v1[reg] = acc[1][reg] + bb[1];
      p1[reg] = v0[reg] + v1[reg];
      p2[reg] = v0[reg] * v0[reg] + v1[reg] * v1[reg];
    }
#pragma unroll
    for (int off = 1; off < 16; off <<= 1) {
#pragma unroll
      for (int reg = 0; reg < 4; ++reg) {
        p1[reg] += __shfl_xor(p1[reg], off, 64);
        p2[reg] += __shfl_xor(p2[reg], off, 64);
      }
    }
    int par = tt & 1;
    if (l16 == 0) {
#pragma unroll
      for (int reg = 0; reg < 4; ++reg)
        red[par][wave][quad * 4 + reg] = make_float2(p1[reg], p2[reg]);
    }
    __syncthreads();
#pragma unroll
    for (int reg = 0; reg < 4; ++reg) {
      int rr = quad * 4 + reg;
      float2 q0 = red[par][0][rr], q1 = red[par][1][rr];
      float2 q2 = red[par][2][rr], q3 = red[par][3][rr];
      float s1 = q0.x + q1.x + q2.x + q3.x;
      float s2 = q0.y + q1.y + q2.y + q3.y;
      float inv = 1.f / fmaxf(sqrtf(s2), 1e-12f);
      float mu = s1 * inv * (1.f / 128.f);
      float ex2 = (s2 * inv) * inv * (1.f / 128.f);
      float rstd = rsqrtf(ex2 - mu * mu + 1e-5f);
      int r = tb + rr;
      if (r < M) {
        float o0 = (v0[reg] * inv - mu) * rstd * gg[0] + lb[0];
        float o1 = (v1[reg] * inv - mu) * rstd * gg[1] + lb[1];
        o0 = fmaxf(o0, NEG_ * o0);
        o1 = fmaxf(o1, NEG_ * o1);
        C[(size_t)r * 128 + col[0]] = o0;
        C[(size_t)r * 128 + col[1]] = o1;
      }
    }
  }
}

// ---------------- GATv2 + LN + ELU; lane=(head, edge-slot); packed fp16 + v_dot2 ----------------
// Software-pipelined (depth 2): next 8-edge block's csr + row uint4s are issued
// before the current block's score/accumulate chain, overlapping gather latency.
__global__ __launch_bounds__(256) void gat_ln_kernel(const _Float16* __restrict__ xl,
                                                     const _Float16* __restrict__ xr,
                                                     const float* __restrict__ att,
                                                     const float* __restrict__ gbias,
                                                     const int* __restrict__ rowptr,
                                                     const int* __restrict__ csr,
                                                     const float* __restrict__ lng,
                                                     const float* __restrict__ lnb,
                                                     float* __restrict__ out, int n) {
  int wid = (blockIdx.x * 256 + threadIdx.x) >> 6;
  int lane = threadIdx.x & 63;
  if (wid >= n) return;
  const int h = lane >> 3, e = lane & 7;
  const char* __restrict__ xbase = (const char*)(xl + h * 16);  // per-lane head base

  half2v xr2[8], at2[8];
  {
    const uint4* xrp = reinterpret_cast<const uint4*>(xr + (size_t)wid * 128 + h * 16);
    uint4 u0 = xrp[0], u1 = xrp[1];
    unsigned uu[8] = {u0.x, u0.y, u0.z, u0.w, u1.x, u1.y, u1.z, u1.w};
#pragma unroll
    for (int i = 0; i < 8; ++i) xr2[i] = __builtin_bit_cast(half2v, uu[i]);
    const float2* ap = reinterpret_cast<const float2*>(att + h * 16);
#pragma unroll
    for (int i = 0; i < 8; ++i) {
      float2 a = ap[i];
      at2[i][0] = (_Float16)(a.x * LOG2E_);
      at2[i][1] = (_Float16)(a.y * LOG2E_);
    }
  }
  const half2v negc = {(_Float16)NEG_, (_Float16)NEG_};

  // self loop: anchor + init (only e==0 contributes)
  float m0, den;
  float acc[16];
  {
    const uint4* sp = reinterpret_cast<const uint4*>(xbase + (size_t)wid * 256);
    uint4 u0 = sp[0], u1 = sp[1];
    unsigned uu[8] = {u0.x, u0.y, u0.z, u0.w, u1.x, u1.y, u1.z, u1.w};
    float p = 0.f;
#pragma unroll
    for (int i = 0; i < 8; ++i) {
      half2v x = __builtin_bit_cast(half2v, uu[i]);
      half2v z = x + xr2[i];
      half2v zl = __builtin_elementwise_max(z, z * negc);
      p = __builtin_amdgcn_fdot2(zl, at2[i], p, false);
    }
    m0 = p;
    float w = (e == 0) ? 1.f : 0.f;
    den = w;
#pragma unroll
    for (int i = 0; i < 8; ++i) {
      half2v x = __builtin_bit_cast(half2v, uu[i]);
      acc[2 * i] = w * (float)x[0];
      acc[2 * i + 1] = w * (float)x[1];
    }
  }

  int beg = rowptr[wid], end = rowptr[wid + 1];
  if (beg < end) {
    // prologue: load block 0
    int idx0 = beg + e;
    bool vcur = idx0 < end;
    int ci0 = vcur ? idx0 : end - 1;
    int s0 = csr[ci0];
    const uint4* gp0 = reinterpret_cast<const uint4*>(xbase + (size_t)s0 * 256);
    uint4 cu0 = gp0[0], cu1 = gp0[1];
    for (int base = beg; base < end; base += 8) {
      // prefetch next block (wave-uniform branch)
      uint4 nu0, nu1;
      bool vnxt = false;
      int nb = base + 8;
      if (nb < end) {
        int idxn = nb + e;
        vnxt = idxn < end;
        int cin = vnxt ? idxn : end - 1;
        int sn = csr[cin];
        const uint4* gpn = reinterpret_cast<const uint4*>(xbase + (size_t)sn * 256);
        nu0 = gpn[0];
        nu1 = gpn[1];
      }
      // compute on current block
      unsigned uu[8] = {cu0.x, cu0.y, cu0.z, cu0.w, cu1.x, cu1.y, cu1.z, cu1.w};
      float p = 0.f;
#pragma unroll
      for (int i = 0; i < 8; ++i) {
        half2v x = __builtin_bit_cast(half2v, uu[i]);
        half2v z = x + xr2[i];
        half2v zl = __builtin_elementwise_max(z, z * negc);
        p = __builtin_amdgcn_fdot2(zl, at2[i], p, false);
      }
      float w = vcur ? exp2f(p - m0) : 0.f;
      den += w;
#pragma unroll
      for (int i = 0; i < 8; ++i) {
        half2v x = __builtin_bit_cast(half2v, uu[i]);
        acc[2 * i] += w * (float)x[0];
        acc[2 * i + 1] += w * (float)x[1];
      }
      cu0 = nu0;
      cu1 = nu1;
      vcur = vnxt;
    }
  }

  // reduce across the 8 edge slots
#pragma unroll
  for (int off = 1; off < 8; off <<= 1) {
    den += __shfl_xor(den, off, 64);
#pragma unroll
    for (int i = 0; i < 16; ++i) acc[i] += __shfl_xor(acc[i], off, 64);
  }

  float inv = 1.f / (den + 1e-16f);
  int c = h * 16 + 2 * e;
  float2 bv = reinterpret_cast<const float2*>(gbias + c)[0];
  float o0 = acc[2 * e] * inv + bv.x;
  float o1 = acc[2 * e + 1] * inv + bv.y;
  float s1 = o0 + o1;
  float s2 = o0 * o0 + o1 * o1;
#pragma unroll
  for (int off = 1; off < 64; off <<= 1) {
    s1 += __shfl_xor(s1, off, 64);
    s2 += __shfl_xor(s2, off, 64);
  }
  float mu = s1 * (1.f / 128.f);
  float var = s2 * (1.f / 128.f) - mu * mu;
  float rstd = rsqrtf(var + 1e-5f);
  float2 gvv = reinterpret_cast<const float2*>(lng + c)[0];
  float2 lbv = reinterpret_cast<const float2*>(lnb + c)[0];
  float e0 = (o0 - mu) * rstd * gvv.x + lbv.x;
  float e1 = (o1 - mu) * rstd * gvv.y + lbv.y;
  e0 = e0 > 0.f ? e0 : exp2f(e0 * LOG2E_) - 1.f;
  e1 = e1 > 0.f ? e1 : exp2f(e1 * LOG2E_) - 1.f;
  *reinterpret_cast<float2*>(out + (size_t)wid * 128 + c) = make_float2(e0, e1);
}

// ---------------- SAGE mean aggregation; pipelined, lane = (group, edge-slot) ----------------
__global__ __launch_bounds__(256) void sage_agg_kernel(const _Float16* __restrict__ xp,
                                                       const int* __restrict__ rowptr,
                                                       const int* __restrict__ csr,
                                                       float* __restrict__ mean, int n) {
  int wid = (blockIdx.x * 256 + threadIdx.x) >> 6;
  int lane = threadIdx.x & 63;
  if (wid >= n) return;
  const int g = lane >> 3, e = lane & 7;
  const char* __restrict__ xbase = (const char*)(xp + g * 16);

  float acc[16];
#pragma unroll
  for (int i = 0; i < 16; ++i) acc[i] = 0.f;

  int beg = rowptr[wid], end = rowptr[wid + 1];
  if (beg < end) {
    int idx0 = beg + e;
    bool vcur = idx0 < end;
    int ci0 = vcur ? idx0 : end - 1;
    int s0 = csr[ci0];
    const uint4* gp0 = reinterpret_cast<const uint4*>(xbase + (size_t)s0 * 256);
    uint4 cu0 = gp0[0], cu1 = gp0[1];
    for (int base = beg; base < end; base += 8) {
      uint4 nu0, nu1;
      bool vnxt = false;
      int nb = base + 8;
      if (nb < end) {
        int idxn = nb + e;
        vnxt = idxn < end;
        int cin = vnxt ? idxn : end - 1;
        int sn = csr[cin];
        const uint4* gpn = reinterpret_cast<const uint4*>(xbase + (size_t)sn * 256);
        nu0 = gpn[0];
        nu1 = gpn[1];
      }
      unsigned uu[8] = {cu0.x, cu0.y, cu0.z, cu0.w, cu1.x, cu1.y, cu1.z, cu1.w};
      float w = vcur ? 1.f : 0.f;
#pragma unroll
      for (int i = 0; i < 8; ++i) {
        half2v x = __builtin_bit_cast(half2v, uu[i]);
        acc[2 * i] += w * (float)x[0];
        acc[2 * i + 1] += w * (float)x[1];
      }
      cu0 = nu0;
      cu1 = nu1;
      vcur = vnxt;
    }
  }
#pragma unroll
  for (int off = 1; off < 8; off <<= 1) {
#pragma unroll
    for (int i = 0; i < 16; ++i) acc[i] += __shfl_xor(acc[i], off, 64);
  }
  float inv = 1.f / fmaxf((float)(end - beg), 1.f);
  int c = g * 16 + 2 * e;
  *reinterpret_cast<float2*>(mean + (size_t)wid * 128 + c) =
      make_float2(acc[2 * e] * inv, acc[2 * e + 1] * inv);
}

// ---------------- JK max + sigmoid gate + mean-pool (chunked, few atomics) ----------------
__global__ __launch_bounds__(256) void jk_pool_kernel(const float* __restrict__ x0,
                                                      const float* __restrict__ x1,
                                                      const float* __restrict__ x2,
                                                      const float* __restrict__ x3,
                                                      const float* __restrict__ wap,
                                                      const float* __restrict__ bap,
                                                      const int* __restrict__ batch,
                                                      float* __restrict__ pooled,
                                                      float* __restrict__ cnt, int n,
                                                      int chunk) {
  int wid = (blockIdx.x * 256 + threadIdx.x) >> 6;
  int lane = threadIdx.x & 63;
  int start = wid * chunk;
  if (start >= n) return;
  int end = start + chunk;
  if (end > n) end = n;

  const float2 wv = reinterpret_cast<const float2*>(wap)[lane];
  const float b0 = bap[0];

  int cur = -1;
  float2 acc = make_float2(0.f, 0.f);
  float c = 0.f;

  for (int i = start; i < end; ++i) {
    int off = i * 64 + lane;
    float2 a0 = reinterpret_cast<const float2*>(x0)[off];
    float2 a1 = reinterpret_cast<const float2*>(x1)[off];
    float2 a2 = reinterpret_cast<const float2*>(x2)[off];
    float2 a3 = reinterpret_cast<const float2*>(x3)[off];
    float2 v;
    v.x = fmaxf(fmaxf(a0.x, a1.x), fmaxf(a2.x, a3.x));
    v.y = fmaxf(fmaxf(a0.y, a1.y), fmaxf(a2.y, a3.y));
    float p = v.x * wv.x + v.y * wv.y;
#pragma unroll
    for (int o = 1; o < 64; o <<= 1) p += __shfl_xor(p, o, 64);
    float a = 1.f / (1.f + exp2f(-(p + b0) * LOG2E_));
    int bg = batch[i];
    if (bg != cur) {
      if (cur >= 0) {
        atomicAdd(&pooled[cur * 128 + 2 * lane], acc.x);
        atomicAdd(&pooled[cur * 128 + 2 * lane + 1], acc.y);
        if (lane == 0) atomicAdd(&cnt[cur], c);
      }
      cur = bg;
      acc = make_float2(0.f, 0.f);
      c = 0.f;
    }
    acc.x += v.x * a;
    acc.y += v.y * a;
    c += 1.f;
  }
  if (cur >= 0) {
    atomicAdd(&pooled[cur * 128 + 2 * lane], acc.x);
    atomicAdd(&pooled[cur * 128 + 2 * lane + 1], acc.y);
    if (lane == 0) atomicAdd(&cnt[cur], c);
  }
}

// ---------------- final MLP: one block per graph ----------------
__global__ __launch_bounds__(128) void mlp_kernel(const float* __restrict__ pooled,
                                                  const float* __restrict__ cnt,
                                                  const float* __restrict__ Wc1,
                                                  const float* __restrict__ bc1,
                                                  const float* __restrict__ a1,
                                                  const float* __restrict__ Wc2,
                                                  const float* __restrict__ bc2,
                                                  const float* __restrict__ a2,
                                                  const float* __restrict__ Wc3,
                                                  const float* __restrict__ bc3,
                                                  float* __restrict__ out) {
  __shared__ float sh[128];
  __shared__ float sh2[128];
  __shared__ float sh3[64];
  int g = blockIdx.x, t = threadIdx.x;
  float inv = 1.f / fmaxf(cnt[g], 1.f);
  sh[t] = pooled[g * 128 + t] * inv;
  __syncthreads();
  float z = bc1[t];
  for (int k = 0; k < 128; ++k) z += sh[k] * Wc1[k * 128 + t];
  float al = a1[0];
  z = z >= 0.f ? z : al * z;
  sh2[t] = z;
  __syncthreads();
  if (t < 64) {
    float z2 = bc2[t];
    for (int k = 0; k < 128; ++k) z2 += sh2[k] * Wc2[k * 64 + t];
    float a2v = a2[0];
    z2 = z2 >= 0.f ? z2 : a2v * z2;
    sh3[t] = z2;
  }
  __syncthreads();
  if (t < 2) {
    float o = bc3[t];
    for (int k = 0; k < 64; ++k) o += sh3[k] * Wc3[k * 2 + t];
    out[g * 2 + t] = o;
  }
}

// ================= host =================
extern "C" void kernel_launch(void* const* d_in, const int* in_sizes, int n_in,
                              void* d_out, int out_size, void* d_ws, size_t ws_size,
                              hipStream_t stream) {
  const float* x = (const float*)d_in[0];
  const int* ei = (const int*)d_in[1];
  const int* batch = (const int*)d_in[2];
  const float* W_in = (const float*)d_in[3];
  const float* b_in = (const float*)d_in[4];
  const float* W_res = (const float*)d_in[5];
  const float* b_res = (const float*)d_in[6];
  const float* g0_Wl = (const float*)d_in[7];
  const float* g0_bl = (const float*)d_in[8];
  const float* g0_Wr = (const float*)d_in[9];
  const float* g0_br = (const float*)d_in[10];
  const float* g0_att = (const float*)d_in[11];
  const float* g0_bias = (const float*)d_in[12];
  const float* g2_Wl = (const float*)d_in[13];
  const float* g2_bl = (const float*)d_in[14];
  const float* g2_Wr = (const float*)d_in[15];
  const float* g2_br = (const float*)d_in[16];
  const float* g2_att = (const float*)d_in[17];
  const float* g2_bias = (const float*)d_in[18];
  const float* s1_Wp = (const float*)d_in[19];
  const float* s1_bp = (const float*)d_in[20];
  const float* s1_Wl = (const float*)d_in[21];
  const float* s1_bl = (const float*)d_in[22];
  const float* s1_Wr = (const float*)d_in[23];
  const float* s3_Wp = (const float*)d_in[24];
  const float* s3_bp = (const float*)d_in[25];
  const float* s3_Wl = (const float*)d_in[26];
  const float* s3_bl = (const float*)d_in[27];
  const float* s3_Wr = (const float*)d_in[28];
  const float* ln_g = (const float*)d_in[29];
  const float* ln_b = (const float*)d_in[30];
  const float* Wap = (const float*)d_in[31];
  const float* bap = (const float*)d_in[32];
  const float* Wc1 = (const float*)d_in[33];
  const float* bc1 = (const float*)d_in[34];
  const float* a1 = (const float*)d_in[35];
  const float* Wc2 = (const float*)d_in[36];
  const float* bc2 = (const float*)d_in[37];
  const float* a2 = (const float*)d_in[38];
  const float* Wc3 = (const float*)d_in[39];
  const float* bc3 = (const float*)d_in[40];
  float* out = (float*)d_out;

  char* w = (char*)d_ws;
  auto alloc = [&](size_t bytes) -> void* {
    void* p = (void*)w;
    w += (bytes + 255) & ~(size_t)255;
    return p;
  };
  int* deg_cursor = (int*)alloc((size_t)N_ * 4);
  int* rowptr = (int*)alloc((size_t)(N_ + 1) * 4);
  int* bscan = (int*)alloc(256 * 4);
  int* csr = (int*)alloc((size_t)E_ * 4);
  float* bsumf = (float*)alloc((size_t)HID_ * 4);
  float* pooled = (float*)alloc((size_t)G_ * HID_ * 4);   // 32768 B, 256-aligned
  float* cntf = (float*)alloc((size_t)G_ * 4);            // adjacent to pooled
  _Float16* wsp = (_Float16*)alloc((size_t)(16384 + 10 * 32768) * 2);
  size_t big = (size_t)N_ * HID_ * 4;
  size_t bigh = (size_t)N_ * HID_ * 2;
  float* T1 = (float*)alloc(big);                 // mean
  float* T2 = (float*)alloc(big);                 // input proj out
  _Float16* H0 = (_Float16*)alloc(bigh);          // xl16 / xp16 (reused per layer)
  _Float16* H1 = (_Float16*)alloc(bigh);          // xr16
  float* B0 = (float*)alloc(big);
  float* B1 = (float*)alloc(big);
  float* B2 = (float*)alloc(big);
  float* B3 = (float*)alloc(big);

  const _Float16* WsT_h = wsp;
  const _Float16* WsT_l = wsp + 8192;
  auto WTh = [&](int j) { return (const _Float16*)(wsp + 16384 + j * 32768); };
  auto WTl = [&](int j) { return (const _Float16*)(wsp + 16384 + j * 32768 + 16384); };
  // j: 0 g0_Wl, 1 g0_Wr, 2 s1_Wp, 3 s1_Wl, 4 s1_Wr, 5 g2_Wl, 6 g2_Wr, 7 s3_Wp, 8 s3_Wl, 9 s3_Wr

  const int EB = (E_ + 255) / 256;
  const int NB256 = (N_ + 255) / 256;
  const int WB = (N_ + 3) / 4;
  const int GB = (N_ + 63) / 64;

  // ---- CSR build ----
  hipMemsetAsync(deg_cursor, 0, (size_t)N_ * 4, stream);
  hist_kernel<<<EB, 256, 0, stream>>>(ei + E_, deg_cursor, E_);
  scan1_kernel<<<NB256, 256, 0, stream>>>(deg_cursor, rowptr, bscan, N_);
  scan2_kernel<<<1, 256, 0, stream>>>(bscan, NB256);
  scan3_kernel<<<NB256, 256, 0, stream>>>(rowptr, deg_cursor, bscan, N_, E_);
  fill_kernel<<<EB, 256, 0, stream>>>(ei, ei + E_, deg_cursor, csr, E_);

  // ---- weight prep (incl. bias sum) ----
  prep_w_kernel<<<(8192 + 10 * 16384 + 128 + 255) / 256, 256, 0, stream>>>(
      W_in, W_res, b_in, b_res, g0_Wl, g0_Wr, s1_Wp, s1_Wl, s1_Wr, g2_Wl, g2_Wr, s3_Wp,
      s3_Wl, s3_Wr, wsp, bsumf);

  // ---- input proj: h = x @ (W_in+W_res) + bsum  -> T2 ----
  gemm_rw<64, ACT_NONE, float><<<GB, 256, 0, stream>>>(x, WsT_h, WsT_l, bsumf, T2, N_);

  // ---- GAT layer 0 ----
  gemm_rw_dual_gat<<<GB, 256, 0, stream>>>(T2, WTh(0), WTl(0), WTh(1), WTl(1), g0_bl, g0_br,
                                           H0, H1, N_);
  gat_ln_kernel<<<WB, 256, 0, stream>>>(H0, H1, g0_att, g0_bias, rowptr, csr,
                                        ln_g + 0 * 128, ln_b + 0 * 128, B0, N_);

  // ---- SAGE layer 1 ----
  gemm_rw<128, ACT_RELU, _Float16><<<GB, 256, 0, stream>>>(B0, WTh(2), WTl(2), s1_bp, H0, N_);
  sage_agg_kernel<<<WB, 256, 0, stream>>>(H0, rowptr, csr, T1, N_);
  gemm_rw_dual_sage<<<GB, 256, 0, stream>>>(T1, WTh(3), WTl(3), B0, WTh(4), WTl(4), s1_bl,
                                            ln_g + 1 * 128, ln_b + 1 * 128, B1, N_);

  // ---- GAT layer 2 ----
  gemm_rw_dual_gat<<<GB, 256, 0, stream>>>(B1, WTh(5), WTl(5), WTh(6), WTl(6), g2_bl, g2_br,
                                           H0, H1, N_);
  gat_ln_kernel<<<WB, 256, 0, stream>>>(H0, H1, g2_att, g2_bias, rowptr, csr,
                                        ln_g + 2 * 128, ln_b + 2 * 128, B2, N_);

  // ---- SAGE layer 3 ----
  gemm_rw<128, ACT_RELU, _Float16><<<GB, 256, 0, stream>>>(B2, WTh(7), WTl(7), s3_bp, H0, N_);
  sage_agg_kernel<<<WB, 256, 0, stream>>>(H0, rowptr, csr, T1, N_);
  gemm_rw_dual_sage<<<GB, 256, 0, stream>>>(T1, WTh(8), WTl(8), B2, WTh(9), WTl(9), s3_bl,
                                            ln_g + 3 * 128, ln_b + 3 * 128, B3, N_);

  // ---- JK max + gate + pool + MLP ----
  hipMemsetAsync(pooled, 0, (size_t)G_ * HID_ * 4 + (size_t)G_ * 4, stream);
  {
    const int chunk = 12;
    int nwaves = (N_ + chunk - 1) / chunk;
    int nblocks = (nwaves + 3) / 4;
    jk_pool_kernel<<<nblocks, 256, 0, stream>>>(B0, B1, B2, B3, Wap, bap, batch,
                                                pooled, cntf, N_, chunk);
  }
  mlp_kernel<<<G_, 128, 0, stream>>>(pooled, cntf, Wc1, bc1, a1, Wc2, bc2, a2, Wc3, bc3, out);
}

// Round 11
// 647.635 us; speedup vs baseline: 2.2904x; 1.0969x over previous
//
#include <hip/hip_runtime.h>
#include <math.h>

constexpr int N_ = 50000;
constexpr int E_ = 800000;
constexpr int IN_ = 64;
constexpr int HID_ = 128;
constexpr int G_ = 64;
constexpr float NEG_ = 0.2f;
constexpr float LOG2E_ = 1.44269504088896340736f;

#define ACT_NONE 0
#define ACT_RELU 1

typedef _Float16 half8 __attribute__((ext_vector_type(8)));
typedef _Float16 half2v __attribute__((ext_vector_type(2)));
typedef float floatx4 __attribute__((ext_vector_type(4)));

// ---------------- CSR build ----------------
__global__ __launch_bounds__(256) void hist_kernel(const int* __restrict__ dst,
                                                   int* __restrict__ deg, int e) {
  int i = blockIdx.x * 256 + threadIdx.x;
  if (i < e) atomicAdd(&deg[dst[i]], 1);
}

__global__ __launch_bounds__(256) void scan1_kernel(const int* __restrict__ deg,
                                                    int* __restrict__ excl,
                                                    int* __restrict__ bscan, int n) {
  __shared__ int sh[256];
  int t = threadIdx.x;
  int i = blockIdx.x * 256 + t;
  int v = (i < n) ? deg[i] : 0;
  sh[t] = v;
  __syncthreads();
  for (int off = 1; off < 256; off <<= 1) {
    int y = (t >= off) ? sh[t - off] : 0;
    __syncthreads();
    sh[t] += y;
    __syncthreads();
  }
  int incl = sh[t];
  if (i < n) excl[i] = incl - v;
  if (t == 255) bscan[blockIdx.x] = incl;
}

__global__ __launch_bounds__(256) void scan2_kernel(int* __restrict__ data, int nb) {
  __shared__ int sh[256];
  int t = threadIdx.x;
  int v = (t < nb) ? data[t] : 0;
  sh[t] = v;
  __syncthreads();
  for (int off = 1; off < 256; off <<= 1) {
    int y = (t >= off) ? sh[t - off] : 0;
    __syncthreads();
    sh[t] += y;
    __syncthreads();
  }
  if (t < nb) data[t] = sh[t] - v;  // exclusive
}

__global__ __launch_bounds__(256) void scan3_kernel(int* __restrict__ rowptr,
                                                    int* __restrict__ cursor,
                                                    const int* __restrict__ bscan,
                                                    int n, int e) {
  int i = blockIdx.x * 256 + threadIdx.x;
  if (i < n) {
    int v = rowptr[i] + bscan[blockIdx.x];
    rowptr[i] = v;
    cursor[i] = v;
  }
  if (i == n) rowptr[n] = e;
}

__global__ __launch_bounds__(256) void fill_kernel(const int* __restrict__ src,
                                                   const int* __restrict__ dst,
                                                   int* __restrict__ cursor,
                                                   int* __restrict__ csr, int e) {
  int i = blockIdx.x * 256 + threadIdx.x;
  if (i < e) {
    int d = dst[i];
    int p = atomicAdd(&cursor[d], 1);
    csr[p] = src[i];
  }
}

// ---------------- weight prep: transpose + fp16 hi/lo split (+ bias sum fused) ----------------
__global__ __launch_bounds__(256) void prep_w_kernel(
    const float* __restrict__ W_in, const float* __restrict__ W_res,
    const float* __restrict__ b_in, const float* __restrict__ b_res,
    const float* __restrict__ m0, const float* __restrict__ m1,
    const float* __restrict__ m2, const float* __restrict__ m3,
    const float* __restrict__ m4, const float* __restrict__ m5,
    const float* __restrict__ m6, const float* __restrict__ m7,
    const float* __restrict__ m8, const float* __restrict__ m9,
    _Float16* __restrict__ dst, float* __restrict__ bsum) {
  int idx = blockIdx.x * 256 + threadIdx.x;
  if (idx < 8192) {
    int n = idx >> 6, k = idx & 63;
    float v = W_in[k * 128 + n] + W_res[k * 128 + n];
    _Float16 h = (_Float16)v;
    dst[idx] = h;
    dst[8192 + idx] = (_Float16)(v - (float)h);
  } else if (idx < 8192 + 10 * 16384) {
    int r = idx - 8192;
    int j = r >> 14;
    int e = r & 16383;
    int n = e >> 7, k = e & 127;
    const float* S;
    switch (j) {
      case 0: S = m0; break; case 1: S = m1; break; case 2: S = m2; break;
      case 3: S = m3; break; case 4: S = m4; break; case 5: S = m5; break;
      case 6: S = m6; break; case 7: S = m7; break; case 8: S = m8; break;
      default: S = m9; break;
    }
    float v = S[k * 128 + n];
    _Float16 h = (_Float16)v;
    _Float16* base = dst + 16384 + j * 32768;
    base[e] = h;                       // e == n*128+k
    base[16384 + e] = (_Float16)(v - (float)h);
  } else if (idx < 8192 + 10 * 16384 + 128) {
    int k = idx - (8192 + 10 * 16384);
    bsum[k] = b_in[k] + b_res[k];
  }
}

// ---------------- fp16 hi/lo split of 8 floats (input-proj GEMM only) ----------------
__device__ inline void split8v(float4 a, float4 b, half8& h, half8& l) {
  float v0 = a.x, v1 = a.y, v2 = a.z, v3 = a.w;
  float v4 = b.x, v5 = b.y, v6 = b.z, v7 = b.w;
  _Float16 h0 = (_Float16)v0, h1 = (_Float16)v1, h2 = (_Float16)v2, h3 = (_Float16)v3;
  _Float16 h4 = (_Float16)v4, h5 = (_Float16)v5, h6 = (_Float16)v6, h7 = (_Float16)v7;
  h[0] = h0; h[1] = h1; h[2] = h2; h[3] = h3; h[4] = h4; h[5] = h5; h[6] = h6; h[7] = h7;
  l[0] = (_Float16)(v0 - (float)h0); l[1] = (_Float16)(v1 - (float)h1);
  l[2] = (_Float16)(v2 - (float)h2); l[3] = (_Float16)(v3 - (float)h3);
  l[4] = (_Float16)(v4 - (float)h4); l[5] = (_Float16)(v5 - (float)h5);
  l[6] = (_Float16)(v6 - (float)h6); l[7] = (_Float16)(v7 - (float)h7);
}

// ---- input-proj GEMM (fp32 A, hi/lo split): C16 = A[M,64]@W + bias ----
__global__ __launch_bounds__(256, 2) void gemm_rw_in(const float* __restrict__ A,
                                                     const _Float16* __restrict__ Wh,
                                                     const _Float16* __restrict__ Wl,
                                                     const float* __restrict__ bias,
                                                     _Float16* __restrict__ C, int M) {
  constexpr int K1 = 64, KK = 2;
  const int t = threadIdx.x;
  const int wave = t >> 6, lane = t & 63;
  const int quad = lane >> 4, l16 = lane & 15;
  const int nt0 = wave * 2;

  half8 wh[2][KK], wl[2][KK];
  float bb[2];
  int col[2];
#pragma unroll
  for (int i = 0; i < 2; ++i) {
    col[i] = (nt0 + i) * 16 + l16;
    bb[i] = bias[col[i]];
#pragma unroll
    for (int k = 0; k < KK; ++k) {
      size_t off = (size_t)col[i] * K1 + k * 32 + quad * 8;
      wh[i][k] = *reinterpret_cast<const half8*>(Wh + off);
      wl[i][k] = *reinterpret_cast<const half8*>(Wl + off);
    }
  }
  const int r0 = blockIdx.x * 64;
#pragma unroll
  for (int tt = 0; tt < 4; ++tt) {
    int tb = r0 + tt * 16;
    if (tb >= M) break;
    int arow = tb + l16;
    if (arow >= M) arow = M - 1;
    const float* ap = A + (size_t)arow * K1 + quad * 8;
    floatx4 acc[2];
    acc[0] = (floatx4){0.f, 0.f, 0.f, 0.f};
    acc[1] = (floatx4){0.f, 0.f, 0.f, 0.f};
#pragma unroll
    for (int k = 0; k < KK; ++k) {
      float4 a0 = *reinterpret_cast<const float4*>(ap + k * 32);
      float4 a1 = *reinterpret_cast<const float4*>(ap + k * 32 + 4);
      half8 ah, al;
      split8v(a0, a1, ah, al);
      acc[0] = __builtin_amdgcn_mfma_f32_16x16x32_f16(ah, wh[0][k], acc[0], 0, 0, 0);
      acc[0] = __builtin_amdgcn_mfma_f32_16x16x32_f16(ah, wl[0][k], acc[0], 0, 0, 0);
      acc[0] = __builtin_amdgcn_mfma_f32_16x16x32_f16(al, wh[0][k], acc[0], 0, 0, 0);
      acc[1] = __builtin_amdgcn_mfma_f32_16x16x32_f16(ah, wh[1][k], acc[1], 0, 0, 0);
      acc[1] = __builtin_amdgcn_mfma_f32_16x16x32_f16(ah, wl[1][k], acc[1], 0, 0, 0);
      acc[1] = __builtin_amdgcn_mfma_f32_16x16x32_f16(al, wh[1][k], acc[1], 0, 0, 0);
    }
#pragma unroll
    for (int i = 0; i < 2; ++i) {
#pragma unroll
      for (int reg = 0; reg < 4; ++reg) {
        int r = tb + quad * 4 + reg;
        if (r < M) C[(size_t)r * 128 + col[i]] = (_Float16)(acc[i][reg] + bb[i]);
      }
    }
  }
}

// ---- fp16-A GEMM: C = act(A16[M,128]@W + bias); no split, 2 MFMA/tile ----
template <int ACT, typename OutT>
__global__ __launch_bounds__(256, 2) void gemm_rw16(const _Float16* __restrict__ A,
                                                    const _Float16* __restrict__ Wh,
                                                    const _Float16* __restrict__ Wl,
                                                    const float* __restrict__ bias,
                                                    OutT* __restrict__ C, int M) {
  const int t = threadIdx.x;
  const int wave = t >> 6, lane = t & 63;
  const int quad = lane >> 4, l16 = lane & 15;
  const int nt0 = wave * 2;

  half8 wh[2][4], wl[2][4];
  float bb[2];
  int col[2];
#pragma unroll
  for (int i = 0; i < 2; ++i) {
    col[i] = (nt0 + i) * 16 + l16;
    bb[i] = bias[col[i]];
#pragma unroll
    for (int k = 0; k < 4; ++k) {
      size_t off = (size_t)col[i] * 128 + k * 32 + quad * 8;
      wh[i][k] = *reinterpret_cast<const half8*>(Wh + off);
      wl[i][k] = *reinterpret_cast<const half8*>(Wl + off);
    }
  }
  const int r0 = blockIdx.x * 64;
#pragma unroll
  for (int tt = 0; tt < 4; ++tt) {
    int tb = r0 + tt * 16;
    if (tb >= M) break;
    int arow = tb + l16;
    if (arow >= M) arow = M - 1;
    const _Float16* ap = A + (size_t)arow * 128 + quad * 8;
    half8 a[4];
#pragma unroll
    for (int k = 0; k < 4; ++k) a[k] = *reinterpret_cast<const half8*>(ap + k * 32);
    floatx4 acc[2];
    acc[0] = (floatx4){0.f, 0.f, 0.f, 0.f};
    acc[1] = (floatx4){0.f, 0.f, 0.f, 0.f};
#pragma unroll
    for (int k = 0; k < 4; ++k) {
      acc[0] = __builtin_amdgcn_mfma_f32_16x16x32_f16(a[k], wh[0][k], acc[0], 0, 0, 0);
      acc[0] = __builtin_amdgcn_mfma_f32_16x16x32_f16(a[k], wl[0][k], acc[0], 0, 0, 0);
      acc[1] = __builtin_amdgcn_mfma_f32_16x16x32_f16(a[k], wh[1][k], acc[1], 0, 0, 0);
      acc[1] = __builtin_amdgcn_mfma_f32_16x16x32_f16(a[k], wl[1][k], acc[1], 0, 0, 0);
    }
#pragma unroll
    for (int i = 0; i < 2; ++i) {
#pragma unroll
      for (int reg = 0; reg < 4; ++reg) {
        int r = tb + quad * 4 + reg;
        if (r < M) {
          float v = acc[i][reg] + bb[i];
          if (ACT == ACT_RELU) v = fmaxf(v, 0.f);
          C[(size_t)r * 128 + col[i]] = (OutT)v;
        }
      }
    }
  }
}

// ---- fp16-A dual-output GEMM (GAT): C0 = A@W0+b0, C1 = A@W1+b1 ----
__global__ __launch_bounds__(256, 2) void gemm_rw16_dual_gat(const _Float16* __restrict__ A,
                                                             const _Float16* __restrict__ W0h,
                                                             const _Float16* __restrict__ W0l,
                                                             const _Float16* __restrict__ W1h,
                                                             const _Float16* __restrict__ W1l,
                                                             const float* __restrict__ b0,
                                                             const float* __restrict__ b1,
                                                             _Float16* __restrict__ C0,
                                                             _Float16* __restrict__ C1, int M) {
  const int t = threadIdx.x;
  const int wave = t >> 6, lane = t & 63;
  const int quad = lane >> 4, l16 = lane & 15;
  const int nt0 = wave * 2;

  half8 w0h[2][4], w0l[2][4], w1h[2][4], w1l[2][4];
  float bb0[2], bb1[2];
  int col[2];
#pragma unroll
  for (int i = 0; i < 2; ++i) {
    col[i] = (nt0 + i) * 16 + l16;
    bb0[i] = b0[col[i]];
    bb1[i] = b1[col[i]];
#pragma unroll
    for (int k = 0; k < 4; ++k) {
      size_t off = (size_t)col[i] * 128 + k * 32 + quad * 8;
      w0h[i][k] = *reinterpret_cast<const half8*>(W0h + off);
      w0l[i][k] = *reinterpret_cast<const half8*>(W0l + off);
      w1h[i][k] = *reinterpret_cast<const half8*>(W1h + off);
      w1l[i][k] = *reinterpret_cast<const half8*>(W1l + off);
    }
  }
  const int r0 = blockIdx.x * 64;
#pragma unroll
  for (int tt = 0; tt < 4; ++tt) {
    int tb = r0 + tt * 16;
    if (tb >= M) break;
    int arow = tb + l16;
    if (arow >= M) arow = M - 1;
    const _Float16* ap = A + (size_t)arow * 128 + quad * 8;
    half8 a[4];
#pragma unroll
    for (int k = 0; k < 4; ++k) a[k] = *reinterpret_cast<const half8*>(ap + k * 32);
    floatx4 acc0[2], acc1[2];
    acc0[0] = (floatx4){0.f, 0.f, 0.f, 0.f};
    acc0[1] = (floatx4){0.f, 0.f, 0.f, 0.f};
    acc1[0] = (floatx4){0.f, 0.f, 0.f, 0.f};
    acc1[1] = (floatx4){0.f, 0.f, 0.f, 0.f};
#pragma unroll
    for (int k = 0; k < 4; ++k) {
#pragma unroll
      for (int i = 0; i < 2; ++i) {
        acc0[i] = __builtin_amdgcn_mfma_f32_16x16x32_f16(a[k], w0h[i][k], acc0[i], 0, 0, 0);
        acc0[i] = __builtin_amdgcn_mfma_f32_16x16x32_f16(a[k], w0l[i][k], acc0[i], 0, 0, 0);
        acc1[i] = __builtin_amdgcn_mfma_f32_16x16x32_f16(a[k], w1h[i][k], acc1[i], 0, 0, 0);
        acc1[i] = __builtin_amdgcn_mfma_f32_16x16x32_f16(a[k], w1l[i][k], acc1[i], 0, 0, 0);
      }
    }
#pragma unroll
    for (int i = 0; i < 2; ++i) {
#pragma unroll
      for (int reg = 0; reg < 4; ++reg) {
        int r = tb + quad * 4 + reg;
        if (r < M) {
          C0[(size_t)r * 128 + col[i]] = (_Float16)(acc0[i][reg] + bb0[i]);
          C1[(size_t)r * 128 + col[i]] = (_Float16)(acc1[i][reg] + bb1[i]);
        }
      }
    }
  }
}

// ---- fp16-A dual-A GEMM (SAGE) + fused L2norm + LN + leaky; fp16 out ----
__global__ __launch_bounds__(256, 2) void gemm_rw16_dual_sage(const _Float16* __restrict__ A1,
                                                              const _Float16* __restrict__ W1h,
                                                              const _Float16* __restrict__ W1l,
                                                              const _Float16* __restrict__ A2,
                                                              const _Float16* __restrict__ W2h,
                                                              const _Float16* __restrict__ W2l,
                                                              const float* __restrict__ bias,
                                                              const float* __restrict__ lng,
                                                              const float* __restrict__ lnb,
                                                              _Float16* __restrict__ C, int M) {
  const int t = threadIdx.x;
  const int wave = t >> 6, lane = t & 63;
  const int quad = lane >> 4, l16 = lane & 15;
  const int nt0 = wave * 2;

  half8 w1h[2][4], w1l[2][4], w2h[2][4], w2l[2][4];
  float bb[2], gg[2], lb[2];
  int col[2];
#pragma unroll
  for (int i = 0; i < 2; ++i) {
    col[i] = (nt0 + i) * 16 + l16;
    bb[i] = bias[col[i]];
    gg[i] = lng[col[i]];
    lb[i] = lnb[col[i]];
#pragma unroll
    for (int k = 0; k < 4; ++k) {
      size_t off = (size_t)col[i] * 128 + k * 32 + quad * 8;
      w1h[i][k] = *reinterpret_cast<const half8*>(W1h + off);
      w1l[i][k] = *reinterpret_cast<const half8*>(W1l + off);
      w2h[i][k] = *reinterpret_cast<const half8*>(W2h + off);
      w2l[i][k] = *reinterpret_cast<const half8*>(W2l + off);
    }
  }
  __shared__ float2 red[2][4][16];  // [tile parity][wave][row]
  const int r0 = blockIdx.x * 64;
#pragma unroll 1
  for (int tt = 0; tt < 4; ++tt) {
    int tb = r0 + tt * 16;
    if (tb >= M) break;
    int arow = tb + l16;
    if (arow >= M) arow = M - 1;
    const _Float16* ap1 = A1 + (size_t)arow * 128 + quad * 8;
    const _Float16* ap2 = A2 + (size_t)arow * 128 + quad * 8;
    half8 a[4], b[4];
#pragma unroll
    for (int k = 0; k < 4; ++k) {
      a[k] = *reinterpret_cast<const half8*>(ap1 + k * 32);
      b[k] = *reinterpret_cast<const half8*>(ap2 + k * 32);
    }
    floatx4 acc[2];
    acc[0] = (floatx4){0.f, 0.f, 0.f, 0.f};
    acc[1] = (floatx4){0.f, 0.f, 0.f, 0.f};
#pragma unroll
    for (int k = 0; k < 4; ++k) {
#pragma unroll
      for (int i = 0; i < 2; ++i) {
        acc[i] = __builtin_amdgcn_mfma_f32_16x16x32_f16(a[k], w1h[i][k], acc[i], 0, 0, 0);
        acc[i] = __builtin_amdgcn_mfma_f32_16x16x32_f16(a[k], w1l[i][k], acc[i], 0, 0, 0);
        acc[i] = __builtin_amdgcn_mfma_f32_16x16x32_f16(b[k], w2h[i][k], acc[i], 0, 0, 0);
        acc[i] = __builtin_amdgcn_mfma_f32_16x16x32_f16(b[k], w2l[i][k], acc[i], 0, 0, 0);
      }
    }
    float v0[4], v1[4], p1[4], p2[4];
#pragma unroll
    for (int reg = 0; reg < 4; ++reg) {
      v0[reg] = acc[0][reg] + bb[0];
      v1[reg] = acc[1][reg] + bb[1];
      p1[reg] = v0[reg] + v1[reg];
      p2[reg] = v0[reg] * v0[reg] + v1[reg] * v1[reg];
    }
#pragma unroll
    for (int off = 1; off < 16; off <<= 1) {
#pragma unroll
      for (int reg = 0; reg < 4; ++reg) {
        p1[reg] += __shfl_xor(p1[reg], off, 64);
        p2[reg] += __shfl_xor(p2[reg], off, 64);
      }
    }
    int par = tt & 1;
    if (l16 == 0) {
#pragma unroll
      for (int reg = 0; reg < 4; ++reg)
        red[par][wave][quad * 4 + reg] = make_float2(p1[reg], p2[reg]);
    }
    __syncthreads();
#pragma unroll
    for (int reg = 0; reg < 4; ++reg) {
      int rr = quad * 4 + reg;
      float2 q0 = red[par][0][rr], q1 = red[par][1][rr];
      float2 q2 = red[par][2][rr], q3 = red[par][3][rr];
      float s1 = q0.x + q1.x + q2.x + q3.x;
      float s2 = q0.y + q1.y + q2.y + q3.y;
      float inv = 1.f / fmaxf(sqrtf(s2), 1e-12f);
      float mu = s1 * inv * (1.f / 128.f);
      float ex2 = (s2 * inv) * inv * (1.f / 128.f);
      float rstd = rsqrtf(ex2 - mu * mu + 1e-5f);
      int r = tb + rr;
      if (r < M) {
        float o0 = (v0[reg] * inv - mu) * rstd * gg[0] + lb[0];
        float o1 = (v1[reg] * inv - mu) * rstd * gg[1] + lb[1];
        o0 = fmaxf(o0, NEG_ * o0);
        o1 = fmaxf(o1, NEG_ * o1);
        C[(size_t)r * 128 + col[0]] = (_Float16)o0;
        C[(size_t)r * 128 + col[1]] = (_Float16)o1;
      }
    }
  }
}

// ---------------- GATv2 + LN + ELU; lane=(head, edge-slot); fp16 out (R9 body) ----------------
__global__ __launch_bounds__(256) void gat_ln_kernel(const _Float16* __restrict__ xl,
                                                     const _Float16* __restrict__ xr,
                                                     const float* __restrict__ att,
                                                     const float* __restrict__ gbias,
                                                     const int* __restrict__ rowptr,
                                                     const int* __restrict__ csr,
                                                     const float* __restrict__ lng,
                                                     const float* __restrict__ lnb,
                                                     _Float16* __restrict__ out, int n) {
  int wid = (blockIdx.x * 256 + threadIdx.x) >> 6;
  int lane = threadIdx.x & 63;
  if (wid >= n) return;
  const int h = lane >> 3, e = lane & 7;
  const char* __restrict__ xbase = (const char*)(xl + h * 16);

  half2v xr2[8], at2[8];
  {
    const uint4* xrp = reinterpret_cast<const uint4*>(xr + (size_t)wid * 128 + h * 16);
    uint4 u0 = xrp[0], u1 = xrp[1];
    unsigned uu[8] = {u0.x, u0.y, u0.z, u0.w, u1.x, u1.y, u1.z, u1.w};
#pragma unroll
    for (int i = 0; i < 8; ++i) xr2[i] = __builtin_bit_cast(half2v, uu[i]);
    const float2* ap = reinterpret_cast<const float2*>(att + h * 16);
#pragma unroll
    for (int i = 0; i < 8; ++i) {
      float2 a = ap[i];
      at2[i][0] = (_Float16)(a.x * LOG2E_);
      at2[i][1] = (_Float16)(a.y * LOG2E_);
    }
  }
  const half2v negc = {(_Float16)NEG_, (_Float16)NEG_};

  float m0, den;
  float acc[16];
  {
    const uint4* sp = reinterpret_cast<const uint4*>(xbase + (size_t)wid * 256);
    uint4 u0 = sp[0], u1 = sp[1];
    unsigned uu[8] = {u0.x, u0.y, u0.z, u0.w, u1.x, u1.y, u1.z, u1.w};
    float p = 0.f;
#pragma unroll
    for (int i = 0; i < 8; ++i) {
      half2v x = __builtin_bit_cast(half2v, uu[i]);
      half2v z = x + xr2[i];
      half2v zl = __builtin_elementwise_max(z, z * negc);
      p = __builtin_amdgcn_fdot2(zl, at2[i], p, false);
    }
    m0 = p;
    float w = (e == 0) ? 1.f : 0.f;
    den = w;
#pragma unroll
    for (int i = 0; i < 8; ++i) {
      half2v x = __builtin_bit_cast(half2v, uu[i]);
      acc[2 * i] = w * (float)x[0];
      acc[2 * i + 1] = w * (float)x[1];
    }
  }

  int beg = rowptr[wid], end = rowptr[wid + 1];
  for (int base = beg; base < end; base += 8) {
    int idx = base + e;
    bool valid = idx < end;
    int ci = valid ? idx : end - 1;
    int s = csr[ci];
    const uint4* gp = reinterpret_cast<const uint4*>(xbase + (size_t)s * 256);
    uint4 u0 = gp[0], u1 = gp[1];
    unsigned uu[8] = {u0.x, u0.y, u0.z, u0.w, u1.x, u1.y, u1.z, u1.w};
    float p = 0.f;
#pragma unroll
    for (int i = 0; i < 8; ++i) {
      half2v x = __builtin_bit_cast(half2v, uu[i]);
      half2v z = x + xr2[i];
      half2v zl = __builtin_elementwise_max(z, z * negc);
      p = __builtin_amdgcn_fdot2(zl, at2[i], p, false);
    }
    float w = valid ? exp2f(p - m0) : 0.f;
    den += w;
#pragma unroll
    for (int i = 0; i < 8; ++i) {
      half2v x = __builtin_bit_cast(half2v, uu[i]);
      acc[2 * i] += w * (float)x[0];
      acc[2 * i + 1] += w * (float)x[1];
    }
  }

#pragma unroll
  for (int off = 1; off < 8; off <<= 1) {
    den += __shfl_xor(den, off, 64);
#pragma unroll
    for (int i = 0; i < 16; ++i) acc[i] += __shfl_xor(acc[i], off, 64);
  }

  float inv = 1.f / (den + 1e-16f);
  int c = h * 16 + 2 * e;
  float2 bv = reinterpret_cast<const float2*>(gbias + c)[0];
  float o0 = acc[2 * e] * inv + bv.x;
  float o1 = acc[2 * e + 1] * inv + bv.y;
  float s1 = o0 + o1;
  float s2 = o0 * o0 + o1 * o1;
#pragma unroll
  for (int off = 1; off < 64; off <<= 1) {
    s1 += __shfl_xor(s1, off, 64);
    s2 += __shfl_xor(s2, off, 64);
  }
  float mu = s1 * (1.f / 128.f);
  float var = s2 * (1.f / 128.f) - mu * mu;
  float rstd = rsqrtf(var + 1e-5f);
  float2 gvv = reinterpret_cast<const float2*>(lng + c)[0];
  float2 lbv = reinterpret_cast<const float2*>(lnb + c)[0];
  float e0 = (o0 - mu) * rstd * gvv.x + lbv.x;
  float e1 = (o1 - mu) * rstd * gvv.y + lbv.y;
  e0 = e0 > 0.f ? e0 : exp2f(e0 * LOG2E_) - 1.f;
  e1 = e1 > 0.f ? e1 : exp2f(e1 * LOG2E_) - 1.f;
  half2v o;
  o[0] = (_Float16)e0;
  o[1] = (_Float16)e1;
  reinterpret_cast<half2v*>(out)[wid * 64 + (c >> 1)] = o;
}

// ---------------- SAGE mean aggregation; fp16 in/out; lane = (group, edge-slot) ----------------
__global__ __launch_bounds__(256) void sage_agg_kernel(const _Float16* __restrict__ xp,
                                                       const int* __restrict__ rowptr,
                                                       const int* __restrict__ csr,
                                                       _Float16* __restrict__ mean, int n) {
  int wid = (blockIdx.x * 256 + threadIdx.x) >> 6;
  int lane = threadIdx.x & 63;
  if (wid >= n) return;
  const int g = lane >> 3, e = lane & 7;
  const char* __restrict__ xbase = (const char*)(xp + g * 16);

  float acc[16];
#pragma unroll
  for (int i = 0; i < 16; ++i) acc[i] = 0.f;

  int beg = rowptr[wid], end = rowptr[wid + 1];
  for (int base = beg; base < end; base += 8) {
    int idx = base + e;
    bool valid = idx < end;
    int ci = valid ? idx : end - 1;
    int s = csr[ci];
    const uint4* gp = reinterpret_cast<const uint4*>(xbase + (size_t)s * 256);
    uint4 u0 = gp[0], u1 = gp[1];
    unsigned uu[8] = {u0.x, u0.y, u0.z, u0.w, u1.x, u1.y, u1.z, u1.w};
    float w = valid ? 1.f : 0.f;
#pragma unroll
    for (int i = 0; i < 8; ++i) {
      half2v x = __builtin_bit_cast(half2v, uu[i]);
      acc[2 * i] += w * (float)x[0];
      acc[2 * i + 1] += w * (float)x[1];
    }
  }
#pragma unroll
  for (int off = 1; off < 8; off <<= 1) {
#pragma unroll
    for (int i = 0; i < 16; ++i) acc[i] += __shfl_xor(acc[i], off, 64);
  }
  float inv = 1.f / fmaxf((float)(end - beg), 1.f);
  int c = g * 16 + 2 * e;
  half2v o;
  o[0] = (_Float16)(acc[2 * e] * inv);
  o[1] = (_Float16)(acc[2 * e + 1] * inv);
  reinterpret_cast<half2v*>(mean)[wid * 64 + (c >> 1)] = o;
}

// ---------------- JK max + sigmoid gate + mean-pool (fp16 inputs) ----------------
__global__ __launch_bounds__(256) void jk_pool_kernel(const _Float16* __restrict__ x0,
                                                      const _Float16* __restrict__ x1,
                                                      const _Float16* __restrict__ x2,
                                                      const _Float16* __restrict__ x3,
                                                      const float* __restrict__ wap,
                                                      const float* __restrict__ bap,
                                                      const int* __restrict__ batch,
                                                      float* __restrict__ pooled,
                                                      float* __restrict__ cnt, int n,
                                                      int chunk) {
  int wid = (blockIdx.x * 256 + threadIdx.x) >> 6;
  int lane = threadIdx.x & 63;
  int start = wid * chunk;
  if (start >= n) return;
  int end = start + chunk;
  if (end > n) end = n;

  const float2 wv = reinterpret_cast<const float2*>(wap)[lane];
  const float b0 = bap[0];

  int cur = -1;
  float2 acc = make_float2(0.f, 0.f);
  float c = 0.f;

  for (int i = start; i < end; ++i) {
    int off = i * 64 + lane;
    half2v a0 = reinterpret_cast<const half2v*>(x0)[off];
    half2v a1 = reinterpret_cast<const half2v*>(x1)[off];
    half2v a2 = reinterpret_cast<const half2v*>(x2)[off];
    half2v a3 = reinterpret_cast<const half2v*>(x3)[off];
    half2v m01 = __builtin_elementwise_max(a0, a1);
    half2v m23 = __builtin_elementwise_max(a2, a3);
    half2v mm = __builtin_elementwise_max(m01, m23);
    float2 v = make_float2((float)mm[0], (float)mm[1]);
    float p = v.x * wv.x + v.y * wv.y;
#pragma unroll
    for (int o = 1; o < 64; o <<= 1) p += __shfl_xor(p, o, 64);
    float a = 1.f / (1.f + exp2f(-(p + b0) * LOG2E_));
    int bg = batch[i];
    if (bg != cur) {
      if (cur >= 0) {
        atomicAdd(&pooled[cur * 128 + 2 * lane], acc.x);
        atomicAdd(&pooled[cur * 128 + 2 * lane + 1], acc.y);
        if (lane == 0) atomicAdd(&cnt[cur], c);
      }
      cur = bg;
      acc = make_float2(0.f, 0.f);
      c = 0.f;
    }
    acc.x += v.x * a;
    acc.y += v.y * a;
    c += 1.f;
  }
  if (cur >= 0) {
    atomicAdd(&pooled[cur * 128 + 2 * lane], acc.x);
    atomicAdd(&pooled[cur * 128 + 2 * lane + 1], acc.y);
    if (lane == 0) atomicAdd(&cnt[cur], c);
  }
}

// ---------------- final MLP: one block per graph ----------------
__global__ __launch_bounds__(128) void mlp_kernel(const float* __restrict__ pooled,
                                                  const float* __restrict__ cnt,
                                                  const float* __restrict__ Wc1,
                                                  const float* __restrict__ bc1,
                                                  const float* __restrict__ a1,
                                                  const float* __restrict__ Wc2,
                                                  const float* __restrict__ bc2,
                                                  const float* __restrict__ a2,
                                                  const float* __restrict__ Wc3,
                                                  const float* __restrict__ bc3,
                                                  float* __restrict__ out) {
  __shared__ float sh[128];
  __shared__ float sh2[128];
  __shared__ float sh3[64];
  int g = blockIdx.x, t = threadIdx.x;
  float inv = 1.f / fmaxf(cnt[g], 1.f);
  sh[t] = pooled[g * 128 + t] * inv;
  __syncthreads();
  float z = bc1[t];
  for (int k = 0; k < 128; ++k) z += sh[k] * Wc1[k * 128 + t];
  float al = a1[0];
  z = z >= 0.f ? z : al * z;
  sh2[t] = z;
  __syncthreads();
  if (t < 64) {
    float z2 = bc2[t];
    for (int k = 0; k < 128; ++k) z2 += sh2[k] * Wc2[k * 64 + t];
    float a2v = a2[0];
    z2 = z2 >= 0.f ? z2 : a2v * z2;
    sh3[t] = z2;
  }
  __syncthreads();
  if (t < 2) {
    float o = bc3[t];
    for (int k = 0; k < 64; ++k) o += sh3[k] * Wc3[k * 2 + t];
    out[g * 2 + t] = o;
  }
}

// ================= host =================
extern "C" void kernel_launch(void* const* d_in, const int* in_sizes, int n_in,
                              void* d_out, int out_size, void* d_ws, size_t ws_size,
                              hipStream_t stream) {
  const float* x = (const float*)d_in[0];
  const int* ei = (const int*)d_in[1];
  const int* batch = (const int*)d_in[2];
  const float* W_in = (const float*)d_in[3];
  const float* b_in = (const float*)d_in[4];
  const float* W_res = (const float*)d_in[5];
  const float* b_res = (const float*)d_in[6];
  const float* g0_Wl = (const float*)d_in[7];
  const float* g0_bl = (const float*)d_in[8];
  const float* g0_Wr = (const float*)d_in[9];
  const float* g0_br = (const float*)d_in[10];
  const float* g0_att = (const float*)d_in[11];
  const float* g0_bias = (const float*)d_in[12];
  const float* g2_Wl = (const float*)d_in[13];
  const float* g2_bl = (const float*)d_in[14];
  const float* g2_Wr = (const float*)d_in[15];
  const float* g2_br = (const float*)d_in[16];
  const float* g2_att = (const float*)d_in[17];
  const float* g2_bias = (const float*)d_in[18];
  const float* s1_Wp = (const float*)d_in[19];
  const float* s1_bp = (const float*)d_in[20];
  const float* s1_Wl = (const float*)d_in[21];
  const float* s1_bl = (const float*)d_in[22];
  const float* s1_Wr = (const float*)d_in[23];
  const float* s3_Wp = (const float*)d_in[24];
  const float* s3_bp = (const float*)d_in[25];
  const float* s3_Wl = (const float*)d_in[26];
  const float* s3_bl = (const float*)d_in[27];
  const float* s3_Wr = (const float*)d_in[28];
  const float* ln_g = (const float*)d_in[29];
  const float* ln_b = (const float*)d_in[30];
  const float* Wap = (const float*)d_in[31];
  const float* bap = (const float*)d_in[32];
  const float* Wc1 = (const float*)d_in[33];
  const float* bc1 = (const float*)d_in[34];
  const float* a1 = (const float*)d_in[35];
  const float* Wc2 = (const float*)d_in[36];
  const float* bc2 = (const float*)d_in[37];
  const float* a2 = (const float*)d_in[38];
  const float* Wc3 = (const float*)d_in[39];
  const float* bc3 = (const float*)d_in[40];
  float* out = (float*)d_out;

  char* w = (char*)d_ws;
  auto alloc = [&](size_t bytes) -> void* {
    void* p = (void*)w;
    w += (bytes + 255) & ~(size_t)255;
    return p;
  };
  int* deg_cursor = (int*)alloc((size_t)N_ * 4);
  int* rowptr = (int*)alloc((size_t)(N_ + 1) * 4);
  int* bscan = (int*)alloc(256 * 4);
  int* csr = (int*)alloc((size_t)E_ * 4);
  float* bsumf = (float*)alloc((size_t)HID_ * 4);
  float* pooled = (float*)alloc((size_t)G_ * HID_ * 4);
  float* cntf = (float*)alloc((size_t)G_ * 4);
  _Float16* wsp = (_Float16*)alloc((size_t)(16384 + 10 * 32768) * 2);
  size_t bigh = (size_t)N_ * HID_ * 2;
  _Float16* T1 = (_Float16*)alloc(bigh);          // mean (fp16)
  _Float16* T2 = (_Float16*)alloc(bigh);          // input proj out (fp16)
  _Float16* H0 = (_Float16*)alloc(bigh);          // xl16 / xp16
  _Float16* H1 = (_Float16*)alloc(bigh);          // xr16
  _Float16* B0 = (_Float16*)alloc(bigh);
  _Float16* B1 = (_Float16*)alloc(bigh);
  _Float16* B2 = (_Float16*)alloc(bigh);
  _Float16* B3 = (_Float16*)alloc(bigh);

  const _Float16* WsT_h = wsp;
  const _Float16* WsT_l = wsp + 8192;
  auto WTh = [&](int j) { return (const _Float16*)(wsp + 16384 + j * 32768); };
  auto WTl = [&](int j) { return (const _Float16*)(wsp + 16384 + j * 32768 + 16384); };
  // j: 0 g0_Wl, 1 g0_Wr, 2 s1_Wp, 3 s1_Wl, 4 s1_Wr, 5 g2_Wl, 6 g2_Wr, 7 s3_Wp, 8 s3_Wl, 9 s3_Wr

  const int EB = (E_ + 255) / 256;
  const int NB256 = (N_ + 255) / 256;
  const int WB = (N_ + 3) / 4;
  const int GB = (N_ + 63) / 64;

  // ---- CSR build ----
  hipMemsetAsync(deg_cursor, 0, (size_t)N_ * 4, stream);
  hist_kernel<<<EB, 256, 0, stream>>>(ei + E_, deg_cursor, E_);
  scan1_kernel<<<NB256, 256, 0, stream>>>(deg_cursor, rowptr, bscan, N_);
  scan2_kernel<<<1, 256, 0, stream>>>(bscan, NB256);
  scan3_kernel<<<NB256, 256, 0, stream>>>(rowptr, deg_cursor, bscan, N_, E_);
  fill_kernel<<<EB, 256, 0, stream>>>(ei, ei + E_, deg_cursor, csr, E_);

  // ---- weight prep (incl. bias sum) ----
  prep_w_kernel<<<(8192 + 10 * 16384 + 128 + 255) / 256, 256, 0, stream>>>(
      W_in, W_res, b_in, b_res, g0_Wl, g0_Wr, s1_Wp, s1_Wl, s1_Wr, g2_Wl, g2_Wr, s3_Wp,
      s3_Wl, s3_Wr, wsp, bsumf);

  // ---- input proj: h = x @ (W_in+W_res) + bsum  -> T2 (fp16) ----
  gemm_rw_in<<<GB, 256, 0, stream>>>(x, WsT_h, WsT_l, bsumf, T2, N_);

  // ---- GAT layer 0 ----
  gemm_rw16_dual_gat<<<GB, 256, 0, stream>>>(T2, WTh(0), WTl(0), WTh(1), WTl(1), g0_bl,
                                             g0_br, H0, H1, N_);
  gat_ln_kernel<<<WB, 256, 0, stream>>>(H0, H1, g0_att, g0_bias, rowptr, csr,
                                        ln_g + 0 * 128, ln_b + 0 * 128, B0, N_);

  // ---- SAGE layer 1 ----
  gemm_rw16<ACT_RELU, _Float16><<<GB, 256, 0, stream>>>(B0, WTh(2), WTl(2), s1_bp, H0, N_);
  sage_agg_kernel<<<WB, 256, 0, stream>>>(H0, rowptr, csr, T1, N_);
  gemm_rw16_dual_sage<<<GB, 256, 0, stream>>>(T1, WTh(3), WTl(3), B0, WTh(4), WTl(4), s1_bl,
                                              ln_g + 1 * 128, ln_b + 1 * 128, B1, N_);

  // ---- GAT layer 2 ----
  gemm_rw16_dual_gat<<<GB, 256, 0, stream>>>(B1, WTh(5), WTl(5), WTh(6), WTl(6), g2_bl,
                                             g2_br, H0, H1, N_);
  gat_ln_kernel<<<WB, 256, 0, stream>>>(H0, H1, g2_att, g2_bias, rowptr, csr,
                                        ln_g + 2 * 128, ln_b + 2 * 128, B2, N_);

  // ---- SAGE layer 3 ----
  gemm_rw16<ACT_RELU, _Float16><<<GB, 256, 0, stream>>>(B2, WTh(7), WTl(7), s3_bp, H0, N_);
  sage_agg_kernel<<<WB, 256, 0, stream>>>(H0, rowptr, csr, T1, N_);
  gemm_rw16_dual_sage<<<GB, 256, 0, stream>>>(T1, WTh(8), WTl(8), B2, WTh(9), WTl(9), s3_bl,
                                              ln_g + 3 * 128, ln_b + 3 * 128, B3, N_);

  // ---- JK max + gate + pool + MLP ----
  hipMemsetAsync(pooled, 0, (size_t)G_ * HID_ * 4 + (size_t)G_ * 4, stream);
  {
    const int chunk = 12;
    int nwaves = (N_ + chunk - 1) / chunk;
    int nblocks = (nwaves + 3) / 4;
    jk_pool_kernel<<<nblocks, 256, 0, stream>>>(B0, B1, B2, B3, Wap, bap, batch,
                                                pooled, cntf, N_, chunk);
  }
  mlp_kernel<<<G_, 128, 0, stream>>>(pooled, cntf, Wc1, bc1, a1, Wc2, bc2, a2, Wc3, bc3, out);
}